// Round 5
// baseline (976.134 us; speedup 1.0000x reference)
//
#include <hip/hip_runtime.h>

// Problem constants (match reference)
#define N_NODES 100000
#define N_EDGES 1200000
#define DIM     64
#define BGRAPHS 1000
#define NCLASS  10
#define BN_EPS  1e-5f

// CSR-build partition constants
#define NBUCK   256            // coarse buckets
#define NPB     391            // nodes per bucket (256*391 = 100096 >= N)
#define MAGIC   10984572u      // ceil(2^32/391): bucket = umulhi(d, MAGIC)
#define CHUNK   8192           // edges per partition block
#define NBLK_P  147            // ceil(E / CHUNK)
#define NB_C    3125           // N*DIM/8/256 convert blocks

typedef __attribute__((ext_vector_type(8))) short   bfx8;   // 8 bf16 MFMA A/B frag
typedef __attribute__((ext_vector_type(4))) float   f32x4;  // MFMA C/D frag
typedef __attribute__((ext_vector_type(8))) unsigned short u16x8;

__device__ __forceinline__ unsigned short f2bf(float f) {
    unsigned u = __builtin_bit_cast(unsigned, f);
    unsigned r = (u + 0x7FFFu + ((u >> 16) & 1u)) >> 16;   // RNE
    return (unsigned short)r;
}
__device__ __forceinline__ float bf2f(unsigned short h) {
    unsigned u = ((unsigned)h) << 16;
    return __builtin_bit_cast(float, u);
}

// ---------------------------------------------------------------------------
// Kernel A (merged): blocks [0,NBLK_P) = per-chunk bucket histogram partials;
// blocks [NBLK_P, NBLK_P+NB_C) = fp32->bf16 convert + zero xs.
// ---------------------------------------------------------------------------
__global__ __launch_bounds__(256) void convhist_kernel(
    const float* __restrict__ x, unsigned short* __restrict__ xb,
    float* __restrict__ xs, const int* __restrict__ ei,
    int* __restrict__ gpart) {
    __shared__ int cnt[NBUCK];
    int t = threadIdx.x;
    if (blockIdx.x < NBLK_P) {
        int blk = blockIdx.x;
        cnt[t] = 0;
        __syncthreads();
        int e0 = blk * CHUNK;
        for (int i = t; i < CHUNK; i += 256) {
            int e = e0 + i;
            if (e >= N_EDGES) break;
            unsigned d = (unsigned)ei[N_EDGES + e];
            atomicAdd(&cnt[__umulhi(d, MAGIC)], 1);
        }
        __syncthreads();
        gpart[blk * NBUCK + t] = cnt[t];
    } else {
        int i = (blockIdx.x - NBLK_P) * 256 + t;
        const int n8 = N_NODES * DIM / 8;
        if (i < n8) {
            float4 a = ((const float4*)x)[i * 2];
            float4 b = ((const float4*)x)[i * 2 + 1];
            u16x8 o;
            o[0] = f2bf(a.x); o[1] = f2bf(a.y); o[2] = f2bf(a.z); o[3] = f2bf(a.w);
            o[4] = f2bf(b.x); o[5] = f2bf(b.y); o[6] = f2bf(b.z); o[7] = f2bf(b.w);
            ((u16x8*)xb)[i] = o;
        }
        if (i < BGRAPHS * DIM) xs[i] = 0.f;
    }
}

// ---------------------------------------------------------------------------
// Single-block scan: reduce 147 partials per bucket, exclusive-scan 256
// totals -> base[257]; init cursor = base for part's chunk reservation.
// ---------------------------------------------------------------------------
__global__ __launch_bounds__(256) void scanB_kernel(const int* __restrict__ gpart,
                                                    int* __restrict__ base,
                                                    int* __restrict__ cursor) {
    __shared__ int tmp[256];
    int t = threadIdx.x;
    int s = 0;
    for (int blk = 0; blk < NBLK_P; ++blk) s += gpart[blk * NBUCK + t];
    tmp[t] = s;
    __syncthreads();
    for (int off = 1; off < 256; off <<= 1) {
        int a = (t >= off) ? tmp[t - off] : 0;
        __syncthreads();
        tmp[t] += a;
        __syncthreads();
    }
    int excl = tmp[t] - s;
    base[t] = excl;
    cursor[t] = excl;
    if (t == 255) base[256] = N_EDGES;
}

// ---------------------------------------------------------------------------
// Partition: per-block LDS count, reserve per-bucket chunk with ONE global
// atomicAdd per (block,bucket), then place edges. Order within bucket is
// irrelevant (scatter accumulates by dst_local).
// ---------------------------------------------------------------------------
__global__ __launch_bounds__(256) void part_kernel(const int* __restrict__ ei,
                                                   int* __restrict__ cursor,
                                                   int* __restrict__ srcbuf,
                                                   unsigned short* __restrict__ dstlbuf) {
    __shared__ int cnt[NBUCK];
    __shared__ int cur[NBUCK];
    int t = threadIdx.x, blk = blockIdx.x;
    cnt[t] = 0;
    __syncthreads();
    int e0 = blk * CHUNK;
    for (int i = t; i < CHUNK; i += 256) {
        int e = e0 + i;
        if (e >= N_EDGES) break;
        unsigned d = (unsigned)ei[N_EDGES + e];
        atomicAdd(&cnt[__umulhi(d, MAGIC)], 1);
    }
    __syncthreads();
    cur[t] = atomicAdd(&cursor[t], cnt[t]);
    __syncthreads();
    for (int i = t; i < CHUNK; i += 256) {
        int e = e0 + i;
        if (e >= N_EDGES) break;
        unsigned d = (unsigned)ei[N_EDGES + e];
        int s = ei[e];
        int b = __umulhi(d, MAGIC);
        int pos = atomicAdd(&cur[b], 1);
        srcbuf[pos] = s;
        dstlbuf[pos] = (unsigned short)(d - b * NPB);
    }
}

// ---------------------------------------------------------------------------
// Bucket scatter aggregation: out[i] = feat[i] + sum_{s->i} feat[s].
// One block per (bucket, 32-dim half). LDS fp32 acc tile [NPB][33] (51.6 KB),
// initialized with self-features. Edge-parallel walk of the bucket's
// contiguous edge range: 4 lanes/edge load 16B each (64B/edge coalesced),
// 8 LDS float atomicAdds into the dst accumulator. No divergence, loop
// iterations independent -> deep load pipelining. Replaces refine+gather.
// ---------------------------------------------------------------------------
__global__ __launch_bounds__(256) void scatter_kernel(
    const unsigned short* __restrict__ feat,
    const int* __restrict__ base,
    const int* __restrict__ srcbuf,
    const unsigned short* __restrict__ dstlbuf,
    unsigned short* __restrict__ out) {
    __shared__ float accf[NPB * 33];   // 391*33*4 = 51.6 KB
    int t = threadIdx.x;
    int b = blockIdx.x >> 1;
    int half = blockIdx.x & 1;
    int n0 = b * NPB;
    int ql = t & 3, sg = t >> 2;       // 64 subgroups of 4 lanes
    const u16x8* f8 = (const u16x8*)feat;

    // init with self-features (dims half*32 + ql*8 .. +7)
    for (int nl = sg; nl < NPB; nl += 64) {
        int g = n0 + nl;
        if (g < N_NODES) {
            u16x8 sv = f8[(long long)g * 8 + half * 4 + ql];
            #pragma unroll
            for (int j = 0; j < 8; ++j) accf[nl * 33 + ql * 8 + j] = bf2f(sv[j]);
        }
    }
    __syncthreads();

    int beg = base[b], end = base[b + 1];
    for (int i = beg + sg; i < end; i += 64) {
        int src = srcbuf[i];
        int dl = dstlbuf[i];
        u16x8 v = f8[(long long)src * 8 + half * 4 + ql];
        #pragma unroll
        for (int j = 0; j < 8; ++j)
            atomicAdd(&accf[dl * 33 + ql * 8 + j], bf2f(v[j]));
    }
    __syncthreads();

    for (int nl = sg; nl < NPB; nl += 64) {
        int g = n0 + nl;
        if (g < N_NODES) {
            u16x8 o;
            #pragma unroll
            for (int j = 0; j < 8; ++j) o[j] = f2bf(accf[nl * 33 + ql * 8 + j]);
            ((u16x8*)out)[(long long)g * 8 + half * 4 + ql] = o;
        }
    }
}

// ---------------------------------------------------------------------------
// B-fragment loader: element j = W[(kt*32 + q*8 + j)][col]  (fp32 W -> bf16)
// ---------------------------------------------------------------------------
__device__ __forceinline__ bfx8 load_wfrag(const float* __restrict__ W, int kt, int q, int col) {
    bfx8 f;
    #pragma unroll
    for (int j = 0; j < 8; ++j)
        f[j] = (short)f2bf(W[(kt * 32 + q * 8 + j) * 64 + col]);
    return f;
}

// ---------------------------------------------------------------------------
// MFMA conv1 MLP: h2 = relu(relu(bn1(h0 @ W1a + b1a)) @ W1b + b1b)
// ---------------------------------------------------------------------------
__global__ __launch_bounds__(256) void mlp1_kernel(
    const unsigned short* __restrict__ h0,
    const float* __restrict__ W1a, const float* __restrict__ b1a,
    const float* __restrict__ g1,  const float* __restrict__ be1,
    const float* __restrict__ m1,  const float* __restrict__ v1,
    const float* __restrict__ W1b, const float* __restrict__ b1b,
    unsigned short* __restrict__ h2) {
    __shared__ unsigned short h1t[4][16 * 72];
    __shared__ unsigned short outt[4][16 * 64];

    int t = threadIdx.x;
    int w = t >> 6, lane = t & 63;
    int m = lane & 15, q = lane >> 4;
    int row0 = blockIdx.x * 64 + w * 16;

    bfx8 wa[4][2], wb[4][2];
    #pragma unroll
    for (int nt = 0; nt < 4; ++nt) {
        #pragma unroll
        for (int kt = 0; kt < 2; ++kt) {
            wa[nt][kt] = load_wfrag(W1a, kt, q, nt * 16 + m);
            wb[nt][kt] = load_wfrag(W1b, kt, q, nt * 16 + m);
        }
    }
    float A1[4], B1[4], B2c[4];
    #pragma unroll
    for (int nt = 0; nt < 4; ++nt) {
        int c = nt * 16 + m;
        float s = g1[c] * rsqrtf(v1[c] + BN_EPS);
        A1[nt] = s;
        B1[nt] = b1a[c] * s + (be1[c] - m1[c] * s);
        B2c[nt] = b1b[c];
    }

    int rowA = row0 + m;
    if (rowA > N_NODES - 1) rowA = N_NODES - 1;
    const bfx8* ap = (const bfx8*)(h0 + (long long)rowA * 64);
    bfx8 a0 = ap[q];
    bfx8 a1 = ap[4 + q];
    f32x4 acc[4];
    #pragma unroll
    for (int nt = 0; nt < 4; ++nt) {
        acc[nt] = (f32x4){0.f, 0.f, 0.f, 0.f};
        acc[nt] = __builtin_amdgcn_mfma_f32_16x16x32_bf16(a0, wa[nt][0], acc[nt], 0, 0, 0);
        acc[nt] = __builtin_amdgcn_mfma_f32_16x16x32_bf16(a1, wa[nt][1], acc[nt], 0, 0, 0);
    }
    #pragma unroll
    for (int nt = 0; nt < 4; ++nt)
        #pragma unroll
        for (int r = 0; r < 4; ++r) {
            float v = fmaxf(acc[nt][r] * A1[nt] + B1[nt], 0.f);
            h1t[w][(q * 4 + r) * 72 + nt * 16 + m] = f2bf(v);
        }
    __syncthreads();

    const bfx8* hp = (const bfx8*)&h1t[w][m * 72];
    bfx8 c0 = hp[q];
    bfx8 c1 = hp[4 + q];
    f32x4 acc2[4];
    #pragma unroll
    for (int nt = 0; nt < 4; ++nt) {
        acc2[nt] = (f32x4){0.f, 0.f, 0.f, 0.f};
        acc2[nt] = __builtin_amdgcn_mfma_f32_16x16x32_bf16(c0, wb[nt][0], acc2[nt], 0, 0, 0);
        acc2[nt] = __builtin_amdgcn_mfma_f32_16x16x32_bf16(c1, wb[nt][1], acc2[nt], 0, 0, 0);
    }
    #pragma unroll
    for (int nt = 0; nt < 4; ++nt)
        #pragma unroll
        for (int r = 0; r < 4; ++r) {
            float v = fmaxf(acc2[nt][r] + B2c[nt], 0.f);
            outt[w][(q * 4 + r) * 64 + nt * 16 + m] = f2bf(v);
        }
    __syncthreads();

    #pragma unroll
    for (int i = lane; i < 128; i += 64) {
        int rr = i >> 3, cc = i & 7;
        int rg = row0 + rr;
        if (rg < N_NODES)
            ((float4*)h2)[(long long)rg * 8 + cc] = *(const float4*)&outt[w][rr * 64 + cc * 8];
    }
}

// ---------------------------------------------------------------------------
// MFMA conv2 + pool: h4 = relu(bn2(h3 @ W2 + b2)); xs[batch[row]] += h4
// ---------------------------------------------------------------------------
__global__ __launch_bounds__(256) void mlp2_kernel(
    const unsigned short* __restrict__ h3,
    const float* __restrict__ W2, const float* __restrict__ b2,
    const float* __restrict__ g2, const float* __restrict__ be2,
    const float* __restrict__ m2, const float* __restrict__ v2,
    const int* __restrict__ batch,
    float* __restrict__ xs) {
    __shared__ float pool[64 * 64];
    __shared__ int bts[64];

    int t = threadIdx.x;
    int w = t >> 6, lane = t & 63;
    int m = lane & 15, q = lane >> 4;
    int row0b = blockIdx.x * 64;
    int row0 = row0b + w * 16;

    bfx8 wf[4][2];
    #pragma unroll
    for (int nt = 0; nt < 4; ++nt)
        #pragma unroll
        for (int kt = 0; kt < 2; ++kt)
            wf[nt][kt] = load_wfrag(W2, kt, q, nt * 16 + m);
    float A[4], Bc[4];
    #pragma unroll
    for (int nt = 0; nt < 4; ++nt) {
        int c = nt * 16 + m;
        float s = g2[c] * rsqrtf(v2[c] + BN_EPS);
        A[nt] = s;
        Bc[nt] = b2[c] * s + (be2[c] - m2[c] * s);
    }
    if (t < 64) {
        int rg = row0b + t;
        bts[t] = (rg < N_NODES) ? batch[rg] : -1;
    }

    int rowA = row0 + m;
    if (rowA > N_NODES - 1) rowA = N_NODES - 1;
    const bfx8* ap = (const bfx8*)(h3 + (long long)rowA * 64);
    bfx8 a0 = ap[q];
    bfx8 a1 = ap[4 + q];
    f32x4 acc[4];
    #pragma unroll
    for (int nt = 0; nt < 4; ++nt) {
        acc[nt] = (f32x4){0.f, 0.f, 0.f, 0.f};
        acc[nt] = __builtin_amdgcn_mfma_f32_16x16x32_bf16(a0, wf[nt][0], acc[nt], 0, 0, 0);
        acc[nt] = __builtin_amdgcn_mfma_f32_16x16x32_bf16(a1, wf[nt][1], acc[nt], 0, 0, 0);
    }
    #pragma unroll
    for (int nt = 0; nt < 4; ++nt)
        #pragma unroll
        for (int r = 0; r < 4; ++r) {
            float v = fmaxf(acc[nt][r] * A[nt] + Bc[nt], 0.f);
            pool[(w * 16 + q * 4 + r) * 64 + nt * 16 + m] = v;
        }
    __syncthreads();

    int col = t & 63;
    int r0 = (t >> 6) * 16;
    int cb = bts[r0];
    float cur = 0.f;
    #pragma unroll
    for (int r = 0; r < 16; ++r) {
        int b = bts[r0 + r];
        if (b != cb) {
            if (cb >= 0) unsafeAtomicAdd(&xs[cb * 64 + col], cur);
            cb = b;
            cur = 0.f;
        }
        cur += pool[(r0 + r) * 64 + col];
    }
    if (cb >= 0) unsafeAtomicAdd(&xs[cb * 64 + col], cur);
}

// ---------------------------------------------------------------------------
// Head: x_topo = relu(topo @ Wt + bt); out = [x_struct, x_topo] @ Wc + bc
// ---------------------------------------------------------------------------
__global__ __launch_bounds__(64) void head_kernel(
    const float* __restrict__ xs, const float* __restrict__ topo,
    const float* __restrict__ Wt, const float* __restrict__ bt,
    const float* __restrict__ Wc, const float* __restrict__ bc,
    float* __restrict__ out) {
    __shared__ float trow[64];
    __shared__ float comb[128];
    int b = blockIdx.x;
    int h = threadIdx.x;
    trow[h] = topo[b * 64 + h];
    __syncthreads();
    float acc = bt[h];
    #pragma unroll
    for (int k = 0; k < 64; ++k) acc += trow[k] * Wt[k * 64 + h];
    comb[h] = xs[b * 64 + h];
    comb[64 + h] = fmaxf(acc, 0.f);
    __syncthreads();
    if (h < NCLASS) {
        float o = bc[h];
        #pragma unroll
        for (int k = 0; k < 128; ++k) o += comb[k] * Wc[k * NCLASS + h];
        out[b * NCLASS + h] = o;
    }
}

// ---------------------------------------------------------------------------
extern "C" void kernel_launch(void* const* d_in, const int* in_sizes, int n_in,
                              void* d_out, int out_size, void* d_ws, size_t ws_size,
                              hipStream_t stream) {
    const float* x     = (const float*)d_in[0];
    const int*   ei    = (const int*)d_in[1];
    const int*   batch = (const int*)d_in[2];
    const float* topo  = (const float*)d_in[3];
    const float* W1a   = (const float*)d_in[4];
    const float* b1a   = (const float*)d_in[5];
    const float* g1    = (const float*)d_in[6];
    const float* be1   = (const float*)d_in[7];
    const float* m1    = (const float*)d_in[8];
    const float* v1    = (const float*)d_in[9];
    const float* W1b   = (const float*)d_in[10];
    const float* b1b   = (const float*)d_in[11];
    const float* W2    = (const float*)d_in[12];
    const float* b2    = (const float*)d_in[13];
    const float* g2    = (const float*)d_in[14];
    const float* be2   = (const float*)d_in[15];
    const float* m2    = (const float*)d_in[16];
    const float* v2    = (const float*)d_in[17];
    const float* Wt    = (const float*)d_in[18];
    const float* bt    = (const float*)d_in[19];
    const float* Wc    = (const float*)d_in[20];
    const float* bc    = (const float*)d_in[21];
    float* out = (float*)d_out;

    // Workspace layout (16B-aligned chunks)
    char* p = (char*)d_ws;
    unsigned short* xbf  = (unsigned short*)p; p += (size_t)N_NODES * DIM * 2;  // 12.8 MB
    unsigned short* bufA = (unsigned short*)p; p += (size_t)N_NODES * DIM * 2;  // 12.8 MB
    unsigned short* bufB = (unsigned short*)p; p += (size_t)N_NODES * DIM * 2;  // 12.8 MB
    float* xs      = (float*)p; p += (size_t)BGRAPHS * DIM * 4;                 // 256 KB
    int*   gpart   = (int*)p;   p += (size_t)NBLK_P * NBUCK * 4;                // 150 KB
    int*   base    = (int*)p;   p += 1040;                                      // 257 ints (16B-aligned slot)
    int*   cursor  = (int*)p;   p += 1024;                                      // 256 ints
    int*   srcbuf  = (int*)p;   p += (size_t)N_EDGES * 4;                       // 4.8 MB
    unsigned short* dstlbuf = (unsigned short*)p;                               // 2.4 MB

    // 1) convert + per-chunk bucket histogram (independent work, one launch)
    convhist_kernel<<<NBLK_P + NB_C, 256, 0, stream>>>(x, xbf, xs, ei, gpart);
    // 2) bucket totals -> exclusive scan -> base/cursor
    scanB_kernel<<<1, 256, 0, stream>>>(gpart, base, cursor);
    // 3) partition edges into bucket regions (chunk reservation, arbitrary order)
    part_kernel<<<NBLK_P, 256, 0, stream>>>(ei, cursor, srcbuf, dstlbuf);
    // 4) agg1: bufA = xbf + scatter(xbf)   (bucket scatter, 2 blocks/bucket)
    scatter_kernel<<<NBUCK * 2, 256, 0, stream>>>(xbf, base, srcbuf, dstlbuf, bufA);
    // 5) conv1 MLP (MFMA): bufB = h2 (bf16)
    mlp1_kernel<<<(N_NODES + 63) / 64, 256, 0, stream>>>(
        bufA, W1a, b1a, g1, be1, m1, v1, W1b, b1b, bufB);
    // 6) agg2: bufA = h2 + scatter(h2)
    scatter_kernel<<<NBUCK * 2, 256, 0, stream>>>(bufB, base, srcbuf, dstlbuf, bufA);
    // 7) conv2 + pool (MFMA)
    mlp2_kernel<<<(N_NODES + 63) / 64, 256, 0, stream>>>(
        bufA, W2, b2, g2, be2, m2, v2, batch, xs);
    // 8) head
    head_kernel<<<BGRAPHS, 64, 0, stream>>>(xs, topo, Wt, bt, Wc, bc, out);
}

// Round 6
// 246.917 us; speedup vs baseline: 3.9533x; 3.9533x over previous
//
#include <hip/hip_runtime.h>

// Problem constants (match reference)
#define N_NODES 100000
#define N_EDGES 1200000
#define DIM     64
#define BGRAPHS 1000
#define NCLASS  10
#define BN_EPS  1e-5f

// CSR-build partition constants
#define NBUCK   256            // coarse buckets
#define NPB     391            // nodes per bucket (256*391 = 100096 >= N)
#define MAGIC   10984572u      // ceil(2^32/391): bucket = umulhi(d, MAGIC)
#define CHUNK   8192           // edges per partition block
#define NBLK_P  147            // ceil(E / CHUNK)
#define CAP     8192           // refine LDS staging capacity (>= max bucket edges)
#define NB_C    3125           // N*DIM/8/256 convert blocks

typedef __attribute__((ext_vector_type(8))) short   bfx8;   // 8 bf16 MFMA A/B frag
typedef __attribute__((ext_vector_type(4))) float   f32x4;  // MFMA C/D frag
typedef __attribute__((ext_vector_type(8))) unsigned short u16x8;

__device__ __forceinline__ unsigned short f2bf(float f) {
    unsigned u = __builtin_bit_cast(unsigned, f);
    unsigned r = (u + 0x7FFFu + ((u >> 16) & 1u)) >> 16;   // RNE
    return (unsigned short)r;
}
__device__ __forceinline__ float bf2f(unsigned short h) {
    unsigned u = ((unsigned)h) << 16;
    return __builtin_bit_cast(float, u);
}

// ---------------------------------------------------------------------------
// Kernel A (merged):
//   blocks [0,NBLK_P)              : per-chunk bucket histogram partials
//   blocks [NBLK_P, NBLK_P+NB_C)   : fp32->bf16 convert of x + zero xs
//   block  NBLK_P+NB_C             : weight prep — permute W1a/W1b/W2 into
//     fragment-ordered bf16: wp[((kt*4+q)*64+col)*8 + j] = bf16(W[(kt*32+q*8+j)*64+col])
// ---------------------------------------------------------------------------
__global__ __launch_bounds__(256) void convhist_kernel(
    const float* __restrict__ x, unsigned short* __restrict__ xb,
    float* __restrict__ xs, const int* __restrict__ ei,
    int* __restrict__ gpart,
    const float* __restrict__ W1a, const float* __restrict__ W1b,
    const float* __restrict__ W2,
    unsigned short* __restrict__ w1ap, unsigned short* __restrict__ w1bp,
    unsigned short* __restrict__ w2p) {
    __shared__ int cnt[NBUCK];
    int t = threadIdx.x;
    if (blockIdx.x < NBLK_P) {
        int blk = blockIdx.x;
        cnt[t] = 0;
        __syncthreads();
        int e0 = blk * CHUNK;
        for (int i = t; i < CHUNK; i += 256) {
            int e = e0 + i;
            if (e >= N_EDGES) break;
            unsigned d = (unsigned)ei[N_EDGES + e];
            atomicAdd(&cnt[__umulhi(d, MAGIC)], 1);
        }
        __syncthreads();
        gpart[blk * NBUCK + t] = cnt[t];
    } else if (blockIdx.x < NBLK_P + NB_C) {
        int i = (blockIdx.x - NBLK_P) * 256 + t;
        const int n8 = N_NODES * DIM / 8;
        if (i < n8) {
            float4 a = ((const float4*)x)[i * 2];
            float4 b = ((const float4*)x)[i * 2 + 1];
            u16x8 o;
            o[0] = f2bf(a.x); o[1] = f2bf(a.y); o[2] = f2bf(a.z); o[3] = f2bf(a.w);
            o[4] = f2bf(b.x); o[5] = f2bf(b.y); o[6] = f2bf(b.z); o[7] = f2bf(b.w);
            ((u16x8*)xb)[i] = o;
        }
        if (i < BGRAPHS * DIM) xs[i] = 0.f;
    } else {
        // weight prep: 512 fragment-entries per weight, 2 per thread per weight
        const float* Ws[3] = {W1a, W1b, W2};
        unsigned short* Wp[3] = {w1ap, w1bp, w2p};
        #pragma unroll
        for (int wsel = 0; wsel < 3; ++wsel) {
            const float* W = Ws[wsel];
            #pragma unroll
            for (int r = 0; r < 2; ++r) {
                int e = r * 256 + t;           // 0..511
                int kt = e >> 8, q = (e >> 6) & 3, col = e & 63;
                u16x8 o;
                #pragma unroll
                for (int j = 0; j < 8; ++j)
                    o[j] = f2bf(W[(kt * 32 + q * 8 + j) * 64 + col]);
                ((u16x8*)Wp[wsel])[e] = o;
            }
        }
    }
}

// ---------------------------------------------------------------------------
// Single-block scan: reduce 147 partials per bucket, exclusive-scan 256
// totals -> base[257]; init cursor = base for part's chunk reservation.
// ---------------------------------------------------------------------------
__global__ __launch_bounds__(256) void scanB_kernel(const int* __restrict__ gpart,
                                                    int* __restrict__ base,
                                                    int* __restrict__ cursor) {
    __shared__ int tmp[256];
    int t = threadIdx.x;
    int s = 0;
    for (int blk = 0; blk < NBLK_P; ++blk) s += gpart[blk * NBUCK + t];
    tmp[t] = s;
    __syncthreads();
    for (int off = 1; off < 256; off <<= 1) {
        int a = (t >= off) ? tmp[t - off] : 0;
        __syncthreads();
        tmp[t] += a;
        __syncthreads();
    }
    int excl = tmp[t] - s;
    base[t] = excl;
    cursor[t] = excl;
    if (t == 255) base[256] = N_EDGES;
}

// ---------------------------------------------------------------------------
// Partition: per-block LDS count, reserve per-bucket chunk with ONE global
// atomicAdd per (block,bucket), then place edges.
// ---------------------------------------------------------------------------
__global__ __launch_bounds__(256) void part_kernel(const int* __restrict__ ei,
                                                   int* __restrict__ cursor,
                                                   int* __restrict__ srcbuf,
                                                   unsigned short* __restrict__ dstlbuf) {
    __shared__ int cnt[NBUCK];
    __shared__ int cur[NBUCK];
    int t = threadIdx.x, blk = blockIdx.x;
    cnt[t] = 0;
    __syncthreads();
    int e0 = blk * CHUNK;
    for (int i = t; i < CHUNK; i += 256) {
        int e = e0 + i;
        if (e >= N_EDGES) break;
        unsigned d = (unsigned)ei[N_EDGES + e];
        atomicAdd(&cnt[__umulhi(d, MAGIC)], 1);
    }
    __syncthreads();
    cur[t] = atomicAdd(&cursor[t], cnt[t]);
    __syncthreads();
    for (int i = t; i < CHUNK; i += 256) {
        int e = e0 + i;
        if (e >= N_EDGES) break;
        unsigned d = (unsigned)ei[N_EDGES + e];
        int s = ei[e];
        int b = __umulhi(d, MAGIC);
        int pos = atomicAdd(&cur[b], 1);
        srcbuf[pos] = s;
        dstlbuf[pos] = (unsigned short)(d - b * NPB);
    }
}

// ---------------------------------------------------------------------------
// Refine: one block per bucket; LDS counting sort by dst_local; coalesced
// csr_src write; emits rowptr from the local exclusive scan.
// ---------------------------------------------------------------------------
__global__ __launch_bounds__(256) void refine_kernel(const int* __restrict__ srcbuf,
                                                     const unsigned short* __restrict__ dstlbuf,
                                                     const int* __restrict__ base,
                                                     int* __restrict__ csr_src,
                                                     int* __restrict__ rowptr) {
    __shared__ int cnt[NPB + 1];
    __shared__ int cur[NPB + 1];
    __shared__ int tmp[256];
    __shared__ int outb[CAP];
    int t = threadIdx.x, b = blockIdx.x;
    int beg = base[b];
    int end = base[b + 1];

    for (int i = t; i < NPB + 1; i += 256) cnt[i] = 0;
    __syncthreads();
    for (int i = beg + t; i < end; i += 256)
        atomicAdd(&cnt[dstlbuf[i]], 1);
    __syncthreads();

    // exclusive scan over NPB entries (2 elems/thread)
    int i0 = 2 * t, i1 = 2 * t + 1;
    int v0 = (i0 < NPB) ? cnt[i0] : 0;
    int v1 = (i1 < NPB) ? cnt[i1] : 0;
    int s = v0 + v1;
    tmp[t] = s;
    __syncthreads();
    for (int off = 1; off < 256; off <<= 1) {
        int a = (t >= off) ? tmp[t - off] : 0;
        __syncthreads();
        tmp[t] += a;
        __syncthreads();
    }
    int excl = tmp[t] - s;
    if (i0 < NPB) cur[i0] = excl;
    if (i1 < NPB) cur[i1] = excl + v0;
    {
        int g0 = b * NPB + i0;
        if (i0 < NPB && g0 < N_NODES) rowptr[g0] = beg + excl;
        int g1 = b * NPB + i1;
        if (i1 < NPB && g1 < N_NODES) rowptr[g1] = beg + excl + v0;
    }
    if (b == NBUCK - 1 && t == 0) rowptr[N_NODES] = N_EDGES;
    __syncthreads();

    for (int i = beg + t; i < end; i += 256) {
        int dl = dstlbuf[i];
        int pos = atomicAdd(&cur[dl], 1);
        if (pos < CAP) outb[pos] = srcbuf[i];
    }
    __syncthreads();

    int nb = end - beg; if (nb > CAP) nb = CAP;
    for (int i = t; i < nb; i += 256) csr_src[beg + i] = outb[i];
}

// ---------------------------------------------------------------------------
// bf16 gather aggregation (round-0 proven version): out[i] = feat[i] + sum.
// 8 lanes per node (16B/lane), 32 nodes per 256-thread block, 1-deep prefetch.
// ---------------------------------------------------------------------------
__global__ __launch_bounds__(256) void gather_kernel(const unsigned short* __restrict__ feat,
                                                     const int* __restrict__ rowptr,
                                                     const int* __restrict__ csr_src,
                                                     unsigned short* __restrict__ out) {
    int t = threadIdx.x;
    int node = blockIdx.x * 32 + (t >> 3);
    int q = t & 7;
    if (node >= N_NODES) return;
    const u16x8* f8 = (const u16x8*)feat;
    u16x8 sv = f8[(long long)node * 8 + q];
    float acc[8];
    #pragma unroll
    for (int j = 0; j < 8; ++j) acc[j] = bf2f(sv[j]);
    int beg = rowptr[node], end = rowptr[node + 1];
    int k = beg;
    int sn = (k < end) ? csr_src[k] : 0;
    while (k < end) {
        int sc = sn;
        ++k;
        if (k < end) sn = csr_src[k];
        u16x8 v = f8[(long long)sc * 8 + q];
        #pragma unroll
        for (int j = 0; j < 8; ++j) acc[j] += bf2f(v[j]);
    }
    u16x8 o;
    #pragma unroll
    for (int j = 0; j < 8; ++j) o[j] = f2bf(acc[j]);
    ((u16x8*)out)[(long long)node * 8 + q] = o;
}

// ---------------------------------------------------------------------------
// MFMA conv1 MLP: h2 = relu(relu(bn1(h0 @ W1a + b1a)) @ W1b + b1b)
// Weights pre-permuted bf16: fragment = one 16B vector load.
// ---------------------------------------------------------------------------
__global__ __launch_bounds__(256) void mlp1_kernel(
    const unsigned short* __restrict__ h0,
    const unsigned short* __restrict__ w1ap, const float* __restrict__ b1a,
    const float* __restrict__ g1,  const float* __restrict__ be1,
    const float* __restrict__ m1,  const float* __restrict__ v1,
    const unsigned short* __restrict__ w1bp, const float* __restrict__ b1b,
    unsigned short* __restrict__ h2) {
    __shared__ unsigned short h1t[4][16 * 72];
    __shared__ unsigned short outt[4][16 * 64];

    int t = threadIdx.x;
    int w = t >> 6, lane = t & 63;
    int m = lane & 15, q = lane >> 4;
    int row0 = blockIdx.x * 64 + w * 16;

    const bfx8* wap = (const bfx8*)w1ap;
    const bfx8* wbp = (const bfx8*)w1bp;
    bfx8 wa[4][2], wb[4][2];
    #pragma unroll
    for (int nt = 0; nt < 4; ++nt) {
        #pragma unroll
        for (int kt = 0; kt < 2; ++kt) {
            int idx = (kt * 4 + q) * 64 + nt * 16 + m;
            wa[nt][kt] = wap[idx];
            wb[nt][kt] = wbp[idx];
        }
    }
    float A1[4], B1[4], B2c[4];
    #pragma unroll
    for (int nt = 0; nt < 4; ++nt) {
        int c = nt * 16 + m;
        float s = g1[c] * rsqrtf(v1[c] + BN_EPS);
        A1[nt] = s;
        B1[nt] = b1a[c] * s + (be1[c] - m1[c] * s);
        B2c[nt] = b1b[c];
    }

    int rowA = row0 + m;
    if (rowA > N_NODES - 1) rowA = N_NODES - 1;
    const bfx8* ap = (const bfx8*)(h0 + (long long)rowA * 64);
    bfx8 a0 = ap[q];
    bfx8 a1 = ap[4 + q];
    f32x4 acc[4];
    #pragma unroll
    for (int nt = 0; nt < 4; ++nt) {
        acc[nt] = (f32x4){0.f, 0.f, 0.f, 0.f};
        acc[nt] = __builtin_amdgcn_mfma_f32_16x16x32_bf16(a0, wa[nt][0], acc[nt], 0, 0, 0);
        acc[nt] = __builtin_amdgcn_mfma_f32_16x16x32_bf16(a1, wa[nt][1], acc[nt], 0, 0, 0);
    }
    #pragma unroll
    for (int nt = 0; nt < 4; ++nt)
        #pragma unroll
        for (int r = 0; r < 4; ++r) {
            float v = fmaxf(acc[nt][r] * A1[nt] + B1[nt], 0.f);
            h1t[w][(q * 4 + r) * 72 + nt * 16 + m] = f2bf(v);
        }
    __syncthreads();

    const bfx8* hp = (const bfx8*)&h1t[w][m * 72];
    bfx8 c0 = hp[q];
    bfx8 c1 = hp[4 + q];
    f32x4 acc2[4];
    #pragma unroll
    for (int nt = 0; nt < 4; ++nt) {
        acc2[nt] = (f32x4){0.f, 0.f, 0.f, 0.f};
        acc2[nt] = __builtin_amdgcn_mfma_f32_16x16x32_bf16(c0, wb[nt][0], acc2[nt], 0, 0, 0);
        acc2[nt] = __builtin_amdgcn_mfma_f32_16x16x32_bf16(c1, wb[nt][1], acc2[nt], 0, 0, 0);
    }
    #pragma unroll
    for (int nt = 0; nt < 4; ++nt)
        #pragma unroll
        for (int r = 0; r < 4; ++r) {
            float v = fmaxf(acc2[nt][r] + B2c[nt], 0.f);
            outt[w][(q * 4 + r) * 64 + nt * 16 + m] = f2bf(v);
        }
    __syncthreads();

    #pragma unroll
    for (int i = lane; i < 128; i += 64) {
        int rr = i >> 3, cc = i & 7;
        int rg = row0 + rr;
        if (rg < N_NODES)
            ((float4*)h2)[(long long)rg * 8 + cc] = *(const float4*)&outt[w][rr * 64 + cc * 8];
    }
}

// ---------------------------------------------------------------------------
// MFMA conv2 + pool: h4 = relu(bn2(h3 @ W2 + b2)); xs[batch[row]] += h4
// ---------------------------------------------------------------------------
__global__ __launch_bounds__(256) void mlp2_kernel(
    const unsigned short* __restrict__ h3,
    const unsigned short* __restrict__ w2p, const float* __restrict__ b2,
    const float* __restrict__ g2, const float* __restrict__ be2,
    const float* __restrict__ m2, const float* __restrict__ v2,
    const int* __restrict__ batch,
    float* __restrict__ xs) {
    __shared__ float pool[64 * 64];
    __shared__ int bts[64];

    int t = threadIdx.x;
    int w = t >> 6, lane = t & 63;
    int m = lane & 15, q = lane >> 4;
    int row0b = blockIdx.x * 64;
    int row0 = row0b + w * 16;

    const bfx8* wpp = (const bfx8*)w2p;
    bfx8 wf[4][2];
    #pragma unroll
    for (int nt = 0; nt < 4; ++nt)
        #pragma unroll
        for (int kt = 0; kt < 2; ++kt)
            wf[nt][kt] = wpp[(kt * 4 + q) * 64 + nt * 16 + m];
    float A[4], Bc[4];
    #pragma unroll
    for (int nt = 0; nt < 4; ++nt) {
        int c = nt * 16 + m;
        float s = g2[c] * rsqrtf(v2[c] + BN_EPS);
        A[nt] = s;
        Bc[nt] = b2[c] * s + (be2[c] - m2[c] * s);
    }
    if (t < 64) {
        int rg = row0b + t;
        bts[t] = (rg < N_NODES) ? batch[rg] : -1;
    }

    int rowA = row0 + m;
    if (rowA > N_NODES - 1) rowA = N_NODES - 1;
    const bfx8* ap = (const bfx8*)(h3 + (long long)rowA * 64);
    bfx8 a0 = ap[q];
    bfx8 a1 = ap[4 + q];
    f32x4 acc[4];
    #pragma unroll
    for (int nt = 0; nt < 4; ++nt) {
        acc[nt] = (f32x4){0.f, 0.f, 0.f, 0.f};
        acc[nt] = __builtin_amdgcn_mfma_f32_16x16x32_bf16(a0, wf[nt][0], acc[nt], 0, 0, 0);
        acc[nt] = __builtin_amdgcn_mfma_f32_16x16x32_bf16(a1, wf[nt][1], acc[nt], 0, 0, 0);
    }
    #pragma unroll
    for (int nt = 0; nt < 4; ++nt)
        #pragma unroll
        for (int r = 0; r < 4; ++r) {
            float v = fmaxf(acc[nt][r] * A[nt] + Bc[nt], 0.f);
            pool[(w * 16 + q * 4 + r) * 64 + nt * 16 + m] = v;
        }
    __syncthreads();

    int col = t & 63;
    int r0 = (t >> 6) * 16;
    int cb = bts[r0];
    float cur = 0.f;
    #pragma unroll
    for (int r = 0; r < 16; ++r) {
        int b = bts[r0 + r];
        if (b != cb) {
            if (cb >= 0) unsafeAtomicAdd(&xs[cb * 64 + col], cur);
            cb = b;
            cur = 0.f;
        }
        cur += pool[(r0 + r) * 64 + col];
    }
    if (cb >= 0) unsafeAtomicAdd(&xs[cb * 64 + col], cur);
}

// ---------------------------------------------------------------------------
// Head: x_topo = relu(topo @ Wt + bt); out = [x_struct, x_topo] @ Wc + bc
// ---------------------------------------------------------------------------
__global__ __launch_bounds__(64) void head_kernel(
    const float* __restrict__ xs, const float* __restrict__ topo,
    const float* __restrict__ Wt, const float* __restrict__ bt,
    const float* __restrict__ Wc, const float* __restrict__ bc,
    float* __restrict__ out) {
    __shared__ float trow[64];
    __shared__ float comb[128];
    int b = blockIdx.x;
    int h = threadIdx.x;
    trow[h] = topo[b * 64 + h];
    __syncthreads();
    float acc = bt[h];
    #pragma unroll
    for (int k = 0; k < 64; ++k) acc += trow[k] * Wt[k * 64 + h];
    comb[h] = xs[b * 64 + h];
    comb[64 + h] = fmaxf(acc, 0.f);
    __syncthreads();
    if (h < NCLASS) {
        float o = bc[h];
        #pragma unroll
        for (int k = 0; k < 128; ++k) o += comb[k] * Wc[k * NCLASS + h];
        out[b * NCLASS + h] = o;
    }
}

// ---------------------------------------------------------------------------
extern "C" void kernel_launch(void* const* d_in, const int* in_sizes, int n_in,
                              void* d_out, int out_size, void* d_ws, size_t ws_size,
                              hipStream_t stream) {
    const float* x     = (const float*)d_in[0];
    const int*   ei    = (const int*)d_in[1];
    const int*   batch = (const int*)d_in[2];
    const float* topo  = (const float*)d_in[3];
    const float* W1a   = (const float*)d_in[4];
    const float* b1a   = (const float*)d_in[5];
    const float* g1    = (const float*)d_in[6];
    const float* be1   = (const float*)d_in[7];
    const float* m1    = (const float*)d_in[8];
    const float* v1    = (const float*)d_in[9];
    const float* W1b   = (const float*)d_in[10];
    const float* b1b   = (const float*)d_in[11];
    const float* W2    = (const float*)d_in[12];
    const float* b2    = (const float*)d_in[13];
    const float* g2    = (const float*)d_in[14];
    const float* be2   = (const float*)d_in[15];
    const float* m2    = (const float*)d_in[16];
    const float* v2    = (const float*)d_in[17];
    const float* Wt    = (const float*)d_in[18];
    const float* bt    = (const float*)d_in[19];
    const float* Wc    = (const float*)d_in[20];
    const float* bc    = (const float*)d_in[21];
    float* out = (float*)d_out;

    // Workspace layout (16B-aligned chunks)
    char* p = (char*)d_ws;
    unsigned short* xbf  = (unsigned short*)p; p += (size_t)N_NODES * DIM * 2;  // 12.8 MB
    unsigned short* bufA = (unsigned short*)p; p += (size_t)N_NODES * DIM * 2;  // 12.8 MB
    unsigned short* bufB = (unsigned short*)p; p += (size_t)N_NODES * DIM * 2;  // 12.8 MB
    float* xs      = (float*)p; p += (size_t)BGRAPHS * DIM * 4;                 // 256 KB
    int*   rowptr  = (int*)p;   p += (size_t)(N_NODES + 16) * 4;                // 400 KB
    int*   gpart   = (int*)p;   p += (size_t)NBLK_P * NBUCK * 4;                // 150 KB
    int*   base    = (int*)p;   p += 1040;                                      // 257 ints (16B-aligned slot)
    int*   cursor  = (int*)p;   p += 1024;                                      // 256 ints
    unsigned short* w1ap = (unsigned short*)p; p += 512 * 16;                   // 8 KB
    unsigned short* w1bp = (unsigned short*)p; p += 512 * 16;                   // 8 KB
    unsigned short* w2p  = (unsigned short*)p; p += 512 * 16;                   // 8 KB
    int*   srcbuf  = (int*)p;   p += (size_t)N_EDGES * 4;                       // 4.8 MB
    unsigned short* dstlbuf = (unsigned short*)p; p += (size_t)N_EDGES * 2;     // 2.4 MB
    int*   csr_src = (int*)p;                                                   // 4.8 MB

    // 1) convert + hist partials + weight prep (one launch)
    convhist_kernel<<<NBLK_P + NB_C + 1, 256, 0, stream>>>(
        x, xbf, xs, ei, gpart, W1a, W1b, W2, w1ap, w1bp, w2p);
    // 2) bucket totals -> exclusive scan -> base/cursor
    scanB_kernel<<<1, 256, 0, stream>>>(gpart, base, cursor);
    // 3) partition edges into bucket regions
    part_kernel<<<NBLK_P, 256, 0, stream>>>(ei, cursor, srcbuf, dstlbuf);
    // 4) per-bucket counting sort -> csr_src + rowptr
    refine_kernel<<<NBUCK, 256, 0, stream>>>(srcbuf, dstlbuf, base, csr_src, rowptr);
    // 5) agg1: bufA = xbf + scatter(xbf)
    gather_kernel<<<(N_NODES + 31) / 32, 256, 0, stream>>>(xbf, rowptr, csr_src, bufA);
    // 6) conv1 MLP (MFMA, prepped weights): bufB = h2 (bf16)
    mlp1_kernel<<<(N_NODES + 63) / 64, 256, 0, stream>>>(
        bufA, w1ap, b1a, g1, be1, m1, v1, w1bp, b1b, bufB);
    // 7) agg2: bufA = h2 + scatter(h2)
    gather_kernel<<<(N_NODES + 31) / 32, 256, 0, stream>>>(bufB, rowptr, csr_src, bufA);
    // 8) conv2 + pool (MFMA, prepped weights)
    mlp2_kernel<<<(N_NODES + 63) / 64, 256, 0, stream>>>(
        bufA, w2p, b2, g2, be2, m2, v2, batch, xs);
    // 9) head
    head_kernel<<<BGRAPHS, 64, 0, stream>>>(xs, topo, Wt, bt, Wc, bc, out);
}

// Round 7
// 238.271 us; speedup vs baseline: 4.0967x; 1.0363x over previous
//
#include <hip/hip_runtime.h>

// Problem constants (match reference)
#define N_NODES 100000
#define N_EDGES 1200000
#define DIM     64
#define BGRAPHS 1000
#define NCLASS  10
#define BN_EPS  1e-5f

// CSR-build partition constants
#define NBUCK   256            // coarse buckets
#define NPB     391            // nodes per bucket (256*391 = 100096 >= N)
#define MAGIC   10984572u      // ceil(2^32/391): bucket = umulhi(d, MAGIC)
#define CHUNK   8192           // edges per partition block
#define NBLK_P  147            // ceil(E / CHUNK)
#define CAP     8192           // refine LDS staging capacity (>= max bucket edges)
#define NB_G    1563           // ceil(N/64) GEMM blocks in prep

typedef __attribute__((ext_vector_type(8))) short   bfx8;   // 8 bf16 MFMA A/B frag
typedef __attribute__((ext_vector_type(4))) float   f32x4;  // MFMA C/D frag
typedef __attribute__((ext_vector_type(8))) unsigned short u16x8;

__device__ __forceinline__ unsigned short f2bf(float f) {
    unsigned u = __builtin_bit_cast(unsigned, f);
    unsigned r = (u + 0x7FFFu + ((u >> 16) & 1u)) >> 16;   // RNE
    return (unsigned short)r;
}
__device__ __forceinline__ float bf2f(unsigned short h) {
    unsigned u = ((unsigned)h) << 16;
    return __builtin_bit_cast(float, u);
}

// B-fragment loader: element j = W[(kt*32 + q*8 + j)][col]  (fp32 W -> bf16)
__device__ __forceinline__ bfx8 load_wfrag(const float* __restrict__ W, int kt, int q, int col) {
    bfx8 f;
    #pragma unroll
    for (int j = 0; j < 8; ++j)
        f[j] = (short)f2bf(W[(kt * 32 + q * 8 + j) * 64 + col]);
    return f;
}

// ---------------------------------------------------------------------------
// Prep kernel (merged):
//   blocks [0,NBLK_P)           : per-chunk bucket histogram partials
//   blocks [NBLK_P,NBLK_P+NB_G) : y0 = bf16(x) @ bf16(W1a)  (agg commutes with
//                                 right-mult: agg(x)@W1a == agg(x@W1a)); also
//                                 zeros xs.
//   block  NBLK_P+NB_G          : fragment-prep W1b/W2 + BN affine constants
//                                 AB = [A1|B1|A2|B2] (4x64 fp32)
// ---------------------------------------------------------------------------
__global__ __launch_bounds__(256) void prep_kernel(
    const float* __restrict__ x, const int* __restrict__ ei,
    int* __restrict__ gpart,
    const float* __restrict__ W1a, unsigned short* __restrict__ y0,
    float* __restrict__ xs,
    const float* __restrict__ W1b, const float* __restrict__ W2,
    unsigned short* __restrict__ w1bp, unsigned short* __restrict__ w2p,
    const float* __restrict__ b1a, const float* __restrict__ g1,
    const float* __restrict__ be1, const float* __restrict__ m1,
    const float* __restrict__ v1,
    const float* __restrict__ b2,  const float* __restrict__ g2,
    const float* __restrict__ be2, const float* __restrict__ m2,
    const float* __restrict__ v2,
    float* __restrict__ AB) {
    __shared__ int cnt[NBUCK];
    __shared__ unsigned short outt[4][16 * 64];
    int t = threadIdx.x;
    if (blockIdx.x < NBLK_P) {
        int blk = blockIdx.x;
        cnt[t] = 0;
        __syncthreads();
        int e0 = blk * CHUNK;
        for (int i = t; i < CHUNK; i += 256) {
            int e = e0 + i;
            if (e >= N_EDGES) break;
            unsigned d = (unsigned)ei[N_EDGES + e];
            atomicAdd(&cnt[__umulhi(d, MAGIC)], 1);
        }
        __syncthreads();
        gpart[blk * NBUCK + t] = cnt[t];
    } else if (blockIdx.x < NBLK_P + NB_G) {
        int g = blockIdx.x - NBLK_P;
        if (g < (BGRAPHS * DIM) / 256) xs[g * 256 + t] = 0.f;
        int w = t >> 6, lane = t & 63;
        int m = lane & 15, q = lane >> 4;
        int row0 = g * 64 + w * 16;

        bfx8 wa[4][2];
        #pragma unroll
        for (int nt = 0; nt < 4; ++nt)
            #pragma unroll
            for (int kt = 0; kt < 2; ++kt)
                wa[nt][kt] = load_wfrag(W1a, kt, q, nt * 16 + m);

        int rowA = row0 + m;
        if (rowA > N_NODES - 1) rowA = N_NODES - 1;
        const float* xp = x + (long long)rowA * 64;
        bfx8 a0, a1;
        #pragma unroll
        for (int j = 0; j < 8; ++j) {
            a0[j] = (short)f2bf(xp[q * 8 + j]);
            a1[j] = (short)f2bf(xp[32 + q * 8 + j]);
        }
        f32x4 acc[4];
        #pragma unroll
        for (int nt = 0; nt < 4; ++nt) {
            acc[nt] = (f32x4){0.f, 0.f, 0.f, 0.f};
            acc[nt] = __builtin_amdgcn_mfma_f32_16x16x32_bf16(a0, wa[nt][0], acc[nt], 0, 0, 0);
            acc[nt] = __builtin_amdgcn_mfma_f32_16x16x32_bf16(a1, wa[nt][1], acc[nt], 0, 0, 0);
        }
        #pragma unroll
        for (int nt = 0; nt < 4; ++nt)
            #pragma unroll
            for (int r = 0; r < 4; ++r)
                outt[w][(q * 4 + r) * 64 + nt * 16 + m] = f2bf(acc[nt][r]);
        __syncthreads();
        #pragma unroll
        for (int i = lane; i < 128; i += 64) {
            int rr = i >> 3, cc = i & 7;
            int rg = row0 + rr;
            if (rg < N_NODES)
                ((float4*)y0)[(long long)rg * 8 + cc] = *(const float4*)&outt[w][rr * 64 + cc * 8];
        }
    } else {
        // fragment-prep W1b, W2
        const float* Ws[2] = {W1b, W2};
        unsigned short* Wp[2] = {w1bp, w2p};
        #pragma unroll
        for (int wsel = 0; wsel < 2; ++wsel) {
            const float* W = Ws[wsel];
            #pragma unroll
            for (int r = 0; r < 2; ++r) {
                int e = r * 256 + t;           // 0..511
                int kt = e >> 8, q = (e >> 6) & 3, col = e & 63;
                u16x8 o;
                #pragma unroll
                for (int j = 0; j < 8; ++j)
                    o[j] = f2bf(W[(kt * 32 + q * 8 + j) * 64 + col]);
                ((u16x8*)Wp[wsel])[e] = o;
            }
        }
        if (t < 64) {
            float s1 = g1[t] * rsqrtf(v1[t] + BN_EPS);
            AB[t]       = s1;
            AB[64 + t]  = b1a[t] * s1 + (be1[t] - m1[t] * s1);
            float s2 = g2[t] * rsqrtf(v2[t] + BN_EPS);
            AB[128 + t] = s2;
            AB[192 + t] = b2[t] * s2 + (be2[t] - m2[t] * s2);
        }
    }
}

// ---------------------------------------------------------------------------
// Single-block scan: reduce 147 partials per bucket, exclusive-scan 256
// totals -> base[257]; init cursor = base for part's chunk reservation.
// ---------------------------------------------------------------------------
__global__ __launch_bounds__(256) void scanB_kernel(const int* __restrict__ gpart,
                                                    int* __restrict__ base,
                                                    int* __restrict__ cursor) {
    __shared__ int tmp[256];
    int t = threadIdx.x;
    int s = 0;
    for (int blk = 0; blk < NBLK_P; ++blk) s += gpart[blk * NBUCK + t];
    tmp[t] = s;
    __syncthreads();
    for (int off = 1; off < 256; off <<= 1) {
        int a = (t >= off) ? tmp[t - off] : 0;
        __syncthreads();
        tmp[t] += a;
        __syncthreads();
    }
    int excl = tmp[t] - s;
    base[t] = excl;
    cursor[t] = excl;
    if (t == 255) base[256] = N_EDGES;
}

// ---------------------------------------------------------------------------
// Partition: reuse gpart for chunk reservation (one atomicAdd per bucket),
// then single placement pass over ei.
// ---------------------------------------------------------------------------
__global__ __launch_bounds__(256) void part_kernel(const int* __restrict__ ei,
                                                   const int* __restrict__ gpart,
                                                   int* __restrict__ cursor,
                                                   int* __restrict__ srcbuf,
                                                   unsigned short* __restrict__ dstlbuf) {
    __shared__ int cur[NBUCK];
    int t = threadIdx.x, blk = blockIdx.x;
    cur[t] = atomicAdd(&cursor[t], gpart[blk * NBUCK + t]);
    __syncthreads();
    int e0 = blk * CHUNK;
    for (int i = t; i < CHUNK; i += 256) {
        int e = e0 + i;
        if (e >= N_EDGES) break;
        unsigned d = (unsigned)ei[N_EDGES + e];
        int s = ei[e];
        int b = __umulhi(d, MAGIC);
        int pos = atomicAdd(&cur[b], 1);
        srcbuf[pos] = s;
        dstlbuf[pos] = (unsigned short)(d - b * NPB);
    }
}

// ---------------------------------------------------------------------------
// Refine: one block per bucket; LDS counting sort by dst_local; coalesced
// csr_src write; emits rowptr from the local exclusive scan.
// ---------------------------------------------------------------------------
__global__ __launch_bounds__(256) void refine_kernel(const int* __restrict__ srcbuf,
                                                     const unsigned short* __restrict__ dstlbuf,
                                                     const int* __restrict__ base,
                                                     int* __restrict__ csr_src,
                                                     int* __restrict__ rowptr) {
    __shared__ int cnt[NPB + 1];
    __shared__ int cur[NPB + 1];
    __shared__ int tmp[256];
    __shared__ int outb[CAP];
    int t = threadIdx.x, b = blockIdx.x;
    int beg = base[b];
    int end = base[b + 1];

    for (int i = t; i < NPB + 1; i += 256) cnt[i] = 0;
    __syncthreads();
    for (int i = beg + t; i < end; i += 256)
        atomicAdd(&cnt[dstlbuf[i]], 1);
    __syncthreads();

    // exclusive scan over NPB entries (2 elems/thread)
    int i0 = 2 * t, i1 = 2 * t + 1;
    int v0 = (i0 < NPB) ? cnt[i0] : 0;
    int v1 = (i1 < NPB) ? cnt[i1] : 0;
    int s = v0 + v1;
    tmp[t] = s;
    __syncthreads();
    for (int off = 1; off < 256; off <<= 1) {
        int a = (t >= off) ? tmp[t - off] : 0;
        __syncthreads();
        tmp[t] += a;
        __syncthreads();
    }
    int excl = tmp[t] - s;
    if (i0 < NPB) cur[i0] = excl;
    if (i1 < NPB) cur[i1] = excl + v0;
    {
        int g0 = b * NPB + i0;
        if (i0 < NPB && g0 < N_NODES) rowptr[g0] = beg + excl;
        int g1 = b * NPB + i1;
        if (i1 < NPB && g1 < N_NODES) rowptr[g1] = beg + excl + v0;
    }
    if (b == NBUCK - 1 && t == 0) rowptr[N_NODES] = N_EDGES;
    __syncthreads();

    for (int i = beg + t; i < end; i += 256) {
        int dl = dstlbuf[i];
        int pos = atomicAdd(&cur[dl], 1);
        if (pos < CAP) outb[pos] = srcbuf[i];
    }
    __syncthreads();

    int nb = end - beg; if (nb > CAP) nb = CAP;
    for (int i = t; i < nb; i += 256) csr_src[beg + i] = outb[i];
}

// ---------------------------------------------------------------------------
// gather + BN1 + ReLU: h1[i] = relu(A1 * (y0[i] + sum y0[src]) + B1).
// Gather loop byte-identical to the proven round-0 version.
// Grid = N/32 exactly (100000 = 32*3125).
// ---------------------------------------------------------------------------
__global__ __launch_bounds__(256) void gather_bn1_kernel(
    const unsigned short* __restrict__ feat,
    const int* __restrict__ rowptr, const int* __restrict__ csr_src,
    const float* __restrict__ AB,
    unsigned short* __restrict__ out) {
    int t = threadIdx.x;
    int node = blockIdx.x * 32 + (t >> 3);
    int q = t & 7;
    const u16x8* f8 = (const u16x8*)feat;
    u16x8 sv = f8[(long long)node * 8 + q];
    float acc[8];
    #pragma unroll
    for (int j = 0; j < 8; ++j) acc[j] = bf2f(sv[j]);
    int beg = rowptr[node], end = rowptr[node + 1];
    int k = beg;
    int sn = (k < end) ? csr_src[k] : 0;
    while (k < end) {
        int sc = sn;
        ++k;
        if (k < end) sn = csr_src[k];
        u16x8 v = f8[(long long)sc * 8 + q];
        #pragma unroll
        for (int j = 0; j < 8; ++j) acc[j] += bf2f(v[j]);
    }
    u16x8 o;
    #pragma unroll
    for (int j = 0; j < 8; ++j) {
        int c = q * 8 + j;
        o[j] = f2bf(fmaxf(acc[j] * AB[c] + AB[64 + c], 0.f));
    }
    ((u16x8*)out)[(long long)node * 8 + q] = o;
}

// ---------------------------------------------------------------------------
// Mid MLP: h2 = relu(h1 @ W1b + b1b);  y2 = h2 @ W2   (raw; BN2/b2 folded
// into AB[128..255], applied after the second aggregation).
// ---------------------------------------------------------------------------
__global__ __launch_bounds__(256) void mlpmid_kernel(
    const unsigned short* __restrict__ h1,
    const unsigned short* __restrict__ w1bp, const float* __restrict__ b1b,
    const unsigned short* __restrict__ w2p,
    unsigned short* __restrict__ y2) {
    __shared__ unsigned short h2t[4][16 * 72];
    __shared__ unsigned short outt[4][16 * 64];

    int t = threadIdx.x;
    int w = t >> 6, lane = t & 63;
    int m = lane & 15, q = lane >> 4;
    int row0 = blockIdx.x * 64 + w * 16;

    const bfx8* wbp = (const bfx8*)w1bp;
    const bfx8* wcp = (const bfx8*)w2p;
    bfx8 wb[4][2], wc[4][2];
    #pragma unroll
    for (int nt = 0; nt < 4; ++nt)
        #pragma unroll
        for (int kt = 0; kt < 2; ++kt) {
            int idx = (kt * 4 + q) * 64 + nt * 16 + m;
            wb[nt][kt] = wbp[idx];
            wc[nt][kt] = wcp[idx];
        }
    float B1b[4];
    #pragma unroll
    for (int nt = 0; nt < 4; ++nt) B1b[nt] = b1b[nt * 16 + m];

    int rowA = row0 + m;
    if (rowA > N_NODES - 1) rowA = N_NODES - 1;
    const bfx8* ap = (const bfx8*)(h1 + (long long)rowA * 64);
    bfx8 a0 = ap[q];
    bfx8 a1 = ap[4 + q];
    f32x4 acc[4];
    #pragma unroll
    for (int nt = 0; nt < 4; ++nt) {
        acc[nt] = (f32x4){0.f, 0.f, 0.f, 0.f};
        acc[nt] = __builtin_amdgcn_mfma_f32_16x16x32_bf16(a0, wb[nt][0], acc[nt], 0, 0, 0);
        acc[nt] = __builtin_amdgcn_mfma_f32_16x16x32_bf16(a1, wb[nt][1], acc[nt], 0, 0, 0);
    }
    #pragma unroll
    for (int nt = 0; nt < 4; ++nt)
        #pragma unroll
        for (int r = 0; r < 4; ++r) {
            float v = fmaxf(acc[nt][r] + B1b[nt], 0.f);
            h2t[w][(q * 4 + r) * 72 + nt * 16 + m] = f2bf(v);
        }
    __syncthreads();

    const bfx8* hp = (const bfx8*)&h2t[w][m * 72];
    bfx8 c0 = hp[q];
    bfx8 c1 = hp[4 + q];
    f32x4 acc2[4];
    #pragma unroll
    for (int nt = 0; nt < 4; ++nt) {
        acc2[nt] = (f32x4){0.f, 0.f, 0.f, 0.f};
        acc2[nt] = __builtin_amdgcn_mfma_f32_16x16x32_bf16(c0, wc[nt][0], acc2[nt], 0, 0, 0);
        acc2[nt] = __builtin_amdgcn_mfma_f32_16x16x32_bf16(c1, wc[nt][1], acc2[nt], 0, 0, 0);
    }
    #pragma unroll
    for (int nt = 0; nt < 4; ++nt)
        #pragma unroll
        for (int r = 0; r < 4; ++r)
            outt[w][(q * 4 + r) * 64 + nt * 16 + m] = f2bf(acc2[nt][r]);
    __syncthreads();

    #pragma unroll
    for (int i = lane; i < 128; i += 64) {
        int rr = i >> 3, cc = i & 7;
        int rg = row0 + rr;
        if (rg < N_NODES)
            ((float4*)y2)[(long long)rg * 8 + cc] = *(const float4*)&outt[w][rr * 64 + cc * 8];
    }
}

// ---------------------------------------------------------------------------
// gather + BN2 + ReLU + pool: h4 = relu(A2*(y2[i]+sum y2[src])+B2);
// xs[batch[i]] += h4. Segmented LDS pool (mlp2's proven epilogue, 32 rows).
// ---------------------------------------------------------------------------
__global__ __launch_bounds__(256) void gather_pool_kernel(
    const unsigned short* __restrict__ feat,
    const int* __restrict__ rowptr, const int* __restrict__ csr_src,
    const float* __restrict__ AB, const int* __restrict__ batch,
    float* __restrict__ xs) {
    __shared__ float h4[32 * 65];
    __shared__ int bts[32];
    int t = threadIdx.x;
    int nl = t >> 3;                 // 0..31 local node
    int q = t & 7;
    int node = blockIdx.x * 32 + nl;
    if (t < 32) bts[t] = batch[blockIdx.x * 32 + t];
    const u16x8* f8 = (const u16x8*)feat;
    u16x8 sv = f8[(long long)node * 8 + q];
    float acc[8];
    #pragma unroll
    for (int j = 0; j < 8; ++j) acc[j] = bf2f(sv[j]);
    int beg = rowptr[node], end = rowptr[node + 1];
    int k = beg;
    int sn = (k < end) ? csr_src[k] : 0;
    while (k < end) {
        int sc = sn;
        ++k;
        if (k < end) sn = csr_src[k];
        u16x8 v = f8[(long long)sc * 8 + q];
        #pragma unroll
        for (int j = 0; j < 8; ++j) acc[j] += bf2f(v[j]);
    }
    #pragma unroll
    for (int j = 0; j < 8; ++j) {
        int c = q * 8 + j;
        h4[nl * 65 + c] = fmaxf(acc[j] * AB[128 + c] + AB[192 + c], 0.f);
    }
    __syncthreads();

    int col = t & 63;
    int r0 = (t >> 6) * 8;
    int cb = bts[r0];
    float cur = 0.f;
    #pragma unroll
    for (int r = 0; r < 8; ++r) {
        int b = bts[r0 + r];
        if (b != cb) {
            unsafeAtomicAdd(&xs[cb * 64 + col], cur);
            cb = b;
            cur = 0.f;
        }
        cur += h4[(r0 + r) * 65 + col];
    }
    unsafeAtomicAdd(&xs[cb * 64 + col], cur);
}

// ---------------------------------------------------------------------------
// Head: x_topo = relu(topo @ Wt + bt); out = [x_struct, x_topo] @ Wc + bc
// ---------------------------------------------------------------------------
__global__ __launch_bounds__(64) void head_kernel(
    const float* __restrict__ xs, const float* __restrict__ topo,
    const float* __restrict__ Wt, const float* __restrict__ bt,
    const float* __restrict__ Wc, const float* __restrict__ bc,
    float* __restrict__ out) {
    __shared__ float trow[64];
    __shared__ float comb[128];
    int b = blockIdx.x;
    int h = threadIdx.x;
    trow[h] = topo[b * 64 + h];
    __syncthreads();
    float acc = bt[h];
    #pragma unroll
    for (int k = 0; k < 64; ++k) acc += trow[k] * Wt[k * 64 + h];
    comb[h] = xs[b * 64 + h];
    comb[64 + h] = fmaxf(acc, 0.f);
    __syncthreads();
    if (h < NCLASS) {
        float o = bc[h];
        #pragma unroll
        for (int k = 0; k < 128; ++k) o += comb[k] * Wc[k * NCLASS + h];
        out[b * NCLASS + h] = o;
    }
}

// ---------------------------------------------------------------------------
extern "C" void kernel_launch(void* const* d_in, const int* in_sizes, int n_in,
                              void* d_out, int out_size, void* d_ws, size_t ws_size,
                              hipStream_t stream) {
    const float* x     = (const float*)d_in[0];
    const int*   ei    = (const int*)d_in[1];
    const int*   batch = (const int*)d_in[2];
    const float* topo  = (const float*)d_in[3];
    const float* W1a   = (const float*)d_in[4];
    const float* b1a   = (const float*)d_in[5];
    const float* g1    = (const float*)d_in[6];
    const float* be1   = (const float*)d_in[7];
    const float* m1    = (const float*)d_in[8];
    const float* v1    = (const float*)d_in[9];
    const float* W1b   = (const float*)d_in[10];
    const float* b1b   = (const float*)d_in[11];
    const float* W2    = (const float*)d_in[12];
    const float* b2    = (const float*)d_in[13];
    const float* g2    = (const float*)d_in[14];
    const float* be2   = (const float*)d_in[15];
    const float* m2    = (const float*)d_in[16];
    const float* v2    = (const float*)d_in[17];
    const float* Wt    = (const float*)d_in[18];
    const float* bt    = (const float*)d_in[19];
    const float* Wc    = (const float*)d_in[20];
    const float* bc    = (const float*)d_in[21];
    float* out = (float*)d_out;

    // Workspace layout (16B-aligned chunks)
    char* p = (char*)d_ws;
    unsigned short* y0   = (unsigned short*)p; p += (size_t)N_NODES * DIM * 2;  // 12.8 MB
    unsigned short* h1b  = (unsigned short*)p; p += (size_t)N_NODES * DIM * 2;  // 12.8 MB
    unsigned short* y2b  = (unsigned short*)p; p += (size_t)N_NODES * DIM * 2;  // 12.8 MB
    float* xs      = (float*)p; p += (size_t)BGRAPHS * DIM * 4;                 // 256 KB
    int*   rowptr  = (int*)p;   p += (size_t)(N_NODES + 16) * 4;                // 400 KB
    int*   gpart   = (int*)p;   p += (size_t)NBLK_P * NBUCK * 4;                // 150 KB
    int*   base    = (int*)p;   p += 1040;                                      // 257 ints
    int*   cursor  = (int*)p;   p += 1024;                                      // 256 ints
    unsigned short* w1bp = (unsigned short*)p; p += 512 * 16;                   // 8 KB
    unsigned short* w2p  = (unsigned short*)p; p += 512 * 16;                   // 8 KB
    float* AB      = (float*)p; p += 256 * 4;                                   // 1 KB
    int*   srcbuf  = (int*)p;   p += (size_t)N_EDGES * 4;                       // 4.8 MB
    unsigned short* dstlbuf = (unsigned short*)p; p += (size_t)N_EDGES * 2;     // 2.4 MB
    int*   csr_src = (int*)p;                                                   // 4.8 MB

    // 1) hist partials + y0 = x@W1a + weight/BN-const prep (one launch)
    prep_kernel<<<NBLK_P + NB_G + 1, 256, 0, stream>>>(
        x, ei, gpart, W1a, y0, xs, W1b, W2, w1bp, w2p,
        b1a, g1, be1, m1, v1, b2, g2, be2, m2, v2, AB);
    // 2) bucket totals -> exclusive scan -> base/cursor
    scanB_kernel<<<1, 256, 0, stream>>>(gpart, base, cursor);
    // 3) partition edges (reserve chunks from gpart, single ei pass)
    part_kernel<<<NBLK_P, 256, 0, stream>>>(ei, gpart, cursor, srcbuf, dstlbuf);
    // 4) per-bucket counting sort -> csr_src + rowptr
    refine_kernel<<<NBUCK, 256, 0, stream>>>(srcbuf, dstlbuf, base, csr_src, rowptr);
    // 5) agg1 + BN1 + ReLU: h1 = relu(A1*agg(y0)+B1)
    gather_bn1_kernel<<<N_NODES / 32, 256, 0, stream>>>(y0, rowptr, csr_src, AB, h1b);
    // 6) h2 = relu(h1@W1b + b1b); y2 = h2@W2
    mlpmid_kernel<<<(N_NODES + 63) / 64, 256, 0, stream>>>(h1b, w1bp, b1b, w2p, y2b);
    // 7) agg2 + BN2 + ReLU + pool
    gather_pool_kernel<<<N_NODES / 32, 256, 0, stream>>>(y2b, rowptr, csr_src, AB, batch, xs);
    // 8) head
    head_kernel<<<BGRAPHS, 64, 0, stream>>>(xs, topo, Wt, bt, Wc, bc, out);
}

// Round 8
// 228.948 us; speedup vs baseline: 4.2636x; 1.0407x over previous
//
#include <hip/hip_runtime.h>

// Problem constants (match reference)
#define N_NODES 100000
#define N_EDGES 1200000
#define DIM     64
#define BGRAPHS 1000
#define NCLASS  10
#define BN_EPS  1e-5f

// CSR-build partition constants
#define NBUCK   256            // coarse buckets
#define NPB     391            // nodes per bucket (256*391 = 100096 >= N)
#define MAGIC   10984572u      // ceil(2^32/391): bucket = umulhi(d, MAGIC)
#define CHUNK   8192           // edges per partition block
#define NBLK_P  147            // ceil(E / CHUNK)
#define CAP     8192           // refine LDS staging capacity (>= max bucket edges)
#define NB_G    1563           // ceil(N/64) GEMM blocks in prep

typedef __attribute__((ext_vector_type(8))) short   bfx8;   // 8 bf16 MFMA A/B frag
typedef __attribute__((ext_vector_type(4))) float   f32x4;  // MFMA C/D frag
typedef __attribute__((ext_vector_type(8))) unsigned short u16x8;

__device__ __forceinline__ unsigned short f2bf(float f) {
    unsigned u = __builtin_bit_cast(unsigned, f);
    unsigned r = (u + 0x7FFFu + ((u >> 16) & 1u)) >> 16;   // RNE
    return (unsigned short)r;
}
__device__ __forceinline__ float bf2f(unsigned short h) {
    unsigned u = ((unsigned)h) << 16;
    return __builtin_bit_cast(float, u);
}

// B-fragment loader: element j = W[(kt*32 + q*8 + j)][col]  (fp32 W -> bf16)
__device__ __forceinline__ bfx8 load_wfrag(const float* __restrict__ W, int kt, int q, int col) {
    bfx8 f;
    #pragma unroll
    for (int j = 0; j < 8; ++j)
        f[j] = (short)f2bf(W[(kt * 32 + q * 8 + j) * 64 + col]);
    return f;
}

// ---------------------------------------------------------------------------
// Prep kernel (merged):
//   blocks [0,NBLK_P)           : per-chunk bucket histogram partials
//   blocks [NBLK_P,NBLK_P+NB_G) : y0 = bf16(x) @ bf16(W1a); zeros xs
//   block  NBLK_P+NB_G          : fragment-prep W1b/W2 + BN consts AB + zero cursor
// ---------------------------------------------------------------------------
__global__ __launch_bounds__(256) void prep_kernel(
    const float* __restrict__ x, const int* __restrict__ ei,
    int* __restrict__ gpart,
    const float* __restrict__ W1a, unsigned short* __restrict__ y0,
    float* __restrict__ xs,
    const float* __restrict__ W1b, const float* __restrict__ W2,
    unsigned short* __restrict__ w1bp, unsigned short* __restrict__ w2p,
    const float* __restrict__ b1a, const float* __restrict__ g1,
    const float* __restrict__ be1, const float* __restrict__ m1,
    const float* __restrict__ v1,
    const float* __restrict__ b2,  const float* __restrict__ g2,
    const float* __restrict__ be2, const float* __restrict__ m2,
    const float* __restrict__ v2,
    float* __restrict__ AB, int* __restrict__ cursor) {
    __shared__ int cnt[NBUCK];
    __shared__ unsigned short outt[4][16 * 64];
    int t = threadIdx.x;
    if (blockIdx.x < NBLK_P) {
        int blk = blockIdx.x;
        cnt[t] = 0;
        __syncthreads();
        int e0 = blk * CHUNK;
        for (int i = t; i < CHUNK; i += 256) {
            int e = e0 + i;
            if (e >= N_EDGES) break;
            unsigned d = (unsigned)ei[N_EDGES + e];
            atomicAdd(&cnt[__umulhi(d, MAGIC)], 1);
        }
        __syncthreads();
        gpart[blk * NBUCK + t] = cnt[t];
    } else if (blockIdx.x < NBLK_P + NB_G) {
        int g = blockIdx.x - NBLK_P;
        if (g < (BGRAPHS * DIM) / 256) xs[g * 256 + t] = 0.f;
        int w = t >> 6, lane = t & 63;
        int m = lane & 15, q = lane >> 4;
        int row0 = g * 64 + w * 16;

        bfx8 wa[4][2];
        #pragma unroll
        for (int nt = 0; nt < 4; ++nt)
            #pragma unroll
            for (int kt = 0; kt < 2; ++kt)
                wa[nt][kt] = load_wfrag(W1a, kt, q, nt * 16 + m);

        int rowA = row0 + m;
        if (rowA > N_NODES - 1) rowA = N_NODES - 1;
        const float* xp = x + (long long)rowA * 64;
        bfx8 a0, a1;
        #pragma unroll
        for (int j = 0; j < 8; ++j) {
            a0[j] = (short)f2bf(xp[q * 8 + j]);
            a1[j] = (short)f2bf(xp[32 + q * 8 + j]);
        }
        f32x4 acc[4];
        #pragma unroll
        for (int nt = 0; nt < 4; ++nt) {
            acc[nt] = (f32x4){0.f, 0.f, 0.f, 0.f};
            acc[nt] = __builtin_amdgcn_mfma_f32_16x16x32_bf16(a0, wa[nt][0], acc[nt], 0, 0, 0);
            acc[nt] = __builtin_amdgcn_mfma_f32_16x16x32_bf16(a1, wa[nt][1], acc[nt], 0, 0, 0);
        }
        #pragma unroll
        for (int nt = 0; nt < 4; ++nt)
            #pragma unroll
            for (int r = 0; r < 4; ++r)
                outt[w][(q * 4 + r) * 64 + nt * 16 + m] = f2bf(acc[nt][r]);
        __syncthreads();
        #pragma unroll
        for (int i = lane; i < 128; i += 64) {
            int rr = i >> 3, cc = i & 7;
            int rg = row0 + rr;
            if (rg < N_NODES)
                ((float4*)y0)[(long long)rg * 8 + cc] = *(const float4*)&outt[w][rr * 64 + cc * 8];
        }
    } else {
        // fragment-prep W1b, W2; AB constants; zero cursor
        cursor[t] = 0;
        const float* Ws[2] = {W1b, W2};
        unsigned short* Wp[2] = {w1bp, w2p};
        #pragma unroll
        for (int wsel = 0; wsel < 2; ++wsel) {
            const float* W = Ws[wsel];
            #pragma unroll
            for (int r = 0; r < 2; ++r) {
                int e = r * 256 + t;           // 0..511
                int kt = e >> 8, q = (e >> 6) & 3, col = e & 63;
                u16x8 o;
                #pragma unroll
                for (int j = 0; j < 8; ++j)
                    o[j] = f2bf(W[(kt * 32 + q * 8 + j) * 64 + col]);
                ((u16x8*)Wp[wsel])[e] = o;
            }
        }
        if (t < 64) {
            float s1 = g1[t] * rsqrtf(v1[t] + BN_EPS);
            AB[t]       = s1;
            AB[64 + t]  = b1a[t] * s1 + (be1[t] - m1[t] * s1);
            float s2 = g2[t] * rsqrtf(v2[t] + BN_EPS);
            AB[128 + t] = s2;
            AB[192 + t] = b2[t] * s2 + (be2[t] - m2[t] * s2);
        }
    }
}

// ---------------------------------------------------------------------------
// Partition (self-scanning): every block redundantly reduces gpart to bucket
// totals + exclusive scan (parallel across 147 CUs -- replaces the serial
// single-block scanB). Writes base idempotently for refine; reserves its
// chunk via one atomicAdd per bucket on the zero-initialized cursor.
// ---------------------------------------------------------------------------
__global__ __launch_bounds__(256) void part_kernel(const int* __restrict__ ei,
                                                   const int* __restrict__ gpart,
                                                   int* __restrict__ cursor,
                                                   int* __restrict__ base,
                                                   int* __restrict__ srcbuf,
                                                   unsigned short* __restrict__ dstlbuf) {
    __shared__ int tmp[256];
    __shared__ int cur[NBUCK];
    int t = threadIdx.x, blk = blockIdx.x;
    int s = 0;
    for (int b = 0; b < NBLK_P; ++b) s += gpart[b * NBUCK + t];
    tmp[t] = s;
    __syncthreads();
    for (int off = 1; off < 256; off <<= 1) {
        int a = (t >= off) ? tmp[t - off] : 0;
        __syncthreads();
        tmp[t] += a;
        __syncthreads();
    }
    int excl = tmp[t] - s;
    base[t] = excl;                               // idempotent across blocks
    if (blk == 0 && t == 255) base[256] = N_EDGES;
    int resv = atomicAdd(&cursor[t], gpart[blk * NBUCK + t]);
    cur[t] = excl + resv;
    __syncthreads();
    int e0 = blk * CHUNK;
    for (int i = t; i < CHUNK; i += 256) {
        int e = e0 + i;
        if (e >= N_EDGES) break;
        unsigned d = (unsigned)ei[N_EDGES + e];
        int sv = ei[e];
        int b = __umulhi(d, MAGIC);
        int pos = atomicAdd(&cur[b], 1);
        srcbuf[pos] = sv;
        dstlbuf[pos] = (unsigned short)(d - b * NPB);
    }
}

// ---------------------------------------------------------------------------
// Refine: one block per bucket; LDS counting sort by dst_local; coalesced
// csr_src write; emits rowptr from the local exclusive scan.
// ---------------------------------------------------------------------------
__global__ __launch_bounds__(256) void refine_kernel(const int* __restrict__ srcbuf,
                                                     const unsigned short* __restrict__ dstlbuf,
                                                     const int* __restrict__ base,
                                                     int* __restrict__ csr_src,
                                                     int* __restrict__ rowptr) {
    __shared__ int cnt[NPB + 1];
    __shared__ int cur[NPB + 1];
    __shared__ int tmp[256];
    __shared__ int outb[CAP];
    int t = threadIdx.x, b = blockIdx.x;
    int beg = base[b];
    int end = base[b + 1];

    for (int i = t; i < NPB + 1; i += 256) cnt[i] = 0;
    __syncthreads();
    for (int i = beg + t; i < end; i += 256)
        atomicAdd(&cnt[dstlbuf[i]], 1);
    __syncthreads();

    // exclusive scan over NPB entries (2 elems/thread)
    int i0 = 2 * t, i1 = 2 * t + 1;
    int v0 = (i0 < NPB) ? cnt[i0] : 0;
    int v1 = (i1 < NPB) ? cnt[i1] : 0;
    int s = v0 + v1;
    tmp[t] = s;
    __syncthreads();
    for (int off = 1; off < 256; off <<= 1) {
        int a = (t >= off) ? tmp[t - off] : 0;
        __syncthreads();
        tmp[t] += a;
        __syncthreads();
    }
    int excl = tmp[t] - s;
    if (i0 < NPB) cur[i0] = excl;
    if (i1 < NPB) cur[i1] = excl + v0;
    {
        int g0 = b * NPB + i0;
        if (i0 < NPB && g0 < N_NODES) rowptr[g0] = beg + excl;
        int g1 = b * NPB + i1;
        if (i1 < NPB && g1 < N_NODES) rowptr[g1] = beg + excl + v0;
    }
    if (b == NBUCK - 1 && t == 0) rowptr[N_NODES] = N_EDGES;
    __syncthreads();

    for (int i = beg + t; i < end; i += 256) {
        int dl = dstlbuf[i];
        int pos = atomicAdd(&cur[dl], 1);
        if (pos < CAP) outb[pos] = srcbuf[i];
    }
    __syncthreads();

    int nb = end - beg; if (nb > CAP) nb = CAP;
    for (int i = t; i < nb; i += 256) csr_src[beg + i] = outb[i];
}

// ---------------------------------------------------------------------------
// Fused agg1 + BN1 + ReLU + MLP: per block of 32 nodes,
//   h1 = relu(A1*agg(y0)+B1)          (gather loop byte-identical to proven)
//   h2 = relu(h1 @ W1b + b1b)         (LDS-staged MFMA, 2 row-tiles x 4 col-tiles)
//   y2 = h2 @ W2
// Weight fragments loaded AFTER the gather loop (register-light loop phase).
// Grid = N/32 = 3125 exactly.
// ---------------------------------------------------------------------------
__global__ __launch_bounds__(256) void gather_mlp1_kernel(
    const unsigned short* __restrict__ feat,
    const int* __restrict__ rowptr, const int* __restrict__ csr_src,
    const float* __restrict__ AB,
    const unsigned short* __restrict__ w1bp, const float* __restrict__ b1b,
    const unsigned short* __restrict__ w2p,
    unsigned short* __restrict__ y2) {
    __shared__ unsigned short h1t[32 * 72];
    __shared__ unsigned short h2t[32 * 72];
    __shared__ unsigned short outt[32 * 64];

    int t = threadIdx.x;
    int nl = t >> 3, q8 = t & 7;
    int node = blockIdx.x * 32 + nl;
    const u16x8* f8 = (const u16x8*)feat;
    {
        u16x8 sv = f8[(long long)node * 8 + q8];
        float acc[8];
        #pragma unroll
        for (int j = 0; j < 8; ++j) acc[j] = bf2f(sv[j]);
        int beg = rowptr[node], end = rowptr[node + 1];
        int k = beg;
        int sn = (k < end) ? csr_src[k] : 0;
        while (k < end) {
            int sc = sn;
            ++k;
            if (k < end) sn = csr_src[k];
            u16x8 v = f8[(long long)sc * 8 + q8];
            #pragma unroll
            for (int j = 0; j < 8; ++j) acc[j] += bf2f(v[j]);
        }
        #pragma unroll
        for (int j = 0; j < 8; ++j) {
            int c = q8 * 8 + j;
            h1t[nl * 72 + c] = f2bf(fmaxf(acc[j] * AB[c] + AB[64 + c], 0.f));
        }
    }
    __syncthreads();

    // MFMA phase: wave w owns row-tile rt=w>>1 (16 rows), col-tiles c0,c0+1
    int w = t >> 6, lane = t & 63;
    int m = lane & 15, q = lane >> 4;
    int rt = w >> 1;
    int c0 = (w & 1) * 2;

    const bfx8* wbp = (const bfx8*)w1bp;
    const bfx8* wcp = (const bfx8*)w2p;

    {
        const bfx8* hp = (const bfx8*)&h1t[(rt * 16 + m) * 72];
        bfx8 a0 = hp[q];
        bfx8 a1 = hp[4 + q];
        #pragma unroll
        for (int ci = 0; ci < 2; ++ci) {
            int ct = c0 + ci;
            bfx8 w0 = wbp[(0 * 4 + q) * 64 + ct * 16 + m];
            bfx8 w1 = wbp[(1 * 4 + q) * 64 + ct * 16 + m];
            f32x4 acc = (f32x4){0.f, 0.f, 0.f, 0.f};
            acc = __builtin_amdgcn_mfma_f32_16x16x32_bf16(a0, w0, acc, 0, 0, 0);
            acc = __builtin_amdgcn_mfma_f32_16x16x32_bf16(a1, w1, acc, 0, 0, 0);
            float bb = b1b[ct * 16 + m];
            #pragma unroll
            for (int r = 0; r < 4; ++r)
                h2t[(rt * 16 + q * 4 + r) * 72 + ct * 16 + m] = f2bf(fmaxf(acc[r] + bb, 0.f));
        }
    }
    __syncthreads();

    {
        const bfx8* hp = (const bfx8*)&h2t[(rt * 16 + m) * 72];
        bfx8 a0 = hp[q];
        bfx8 a1 = hp[4 + q];
        #pragma unroll
        for (int ci = 0; ci < 2; ++ci) {
            int ct = c0 + ci;
            bfx8 w0 = wcp[(0 * 4 + q) * 64 + ct * 16 + m];
            bfx8 w1 = wcp[(1 * 4 + q) * 64 + ct * 16 + m];
            f32x4 acc = (f32x4){0.f, 0.f, 0.f, 0.f};
            acc = __builtin_amdgcn_mfma_f32_16x16x32_bf16(a0, w0, acc, 0, 0, 0);
            acc = __builtin_amdgcn_mfma_f32_16x16x32_bf16(a1, w1, acc, 0, 0, 0);
            #pragma unroll
            for (int r = 0; r < 4; ++r)
                outt[(rt * 16 + q * 4 + r) * 64 + ct * 16 + m] = f2bf(acc[r]);
        }
    }
    __syncthreads();

    // coalesced store: one float4 (8 bf16) per thread
    int rr = t >> 3, cc = t & 7;
    ((float4*)y2)[((long long)blockIdx.x * 32 + rr) * 8 + cc] =
        *(const float4*)&outt[rr * 64 + cc * 8];
}

// ---------------------------------------------------------------------------
// gather + BN2 + ReLU + pool: h4 = relu(A2*(y2[i]+sum y2[src])+B2);
// xs[batch[i]] += h4. Segmented LDS pool.
// ---------------------------------------------------------------------------
__global__ __launch_bounds__(256) void gather_pool_kernel(
    const unsigned short* __restrict__ feat,
    const int* __restrict__ rowptr, const int* __restrict__ csr_src,
    const float* __restrict__ AB, const int* __restrict__ batch,
    float* __restrict__ xs) {
    __shared__ float h4[32 * 65];
    __shared__ int bts[32];
    int t = threadIdx.x;
    int nl = t >> 3;                 // 0..31 local node
    int q = t & 7;
    int node = blockIdx.x * 32 + nl;
    if (t < 32) bts[t] = batch[blockIdx.x * 32 + t];
    const u16x8* f8 = (const u16x8*)feat;
    u16x8 sv = f8[(long long)node * 8 + q];
    float acc[8];
    #pragma unroll
    for (int j = 0; j < 8; ++j) acc[j] = bf2f(sv[j]);
    int beg = rowptr[node], end = rowptr[node + 1];
    int k = beg;
    int sn = (k < end) ? csr_src[k] : 0;
    while (k < end) {
        int sc = sn;
        ++k;
        if (k < end) sn = csr_src[k];
        u16x8 v = f8[(long long)sc * 8 + q];
        #pragma unroll
        for (int j = 0; j < 8; ++j) acc[j] += bf2f(v[j]);
    }
    #pragma unroll
    for (int j = 0; j < 8; ++j) {
        int c = q * 8 + j;
        h4[nl * 65 + c] = fmaxf(acc[j] * AB[128 + c] + AB[192 + c], 0.f);
    }
    __syncthreads();

    int col = t & 63;
    int r0 = (t >> 6) * 8;
    int cb = bts[r0];
    float cur = 0.f;
    #pragma unroll
    for (int r = 0; r < 8; ++r) {
        int b = bts[r0 + r];
        if (b != cb) {
            unsafeAtomicAdd(&xs[cb * 64 + col], cur);
            cb = b;
            cur = 0.f;
        }
        cur += h4[(r0 + r) * 65 + col];
    }
    unsafeAtomicAdd(&xs[cb * 64 + col], cur);
}

// ---------------------------------------------------------------------------
// Head: x_topo = relu(topo @ Wt + bt); out = [x_struct, x_topo] @ Wc + bc
// ---------------------------------------------------------------------------
__global__ __launch_bounds__(64) void head_kernel(
    const float* __restrict__ xs, const float* __restrict__ topo,
    const float* __restrict__ Wt, const float* __restrict__ bt,
    const float* __restrict__ Wc, const float* __restrict__ bc,
    float* __restrict__ out) {
    __shared__ float trow[64];
    __shared__ float comb[128];
    int b = blockIdx.x;
    int h = threadIdx.x;
    trow[h] = topo[b * 64 + h];
    __syncthreads();
    float acc = bt[h];
    #pragma unroll
    for (int k = 0; k < 64; ++k) acc += trow[k] * Wt[k * 64 + h];
    comb[h] = xs[b * 64 + h];
    comb[64 + h] = fmaxf(acc, 0.f);
    __syncthreads();
    if (h < NCLASS) {
        float o = bc[h];
        #pragma unroll
        for (int k = 0; k < 128; ++k) o += comb[k] * Wc[k * NCLASS + h];
        out[b * NCLASS + h] = o;
    }
}

// ---------------------------------------------------------------------------
extern "C" void kernel_launch(void* const* d_in, const int* in_sizes, int n_in,
                              void* d_out, int out_size, void* d_ws, size_t ws_size,
                              hipStream_t stream) {
    const float* x     = (const float*)d_in[0];
    const int*   ei    = (const int*)d_in[1];
    const int*   batch = (const int*)d_in[2];
    const float* topo  = (const float*)d_in[3];
    const float* W1a   = (const float*)d_in[4];
    const float* b1a   = (const float*)d_in[5];
    const float* g1    = (const float*)d_in[6];
    const float* be1   = (const float*)d_in[7];
    const float* m1    = (const float*)d_in[8];
    const float* v1    = (const float*)d_in[9];
    const float* W1b   = (const float*)d_in[10];
    const float* b1b   = (const float*)d_in[11];
    const float* W2    = (const float*)d_in[12];
    const float* b2    = (const float*)d_in[13];
    const float* g2    = (const float*)d_in[14];
    const float* be2   = (const float*)d_in[15];
    const float* m2    = (const float*)d_in[16];
    const float* v2    = (const float*)d_in[17];
    const float* Wt    = (const float*)d_in[18];
    const float* bt    = (const float*)d_in[19];
    const float* Wc    = (const float*)d_in[20];
    const float* bc    = (const float*)d_in[21];
    float* out = (float*)d_out;

    // Workspace layout (16B-aligned chunks)
    char* p = (char*)d_ws;
    unsigned short* y0   = (unsigned short*)p; p += (size_t)N_NODES * DIM * 2;  // 12.8 MB
    unsigned short* y2b  = (unsigned short*)p; p += (size_t)N_NODES * DIM * 2;  // 12.8 MB
    float* xs      = (float*)p; p += (size_t)BGRAPHS * DIM * 4;                 // 256 KB
    int*   rowptr  = (int*)p;   p += (size_t)(N_NODES + 16) * 4;                // 400 KB
    int*   gpart   = (int*)p;   p += (size_t)NBLK_P * NBUCK * 4;                // 150 KB
    int*   base    = (int*)p;   p += 1040;                                      // 257 ints
    int*   cursor  = (int*)p;   p += 1024;                                      // 256 ints
    unsigned short* w1bp = (unsigned short*)p; p += 512 * 16;                   // 8 KB
    unsigned short* w2p  = (unsigned short*)p; p += 512 * 16;                   // 8 KB
    float* AB      = (float*)p; p += 256 * 4;                                   // 1 KB
    int*   srcbuf  = (int*)p;   p += (size_t)N_EDGES * 4;                       // 4.8 MB
    unsigned short* dstlbuf = (unsigned short*)p; p += (size_t)N_EDGES * 2;     // 2.4 MB
    int*   csr_src = (int*)p;                                                   // 4.8 MB

    // 1) hist partials + y0 = x@W1a + weight/BN-const prep + cursor zero
    prep_kernel<<<NBLK_P + NB_G + 1, 256, 0, stream>>>(
        x, ei, gpart, W1a, y0, xs, W1b, W2, w1bp, w2p,
        b1a, g1, be1, m1, v1, b2, g2, be2, m2, v2, AB, cursor);
    // 2) partition edges (self-scan of gpart replaces scanB; writes base)
    part_kernel<<<NBLK_P, 256, 0, stream>>>(ei, gpart, cursor, base, srcbuf, dstlbuf);
    // 3) per-bucket counting sort -> csr_src + rowptr
    refine_kernel<<<NBUCK, 256, 0, stream>>>(srcbuf, dstlbuf, base, csr_src, rowptr);
    // 4) fused agg1+BN1+ReLU + MLP (h1,h2 in LDS): y2 = relu(h1@W1b+b1b)@W2
    gather_mlp1_kernel<<<N_NODES / 32, 256, 0, stream>>>(
        y0, rowptr, csr_src, AB, w1bp, b1b, w2p, y2b);
    // 5) agg2 + BN2 + ReLU + pool
    gather_pool_kernel<<<N_NODES / 32, 256, 0, stream>>>(y2b, rowptr, csr_src, AB, batch, xs);
    // 6) head
    head_kernel<<<BGRAPHS, 64, 0, stream>>>(xs, topo, Wt, bt, Wc, bc, out);
}

// Round 10
// 225.465 us; speedup vs baseline: 4.3294x; 1.0154x over previous
//
#include <hip/hip_runtime.h>

// Problem constants (match reference)
#define N_NODES 100000
#define N_EDGES 1200000
#define DIM     64
#define BGRAPHS 1000
#define NCLASS  10
#define BN_EPS  1e-5f

// CSR-build partition constants
#define NBUCK   256            // coarse buckets
#define NPB     391            // nodes per bucket (256*391 = 100096 >= N)
#define MAGIC   10984572u      // ceil(2^32/391): bucket = umulhi(d, MAGIC)
#define CHUNK   8192           // edges per partition block
#define NBLK_P  147            // ceil(E / CHUNK)
#define BCAP    8192           // fixed per-bucket region capacity (proven >= max bucket size)
#define NB_G    1563           // ceil(N/64) GEMM blocks in prep

typedef __attribute__((ext_vector_type(8))) short   bfx8;   // 8 bf16 MFMA A/B frag
typedef __attribute__((ext_vector_type(4))) float   f32x4;  // MFMA C/D frag
typedef __attribute__((ext_vector_type(8))) unsigned short u16x8;

__device__ __forceinline__ unsigned short f2bf(float f) {
    unsigned u = __builtin_bit_cast(unsigned, f);
    unsigned r = (u + 0x7FFFu + ((u >> 16) & 1u)) >> 16;   // RNE
    return (unsigned short)r;
}
__device__ __forceinline__ float bf2f(unsigned short h) {
    unsigned u = ((unsigned)h) << 16;
    return __builtin_bit_cast(float, u);
}

// B-fragment loader: element j = W[(kt*32 + q*8 + j)][col]  (fp32 W -> bf16)
__device__ __forceinline__ bfx8 load_wfrag(const float* __restrict__ W, int kt, int q, int col) {
    bfx8 f;
    #pragma unroll
    for (int j = 0; j < 8; ++j)
        f[j] = (short)f2bf(W[(kt * 32 + q * 8 + j) * 64 + col]);
    return f;
}

// ---------------------------------------------------------------------------
// Prep kernel (merged):
//   blocks [0,NB_G)  : y0 = bf16(x) @ bf16(W1a); zeros xs
//   block  NB_G      : fragment-prep W1b/W2 + BN consts AB + cursor[b]=b*BCAP
// ---------------------------------------------------------------------------
__global__ __launch_bounds__(256) void prep_kernel(
    const float* __restrict__ x,
    const float* __restrict__ W1a, unsigned short* __restrict__ y0,
    float* __restrict__ xs,
    const float* __restrict__ W1b, const float* __restrict__ W2,
    unsigned short* __restrict__ w1bp, unsigned short* __restrict__ w2p,
    const float* __restrict__ b1a, const float* __restrict__ g1,
    const float* __restrict__ be1, const float* __restrict__ m1,
    const float* __restrict__ v1,
    const float* __restrict__ b2,  const float* __restrict__ g2,
    const float* __restrict__ be2, const float* __restrict__ m2,
    const float* __restrict__ v2,
    float* __restrict__ AB, int* __restrict__ cursor) {
    __shared__ unsigned short outt[4][16 * 64];
    int t = threadIdx.x;
    if (blockIdx.x < NB_G) {
        int g = blockIdx.x;
        if (g < (BGRAPHS * DIM) / 256) xs[g * 256 + t] = 0.f;
        int w = t >> 6, lane = t & 63;
        int m = lane & 15, q = lane >> 4;
        int row0 = g * 64 + w * 16;

        bfx8 wa[4][2];
        #pragma unroll
        for (int nt = 0; nt < 4; ++nt)
            #pragma unroll
            for (int kt = 0; kt < 2; ++kt)
                wa[nt][kt] = load_wfrag(W1a, kt, q, nt * 16 + m);

        int rowA = row0 + m;
        if (rowA > N_NODES - 1) rowA = N_NODES - 1;
        const float* xp = x + (long long)rowA * 64;
        bfx8 a0, a1;
        #pragma unroll
        for (int j = 0; j < 8; ++j) {
            a0[j] = (short)f2bf(xp[q * 8 + j]);
            a1[j] = (short)f2bf(xp[32 + q * 8 + j]);
        }
        f32x4 acc[4];
        #pragma unroll
        for (int nt = 0; nt < 4; ++nt) {
            acc[nt] = (f32x4){0.f, 0.f, 0.f, 0.f};
            acc[nt] = __builtin_amdgcn_mfma_f32_16x16x32_bf16(a0, wa[nt][0], acc[nt], 0, 0, 0);
            acc[nt] = __builtin_amdgcn_mfma_f32_16x16x32_bf16(a1, wa[nt][1], acc[nt], 0, 0, 0);
        }
        #pragma unroll
        for (int nt = 0; nt < 4; ++nt)
            #pragma unroll
            for (int r = 0; r < 4; ++r)
                outt[w][(q * 4 + r) * 64 + nt * 16 + m] = f2bf(acc[nt][r]);
        __syncthreads();
        #pragma unroll
        for (int i = lane; i < 128; i += 64) {
            int rr = i >> 3, cc = i & 7;
            int rg = row0 + rr;
            if (rg < N_NODES)
                ((float4*)y0)[(long long)rg * 8 + cc] = *(const float4*)&outt[w][rr * 64 + cc * 8];
        }
    } else {
        // fragment-prep W1b, W2; AB constants; cursor init to region starts
        cursor[t] = t * BCAP;
        const float* Ws[2] = {W1b, W2};
        unsigned short* Wp[2] = {w1bp, w2p};
        #pragma unroll
        for (int wsel = 0; wsel < 2; ++wsel) {
            const float* W = Ws[wsel];
            #pragma unroll
            for (int r = 0; r < 2; ++r) {
                int e = r * 256 + t;           // 0..511
                int kt = e >> 8, q = (e >> 6) & 3, col = e & 63;
                u16x8 o;
                #pragma unroll
                for (int j = 0; j < 8; ++j)
                    o[j] = f2bf(W[(kt * 32 + q * 8 + j) * 64 + col]);
                ((u16x8*)Wp[wsel])[e] = o;
            }
        }
        if (t < 64) {
            float s1 = g1[t] * rsqrtf(v1[t] + BN_EPS);
            AB[t]       = s1;
            AB[64 + t]  = b1a[t] * s1 + (be1[t] - m1[t] * s1);
            float s2 = g2[t] * rsqrtf(v2[t] + BN_EPS);
            AB[128 + t] = s2;
            AB[192 + t] = b2[t] * s2 + (be2[t] - m2[t] * s2);
        }
    }
}

// ---------------------------------------------------------------------------
// Partition into FIXED per-bucket regions [b*BCAP, b*BCAP+size): LDS count
// of this chunk -> one cursor atomicAdd per bucket -> place. No histogram,
// no scan. Final cursor[b] = b*BCAP + size_b (read by refine).
// ---------------------------------------------------------------------------
__global__ __launch_bounds__(256) void part_kernel(const int* __restrict__ ei,
                                                   int* __restrict__ cursor,
                                                   int* __restrict__ srcbuf,
                                                   unsigned short* __restrict__ dstlbuf) {
    __shared__ int cnt[NBUCK];
    __shared__ int cur[NBUCK];
    int t = threadIdx.x, blk = blockIdx.x;
    cnt[t] = 0;
    __syncthreads();
    int e0 = blk * CHUNK;
    for (int i = t; i < CHUNK; i += 256) {
        int e = e0 + i;
        if (e >= N_EDGES) break;
        unsigned d = (unsigned)ei[N_EDGES + e];
        atomicAdd(&cnt[__umulhi(d, MAGIC)], 1);
    }
    __syncthreads();
    cur[t] = atomicAdd(&cursor[t], cnt[t]);
    __syncthreads();
    for (int i = t; i < CHUNK; i += 256) {
        int e = e0 + i;
        if (e >= N_EDGES) break;
        unsigned d = (unsigned)ei[N_EDGES + e];
        int sv = ei[e];
        int b = __umulhi(d, MAGIC);
        int pos = atomicAdd(&cur[b], 1);
        srcbuf[pos] = sv;
        dstlbuf[pos] = (unsigned short)(d - b * NPB);
    }
}

// ---------------------------------------------------------------------------
// Refine: one block per bucket region; LDS counting sort by dst_local;
// coalesced csr_src write; emits BOTH rowptr (begin) and rowend (end) per
// node from the local exclusive scan -- fixed regions are non-contiguous,
// so end cannot come from the next node's rowptr.
// ---------------------------------------------------------------------------
__global__ __launch_bounds__(256) void refine_kernel(const int* __restrict__ srcbuf,
                                                     const unsigned short* __restrict__ dstlbuf,
                                                     const int* __restrict__ cursor,
                                                     int* __restrict__ csr_src,
                                                     int* __restrict__ rowptr,
                                                     int* __restrict__ rowend) {
    __shared__ int cnt[NPB + 1];
    __shared__ int cur[NPB + 1];
    __shared__ int tmp[256];
    __shared__ int outb[BCAP];
    int t = threadIdx.x, b = blockIdx.x;
    int beg = b * BCAP;
    int end = cursor[b];

    for (int i = t; i < NPB + 1; i += 256) cnt[i] = 0;
    __syncthreads();
    for (int i = beg + t; i < end; i += 256)
        atomicAdd(&cnt[dstlbuf[i]], 1);
    __syncthreads();

    // exclusive scan over NPB entries (2 elems/thread)
    int i0 = 2 * t, i1 = 2 * t + 1;
    int v0 = (i0 < NPB) ? cnt[i0] : 0;
    int v1 = (i1 < NPB) ? cnt[i1] : 0;
    int s = v0 + v1;
    tmp[t] = s;
    __syncthreads();
    for (int off = 1; off < 256; off <<= 1) {
        int a = (t >= off) ? tmp[t - off] : 0;
        __syncthreads();
        tmp[t] += a;
        __syncthreads();
    }
    int excl = tmp[t] - s;
    if (i0 < NPB) cur[i0] = excl;
    if (i1 < NPB) cur[i1] = excl + v0;
    {
        int g0 = b * NPB + i0;
        if (i0 < NPB && g0 < N_NODES) {
            rowptr[g0] = beg + excl;
            rowend[g0] = beg + excl + v0;
        }
        int g1 = b * NPB + i1;
        if (i1 < NPB && g1 < N_NODES) {
            rowptr[g1] = beg + excl + v0;
            rowend[g1] = beg + excl + v0 + v1;
        }
    }
    __syncthreads();

    for (int i = beg + t; i < end; i += 256) {
        int dl = dstlbuf[i];
        int pos = atomicAdd(&cur[dl], 1);
        if (pos < BCAP) outb[pos] = srcbuf[i];
    }
    __syncthreads();

    int nb = end - beg; if (nb > BCAP) nb = BCAP;
    for (int i = t; i < nb; i += 256) csr_src[beg + i] = outb[i];
}

// ---------------------------------------------------------------------------
// Fused agg1 + BN1 + ReLU + MLP: per block of 32 nodes,
//   h1 = relu(A1*agg(y0)+B1)          (gather loop byte-identical to proven)
//   h2 = relu(h1 @ W1b + b1b)         (LDS-staged MFMA, 2 row-tiles x 4 col-tiles)
//   y2 = h2 @ W2
// ---------------------------------------------------------------------------
__global__ __launch_bounds__(256) void gather_mlp1_kernel(
    const unsigned short* __restrict__ feat,
    const int* __restrict__ rowptr, const int* __restrict__ rowend,
    const int* __restrict__ csr_src,
    const float* __restrict__ AB,
    const unsigned short* __restrict__ w1bp, const float* __restrict__ b1b,
    const unsigned short* __restrict__ w2p,
    unsigned short* __restrict__ y2) {
    __shared__ unsigned short h1t[32 * 72];
    __shared__ unsigned short h2t[32 * 72];
    __shared__ unsigned short outt[32 * 64];

    int t = threadIdx.x;
    int nl = t >> 3, q8 = t & 7;
    int node = blockIdx.x * 32 + nl;
    const u16x8* f8 = (const u16x8*)feat;
    {
        u16x8 sv = f8[(long long)node * 8 + q8];
        float acc[8];
        #pragma unroll
        for (int j = 0; j < 8; ++j) acc[j] = bf2f(sv[j]);
        int beg = rowptr[node], end = rowend[node];
        int k = beg;
        int sn = (k < end) ? csr_src[k] : 0;
        while (k < end) {
            int sc = sn;
            ++k;
            if (k < end) sn = csr_src[k];
            u16x8 v = f8[(long long)sc * 8 + q8];
            #pragma unroll
            for (int j = 0; j < 8; ++j) acc[j] += bf2f(v[j]);
        }
        #pragma unroll
        for (int j = 0; j < 8; ++j) {
            int c = q8 * 8 + j;
            h1t[nl * 72 + c] = f2bf(fmaxf(acc[j] * AB[c] + AB[64 + c], 0.f));
        }
    }
    __syncthreads();

    // MFMA phase: wave w owns row-tile rt=w>>1 (16 rows), col-tiles c0,c0+1
    int w = t >> 6, lane = t & 63;
    int m = lane & 15, q = lane >> 4;
    int rt = w >> 1;
    int c0 = (w & 1) * 2;

    const bfx8* wbp = (const bfx8*)w1bp;
    const bfx8* wcp = (const bfx8*)w2p;

    {
        const bfx8* hp = (const bfx8*)&h1t[(rt * 16 + m) * 72];
        bfx8 a0 = hp[q];
        bfx8 a1 = hp[4 + q];
        #pragma unroll
        for (int ci = 0; ci < 2; ++ci) {
            int ct = c0 + ci;
            bfx8 w0 = wbp[(0 * 4 + q) * 64 + ct * 16 + m];
            bfx8 w1 = wbp[(1 * 4 + q) * 64 + ct * 16 + m];
            f32x4 acc = (f32x4){0.f, 0.f, 0.f, 0.f};
            acc = __builtin_amdgcn_mfma_f32_16x16x32_bf16(a0, w0, acc, 0, 0, 0);
            acc = __builtin_amdgcn_mfma_f32_16x16x32_bf16(a1, w1, acc, 0, 0, 0);
            float bb = b1b[ct * 16 + m];
            #pragma unroll
            for (int r = 0; r < 4; ++r)
                h2t[(rt * 16 + q * 4 + r) * 72 + ct * 16 + m] = f2bf(fmaxf(acc[r] + bb, 0.f));
        }
    }
    __syncthreads();

    {
        const bfx8* hp = (const bfx8*)&h2t[(rt * 16 + m) * 72];
        bfx8 a0 = hp[q];
        bfx8 a1 = hp[4 + q];
        #pragma unroll
        for (int ci = 0; ci < 2; ++ci) {
            int ct = c0 + ci;
            bfx8 w0 = wcp[(0 * 4 + q) * 64 + ct * 16 + m];
            bfx8 w1 = wcp[(1 * 4 + q) * 64 + ct * 16 + m];
            f32x4 acc = (f32x4){0.f, 0.f, 0.f, 0.f};
            acc = __builtin_amdgcn_mfma_f32_16x16x32_bf16(a0, w0, acc, 0, 0, 0);
            acc = __builtin_amdgcn_mfma_f32_16x16x32_bf16(a1, w1, acc, 0, 0, 0);
            #pragma unroll
            for (int r = 0; r < 4; ++r)
                outt[(rt * 16 + q * 4 + r) * 64 + ct * 16 + m] = f2bf(acc[r]);
        }
    }
    __syncthreads();

    // coalesced store: one float4 (8 bf16) per thread
    int rr = t >> 3, cc = t & 7;
    ((float4*)y2)[((long long)blockIdx.x * 32 + rr) * 8 + cc] =
        *(const float4*)&outt[rr * 64 + cc * 8];
}

// ---------------------------------------------------------------------------
// gather + BN2 + ReLU + pool: h4 = relu(A2*(y2[i]+sum y2[src])+B2);
// xs[batch[i]] += h4. Segmented LDS pool.
// ---------------------------------------------------------------------------
__global__ __launch_bounds__(256) void gather_pool_kernel(
    const unsigned short* __restrict__ feat,
    const int* __restrict__ rowptr, const int* __restrict__ rowend,
    const int* __restrict__ csr_src,
    const float* __restrict__ AB, const int* __restrict__ batch,
    float* __restrict__ xs) {
    __shared__ float h4[32 * 65];
    __shared__ int bts[32];
    int t = threadIdx.x;
    int nl = t >> 3;                 // 0..31 local node
    int q = t & 7;
    int node = blockIdx.x * 32 + nl;
    if (t < 32) bts[t] = batch[blockIdx.x * 32 + t];
    const u16x8* f8 = (const u16x8*)feat;
    u16x8 sv = f8[(long long)node * 8 + q];
    float acc[8];
    #pragma unroll
    for (int j = 0; j < 8; ++j) acc[j] = bf2f(sv[j]);
    int beg = rowptr[node], end = rowend[node];
    int k = beg;
    int sn = (k < end) ? csr_src[k] : 0;
    while (k < end) {
        int sc = sn;
        ++k;
        if (k < end) sn = csr_src[k];
        u16x8 v = f8[(long long)sc * 8 + q];
        #pragma unroll
        for (int j = 0; j < 8; ++j) acc[j] += bf2f(v[j]);
    }
    #pragma unroll
    for (int j = 0; j < 8; ++j) {
        int c = q * 8 + j;
        h4[nl * 65 + c] = fmaxf(acc[j] * AB[128 + c] + AB[192 + c], 0.f);
    }
    __syncthreads();

    int col = t & 63;
    int r0 = (t >> 6) * 8;
    int cb = bts[r0];
    float cur = 0.f;
    #pragma unroll
    for (int r = 0; r < 8; ++r) {
        int b = bts[r0 + r];
        if (b != cb) {
            unsafeAtomicAdd(&xs[cb * 64 + col], cur);
            cb = b;
            cur = 0.f;
        }
        cur += h4[(r0 + r) * 65 + col];
    }
    unsafeAtomicAdd(&xs[cb * 64 + col], cur);
}

// ---------------------------------------------------------------------------
// Head: x_topo = relu(topo @ Wt + bt); out = [x_struct, x_topo] @ Wc + bc
// ---------------------------------------------------------------------------
__global__ __launch_bounds__(64) void head_kernel(
    const float* __restrict__ xs, const float* __restrict__ topo,
    const float* __restrict__ Wt, const float* __restrict__ bt,
    const float* __restrict__ Wc, const float* __restrict__ bc,
    float* __restrict__ out) {
    __shared__ float trow[64];
    __shared__ float comb[128];
    int b = blockIdx.x;
    int h = threadIdx.x;
    trow[h] = topo[b * 64 + h];
    __syncthreads();
    float acc = bt[h];
    #pragma unroll
    for (int k = 0; k < 64; ++k) acc += trow[k] * Wt[k * 64 + h];
    comb[h] = xs[b * 64 + h];
    comb[64 + h] = fmaxf(acc, 0.f);
    __syncthreads();
    if (h < NCLASS) {
        float o = bc[h];
        #pragma unroll
        for (int k = 0; k < 128; ++k) o += comb[k] * Wc[k * NCLASS + h];
        out[b * NCLASS + h] = o;
    }
}

// ---------------------------------------------------------------------------
extern "C" void kernel_launch(void* const* d_in, const int* in_sizes, int n_in,
                              void* d_out, int out_size, void* d_ws, size_t ws_size,
                              hipStream_t stream) {
    const float* x     = (const float*)d_in[0];
    const int*   ei    = (const int*)d_in[1];
    const int*   batch = (const int*)d_in[2];
    const float* topo  = (const float*)d_in[3];
    const float* W1a   = (const float*)d_in[4];
    const float* b1a   = (const float*)d_in[5];
    const float* g1    = (const float*)d_in[6];
    const float* be1   = (const float*)d_in[7];
    const float* m1    = (const float*)d_in[8];
    const float* v1    = (const float*)d_in[9];
    const float* W1b   = (const float*)d_in[10];
    const float* b1b   = (const float*)d_in[11];
    const float* W2    = (const float*)d_in[12];
    const float* b2    = (const float*)d_in[13];
    const float* g2    = (const float*)d_in[14];
    const float* be2   = (const float*)d_in[15];
    const float* m2    = (const float*)d_in[16];
    const float* v2    = (const float*)d_in[17];
    const float* Wt    = (const float*)d_in[18];
    const float* bt    = (const float*)d_in[19];
    const float* Wc    = (const float*)d_in[20];
    const float* bc    = (const float*)d_in[21];
    float* out = (float*)d_out;

    // Workspace layout (16B-aligned chunks)
    char* p = (char*)d_ws;
    unsigned short* y0   = (unsigned short*)p; p += (size_t)N_NODES * DIM * 2;  // 12.8 MB
    unsigned short* y2b  = (unsigned short*)p; p += (size_t)N_NODES * DIM * 2;  // 12.8 MB
    float* xs      = (float*)p; p += (size_t)BGRAPHS * DIM * 4;                 // 256 KB
    int*   rowptr  = (int*)p;   p += (size_t)(N_NODES + 16) * 4;                // 400 KB
    int*   rowend  = (int*)p;   p += (size_t)(N_NODES + 16) * 4;                // 400 KB
    int*   cursor  = (int*)p;   p += 1024;                                      // 256 ints
    unsigned short* w1bp = (unsigned short*)p; p += 512 * 16;                   // 8 KB
    unsigned short* w2p  = (unsigned short*)p; p += 512 * 16;                   // 8 KB
    float* AB      = (float*)p; p += 256 * 4;                                   // 1 KB
    int*   srcbuf  = (int*)p;   p += (size_t)NBUCK * BCAP * 4;                  // 8.4 MB
    unsigned short* dstlbuf = (unsigned short*)p; p += (size_t)NBUCK * BCAP * 2;// 4.2 MB
    int*   csr_src = (int*)p;                                                   // 8.4 MB

    // 1) y0 = x@W1a + weight/BN-const prep + cursor region-init
    prep_kernel<<<NB_G + 1, 256, 0, stream>>>(
        x, W1a, y0, xs, W1b, W2, w1bp, w2p,
        b1a, g1, be1, m1, v1, b2, g2, be2, m2, v2, AB, cursor);
    // 2) partition edges into fixed bucket regions (no histogram, no scan)
    part_kernel<<<NBLK_P, 256, 0, stream>>>(ei, cursor, srcbuf, dstlbuf);
    // 3) per-bucket counting sort -> csr_src + rowptr/rowend
    refine_kernel<<<NBUCK, 256, 0, stream>>>(srcbuf, dstlbuf, cursor, csr_src, rowptr, rowend);
    // 4) fused agg1+BN1+ReLU + MLP (h1,h2 in LDS): y2 = relu(h1@W1b+b1b)@W2
    gather_mlp1_kernel<<<N_NODES / 32, 256, 0, stream>>>(
        y0, rowptr, rowend, csr_src, AB, w1bp, b1b, w2p, y2b);
    // 5) agg2 + BN2 + ReLU + pool
    gather_pool_kernel<<<N_NODES / 32, 256, 0, stream>>>(
        y2b, rowptr, rowend, csr_src, AB, batch, xs);
    // 6) head
    head_kernel<<<BGRAPHS, 64, 0, stream>>>(xs, topo, Wt, bt, Wc, bc, out);
}

// Round 11
// 225.290 us; speedup vs baseline: 4.3328x; 1.0008x over previous
//
#include <hip/hip_runtime.h>

// Problem constants (match reference)
#define N_NODES 100000
#define N_EDGES 1200000
#define DIM     64
#define BGRAPHS 1000
#define NCLASS  10
#define BN_EPS  1e-5f

// CSR-build partition constants
#define NBUCK   256            // coarse buckets
#define NPB     391            // nodes per bucket (256*391 = 100096 >= N)
#define MAGIC   10984572u      // ceil(2^32/391): bucket = umulhi(d, MAGIC)
#define CHUNK   2048           // edges per partition block (small -> high occupancy)
#define NBLK_P  586            // ceil(E / CHUNK)
#define BCAP    8192           // fixed per-bucket region capacity (proven >= max bucket size)
#define NB_G    1563           // ceil(N/64) GEMM blocks in prep

typedef __attribute__((ext_vector_type(8))) short   bfx8;   // 8 bf16 MFMA A/B frag
typedef __attribute__((ext_vector_type(4))) float   f32x4;  // MFMA C/D frag
typedef __attribute__((ext_vector_type(8))) unsigned short u16x8;

__device__ __forceinline__ unsigned short f2bf(float f) {
    unsigned u = __builtin_bit_cast(unsigned, f);
    unsigned r = (u + 0x7FFFu + ((u >> 16) & 1u)) >> 16;   // RNE
    return (unsigned short)r;
}
__device__ __forceinline__ float bf2f(unsigned short h) {
    unsigned u = ((unsigned)h) << 16;
    return __builtin_bit_cast(float, u);
}

// B-fragment loader: element j = W[(kt*32 + q*8 + j)][col]  (fp32 W -> bf16)
__device__ __forceinline__ bfx8 load_wfrag(const float* __restrict__ W, int kt, int q, int col) {
    bfx8 f;
    #pragma unroll
    for (int j = 0; j < 8; ++j)
        f[j] = (short)f2bf(W[(kt * 32 + q * 8 + j) * 64 + col]);
    return f;
}

// ---------------------------------------------------------------------------
// Prep kernel (merged):
//   blocks [0,NB_G)  : y0 = bf16(x) @ bf16(W1a); zeros xs
//   block  NB_G      : fragment-prep W1b/W2 + BN consts AB + cursor[b]=b*BCAP
// ---------------------------------------------------------------------------
__global__ __launch_bounds__(256) void prep_kernel(
    const float* __restrict__ x,
    const float* __restrict__ W1a, unsigned short* __restrict__ y0,
    float* __restrict__ xs,
    const float* __restrict__ W1b, const float* __restrict__ W2,
    unsigned short* __restrict__ w1bp, unsigned short* __restrict__ w2p,
    const float* __restrict__ b1a, const float* __restrict__ g1,
    const float* __restrict__ be1, const float* __restrict__ m1,
    const float* __restrict__ v1,
    const float* __restrict__ b2,  const float* __restrict__ g2,
    const float* __restrict__ be2, const float* __restrict__ m2,
    const float* __restrict__ v2,
    float* __restrict__ AB, int* __restrict__ cursor) {
    __shared__ unsigned short outt[4][16 * 64];
    int t = threadIdx.x;
    if (blockIdx.x < NB_G) {
        int g = blockIdx.x;
        if (g < (BGRAPHS * DIM) / 256) xs[g * 256 + t] = 0.f;
        int w = t >> 6, lane = t & 63;
        int m = lane & 15, q = lane >> 4;
        int row0 = g * 64 + w * 16;

        bfx8 wa[4][2];
        #pragma unroll
        for (int nt = 0; nt < 4; ++nt)
            #pragma unroll
            for (int kt = 0; kt < 2; ++kt)
                wa[nt][kt] = load_wfrag(W1a, kt, q, nt * 16 + m);

        int rowA = row0 + m;
        if (rowA > N_NODES - 1) rowA = N_NODES - 1;
        const float* xp = x + (long long)rowA * 64;
        bfx8 a0, a1;
        #pragma unroll
        for (int j = 0; j < 8; ++j) {
            a0[j] = (short)f2bf(xp[q * 8 + j]);
            a1[j] = (short)f2bf(xp[32 + q * 8 + j]);
        }
        f32x4 acc[4];
        #pragma unroll
        for (int nt = 0; nt < 4; ++nt) {
            acc[nt] = (f32x4){0.f, 0.f, 0.f, 0.f};
            acc[nt] = __builtin_amdgcn_mfma_f32_16x16x32_bf16(a0, wa[nt][0], acc[nt], 0, 0, 0);
            acc[nt] = __builtin_amdgcn_mfma_f32_16x16x32_bf16(a1, wa[nt][1], acc[nt], 0, 0, 0);
        }
        #pragma unroll
        for (int nt = 0; nt < 4; ++nt)
            #pragma unroll
            for (int r = 0; r < 4; ++r)
                outt[w][(q * 4 + r) * 64 + nt * 16 + m] = f2bf(acc[nt][r]);
        __syncthreads();
        #pragma unroll
        for (int i = lane; i < 128; i += 64) {
            int rr = i >> 3, cc = i & 7;
            int rg = row0 + rr;
            if (rg < N_NODES)
                ((float4*)y0)[(long long)rg * 8 + cc] = *(const float4*)&outt[w][rr * 64 + cc * 8];
        }
    } else {
        // fragment-prep W1b, W2; AB constants; cursor init to region starts
        cursor[t] = t * BCAP;
        const float* Ws[2] = {W1b, W2};
        unsigned short* Wp[2] = {w1bp, w2p};
        #pragma unroll
        for (int wsel = 0; wsel < 2; ++wsel) {
            const float* W = Ws[wsel];
            #pragma unroll
            for (int r = 0; r < 2; ++r) {
                int e = r * 256 + t;           // 0..511
                int kt = e >> 8, q = (e >> 6) & 3, col = e & 63;
                u16x8 o;
                #pragma unroll
                for (int j = 0; j < 8; ++j)
                    o[j] = f2bf(W[(kt * 32 + q * 8 + j) * 64 + col]);
                ((u16x8*)Wp[wsel])[e] = o;
            }
        }
        if (t < 64) {
            float s1 = g1[t] * rsqrtf(v1[t] + BN_EPS);
            AB[t]       = s1;
            AB[64 + t]  = b1a[t] * s1 + (be1[t] - m1[t] * s1);
            float s2 = g2[t] * rsqrtf(v2[t] + BN_EPS);
            AB[128 + t] = s2;
            AB[192 + t] = b2[t] * s2 + (be2[t] - m2[t] * s2);
        }
    }
}

// ---------------------------------------------------------------------------
// Partition into FIXED per-bucket regions [b*BCAP, b*BCAP+size): LDS count
// of this chunk -> one cursor atomicAdd per bucket -> place. Small CHUNK
// (2048) -> 586 blocks -> ~9 waves/CU (was 147 blocks @ 5% occupancy, 44us).
// ---------------------------------------------------------------------------
__global__ __launch_bounds__(256) void part_kernel(const int* __restrict__ ei,
                                                   int* __restrict__ cursor,
                                                   int* __restrict__ srcbuf,
                                                   unsigned short* __restrict__ dstlbuf) {
    __shared__ int cnt[NBUCK];
    __shared__ int cur[NBUCK];
    int t = threadIdx.x, blk = blockIdx.x;
    cnt[t] = 0;
    __syncthreads();
    int e0 = blk * CHUNK;
    #pragma unroll
    for (int i = t; i < CHUNK; i += 256) {
        int e = e0 + i;
        if (e >= N_EDGES) break;
        unsigned d = (unsigned)ei[N_EDGES + e];
        atomicAdd(&cnt[__umulhi(d, MAGIC)], 1);
    }
    __syncthreads();
    cur[t] = atomicAdd(&cursor[t], cnt[t]);
    __syncthreads();
    #pragma unroll
    for (int i = t; i < CHUNK; i += 256) {
        int e = e0 + i;
        if (e >= N_EDGES) break;
        unsigned d = (unsigned)ei[N_EDGES + e];
        int sv = ei[e];
        int b = __umulhi(d, MAGIC);
        int pos = atomicAdd(&cur[b], 1);
        srcbuf[pos] = sv;
        dstlbuf[pos] = (unsigned short)(d - b * NPB);
    }
}

// ---------------------------------------------------------------------------
// Refine: one block per bucket region; LDS counting sort by dst_local;
// coalesced csr_src write; emits BOTH rowptr (begin) and rowend (end) per
// node from the local exclusive scan -- fixed regions are non-contiguous,
// so end cannot come from the next node's rowptr.
// ---------------------------------------------------------------------------
__global__ __launch_bounds__(256) void refine_kernel(const int* __restrict__ srcbuf,
                                                     const unsigned short* __restrict__ dstlbuf,
                                                     const int* __restrict__ cursor,
                                                     int* __restrict__ csr_src,
                                                     int* __restrict__ rowptr,
                                                     int* __restrict__ rowend) {
    __shared__ int cnt[NPB + 1];
    __shared__ int cur[NPB + 1];
    __shared__ int tmp[256];
    __shared__ int outb[BCAP];
    int t = threadIdx.x, b = blockIdx.x;
    int beg = b * BCAP;
    int end = cursor[b];

    for (int i = t; i < NPB + 1; i += 256) cnt[i] = 0;
    __syncthreads();
    for (int i = beg + t; i < end; i += 256)
        atomicAdd(&cnt[dstlbuf[i]], 1);
    __syncthreads();

    // exclusive scan over NPB entries (2 elems/thread)
    int i0 = 2 * t, i1 = 2 * t + 1;
    int v0 = (i0 < NPB) ? cnt[i0] : 0;
    int v1 = (i1 < NPB) ? cnt[i1] : 0;
    int s = v0 + v1;
    tmp[t] = s;
    __syncthreads();
    for (int off = 1; off < 256; off <<= 1) {
        int a = (t >= off) ? tmp[t - off] : 0;
        __syncthreads();
        tmp[t] += a;
        __syncthreads();
    }
    int excl = tmp[t] - s;
    if (i0 < NPB) cur[i0] = excl;
    if (i1 < NPB) cur[i1] = excl + v0;
    {
        int g0 = b * NPB + i0;
        if (i0 < NPB && g0 < N_NODES) {
            rowptr[g0] = beg + excl;
            rowend[g0] = beg + excl + v0;
        }
        int g1 = b * NPB + i1;
        if (i1 < NPB && g1 < N_NODES) {
            rowptr[g1] = beg + excl + v0;
            rowend[g1] = beg + excl + v0 + v1;
        }
    }
    __syncthreads();

    for (int i = beg + t; i < end; i += 256) {
        int dl = dstlbuf[i];
        int pos = atomicAdd(&cur[dl], 1);
        if (pos < BCAP) outb[pos] = srcbuf[i];
    }
    __syncthreads();

    int nb = end - beg; if (nb > BCAP) nb = BCAP;
    for (int i = t; i < nb; i += 256) csr_src[beg + i] = outb[i];
}

// ---------------------------------------------------------------------------
// Fused agg1 + BN1 + ReLU + MLP: per block of 32 nodes,
//   h1 = relu(A1*agg(y0)+B1)          (gather loop byte-identical to proven)
//   h2 = relu(h1 @ W1b + b1b)         (LDS-staged MFMA, 2 row-tiles x 4 col-tiles)
//   y2 = h2 @ W2
// ---------------------------------------------------------------------------
__global__ __launch_bounds__(256) void gather_mlp1_kernel(
    const unsigned short* __restrict__ feat,
    const int* __restrict__ rowptr, const int* __restrict__ rowend,
    const int* __restrict__ csr_src,
    const float* __restrict__ AB,
    const unsigned short* __restrict__ w1bp, const float* __restrict__ b1b,
    const unsigned short* __restrict__ w2p,
    unsigned short* __restrict__ y2) {
    __shared__ unsigned short h1t[32 * 72];
    __shared__ unsigned short h2t[32 * 72];
    __shared__ unsigned short outt[32 * 64];

    int t = threadIdx.x;
    int nl = t >> 3, q8 = t & 7;
    int node = blockIdx.x * 32 + nl;
    const u16x8* f8 = (const u16x8*)feat;
    {
        u16x8 sv = f8[(long long)node * 8 + q8];
        float acc[8];
        #pragma unroll
        for (int j = 0; j < 8; ++j) acc[j] = bf2f(sv[j]);
        int beg = rowptr[node], end = rowend[node];
        int k = beg;
        int sn = (k < end) ? csr_src[k] : 0;
        while (k < end) {
            int sc = sn;
            ++k;
            if (k < end) sn = csr_src[k];
            u16x8 v = f8[(long long)sc * 8 + q8];
            #pragma unroll
            for (int j = 0; j < 8; ++j) acc[j] += bf2f(v[j]);
        }
        #pragma unroll
        for (int j = 0; j < 8; ++j) {
            int c = q8 * 8 + j;
            h1t[nl * 72 + c] = f2bf(fmaxf(acc[j] * AB[c] + AB[64 + c], 0.f));
        }
    }
    __syncthreads();

    // MFMA phase: wave w owns row-tile rt=w>>1 (16 rows), col-tiles c0,c0+1
    int w = t >> 6, lane = t & 63;
    int m = lane & 15, q = lane >> 4;
    int rt = w >> 1;
    int c0 = (w & 1) * 2;

    const bfx8* wbp = (const bfx8*)w1bp;
    const bfx8* wcp = (const bfx8*)w2p;

    {
        const bfx8* hp = (const bfx8*)&h1t[(rt * 16 + m) * 72];
        bfx8 a0 = hp[q];
        bfx8 a1 = hp[4 + q];
        #pragma unroll
        for (int ci = 0; ci < 2; ++ci) {
            int ct = c0 + ci;
            bfx8 w0 = wbp[(0 * 4 + q) * 64 + ct * 16 + m];
            bfx8 w1 = wbp[(1 * 4 + q) * 64 + ct * 16 + m];
            f32x4 acc = (f32x4){0.f, 0.f, 0.f, 0.f};
            acc = __builtin_amdgcn_mfma_f32_16x16x32_bf16(a0, w0, acc, 0, 0, 0);
            acc = __builtin_amdgcn_mfma_f32_16x16x32_bf16(a1, w1, acc, 0, 0, 0);
            float bb = b1b[ct * 16 + m];
            #pragma unroll
            for (int r = 0; r < 4; ++r)
                h2t[(rt * 16 + q * 4 + r) * 72 + ct * 16 + m] = f2bf(fmaxf(acc[r] + bb, 0.f));
        }
    }
    __syncthreads();

    {
        const bfx8* hp = (const bfx8*)&h2t[(rt * 16 + m) * 72];
        bfx8 a0 = hp[q];
        bfx8 a1 = hp[4 + q];
        #pragma unroll
        for (int ci = 0; ci < 2; ++ci) {
            int ct = c0 + ci;
            bfx8 w0 = wcp[(0 * 4 + q) * 64 + ct * 16 + m];
            bfx8 w1 = wcp[(1 * 4 + q) * 64 + ct * 16 + m];
            f32x4 acc = (f32x4){0.f, 0.f, 0.f, 0.f};
            acc = __builtin_amdgcn_mfma_f32_16x16x32_bf16(a0, w0, acc, 0, 0, 0);
            acc = __builtin_amdgcn_mfma_f32_16x16x32_bf16(a1, w1, acc, 0, 0, 0);
            #pragma unroll
            for (int r = 0; r < 4; ++r)
                outt[(rt * 16 + q * 4 + r) * 64 + ct * 16 + m] = f2bf(acc[r]);
        }
    }
    __syncthreads();

    // coalesced store: one float4 (8 bf16) per thread
    int rr = t >> 3, cc = t & 7;
    ((float4*)y2)[((long long)blockIdx.x * 32 + rr) * 8 + cc] =
        *(const float4*)&outt[rr * 64 + cc * 8];
}

// ---------------------------------------------------------------------------
// gather + BN2 + ReLU + pool: h4 = relu(A2*(y2[i]+sum y2[src])+B2);
// xs[batch[i]] += h4. Segmented LDS pool.
// ---------------------------------------------------------------------------
__global__ __launch_bounds__(256) void gather_pool_kernel(
    const unsigned short* __restrict__ feat,
    const int* __restrict__ rowptr, const int* __restrict__ rowend,
    const int* __restrict__ csr_src,
    const float* __restrict__ AB, const int* __restrict__ batch,
    float* __restrict__ xs) {
    __shared__ float h4[32 * 65];
    __shared__ int bts[32];
    int t = threadIdx.x;
    int nl = t >> 3;                 // 0..31 local node
    int q = t & 7;
    int node = blockIdx.x * 32 + nl;
    if (t < 32) bts[t] = batch[blockIdx.x * 32 + t];
    const u16x8* f8 = (const u16x8*)feat;
    u16x8 sv = f8[(long long)node * 8 + q];
    float acc[8];
    #pragma unroll
    for (int j = 0; j < 8; ++j) acc[j] = bf2f(sv[j]);
    int beg = rowptr[node], end = rowend[node];
    int k = beg;
    int sn = (k < end) ? csr_src[k] : 0;
    while (k < end) {
        int sc = sn;
        ++k;
        if (k < end) sn = csr_src[k];
        u16x8 v = f8[(long long)sc * 8 + q];
        #pragma unroll
        for (int j = 0; j < 8; ++j) acc[j] += bf2f(v[j]);
    }
    #pragma unroll
    for (int j = 0; j < 8; ++j) {
        int c = q * 8 + j;
        h4[nl * 65 + c] = fmaxf(acc[j] * AB[128 + c] + AB[192 + c], 0.f);
    }
    __syncthreads();

    int col = t & 63;
    int r0 = (t >> 6) * 8;
    int cb = bts[r0];
    float cur = 0.f;
    #pragma unroll
    for (int r = 0; r < 8; ++r) {
        int b = bts[r0 + r];
        if (b != cb) {
            unsafeAtomicAdd(&xs[cb * 64 + col], cur);
            cb = b;
            cur = 0.f;
        }
        cur += h4[(r0 + r) * 65 + col];
    }
    unsafeAtomicAdd(&xs[cb * 64 + col], cur);
}

// ---------------------------------------------------------------------------
// Head: x_topo = relu(topo @ Wt + bt); out = [x_struct, x_topo] @ Wc + bc
// ---------------------------------------------------------------------------
__global__ __launch_bounds__(64) void head_kernel(
    const float* __restrict__ xs, const float* __restrict__ topo,
    const float* __restrict__ Wt, const float* __restrict__ bt,
    const float* __restrict__ Wc, const float* __restrict__ bc,
    float* __restrict__ out) {
    __shared__ float trow[64];
    __shared__ float comb[128];
    int b = blockIdx.x;
    int h = threadIdx.x;
    trow[h] = topo[b * 64 + h];
    __syncthreads();
    float acc = bt[h];
    #pragma unroll
    for (int k = 0; k < 64; ++k) acc += trow[k] * Wt[k * 64 + h];
    comb[h] = xs[b * 64 + h];
    comb[64 + h] = fmaxf(acc, 0.f);
    __syncthreads();
    if (h < NCLASS) {
        float o = bc[h];
        #pragma unroll
        for (int k = 0; k < 128; ++k) o += comb[k] * Wc[k * NCLASS + h];
        out[b * NCLASS + h] = o;
    }
}

// ---------------------------------------------------------------------------
extern "C" void kernel_launch(void* const* d_in, const int* in_sizes, int n_in,
                              void* d_out, int out_size, void* d_ws, size_t ws_size,
                              hipStream_t stream) {
    const float* x     = (const float*)d_in[0];
    const int*   ei    = (const int*)d_in[1];
    const int*   batch = (const int*)d_in[2];
    const float* topo  = (const float*)d_in[3];
    const float* W1a   = (const float*)d_in[4];
    const float* b1a   = (const float*)d_in[5];
    const float* g1    = (const float*)d_in[6];
    const float* be1   = (const float*)d_in[7];
    const float* m1    = (const float*)d_in[8];
    const float* v1    = (const float*)d_in[9];
    const float* W1b   = (const float*)d_in[10];
    const float* b1b   = (const float*)d_in[11];
    const float* W2    = (const float*)d_in[12];
    const float* b2    = (const float*)d_in[13];
    const float* g2    = (const float*)d_in[14];
    const float* be2   = (const float*)d_in[15];
    const float* m2    = (const float*)d_in[16];
    const float* v2    = (const float*)d_in[17];
    const float* Wt    = (const float*)d_in[18];
    const float* bt    = (const float*)d_in[19];
    const float* Wc    = (const float*)d_in[20];
    const float* bc    = (const float*)d_in[21];
    float* out = (float*)d_out;

    // Workspace layout (16B-aligned chunks)
    char* p = (char*)d_ws;
    unsigned short* y0   = (unsigned short*)p; p += (size_t)N_NODES * DIM * 2;  // 12.8 MB
    unsigned short* y2b  = (unsigned short*)p; p += (size_t)N_NODES * DIM * 2;  // 12.8 MB
    float* xs      = (float*)p; p += (size_t)BGRAPHS * DIM * 4;                 // 256 KB
    int*   rowptr  = (int*)p;   p += (size_t)(N_NODES + 16) * 4;                // 400 KB
    int*   rowend  = (int*)p;   p += (size_t)(N_NODES + 16) * 4;                // 400 KB
    int*   cursor  = (int*)p;   p += 1024;                                      // 256 ints
    unsigned short* w1bp = (unsigned short*)p; p += 512 * 16;                   // 8 KB
    unsigned short* w2p  = (unsigned short*)p; p += 512 * 16;                   // 8 KB
    float* AB      = (float*)p; p += 256 * 4;                                   // 1 KB
    int*   srcbuf  = (int*)p;   p += (size_t)NBUCK * BCAP * 4;                  // 8.4 MB
    unsigned short* dstlbuf = (unsigned short*)p; p += (size_t)NBUCK * BCAP * 2;// 4.2 MB
    int*   csr_src = (int*)p;                                                   // 8.4 MB

    // 1) y0 = x@W1a + weight/BN-const prep + cursor region-init
    prep_kernel<<<NB_G + 1, 256, 0, stream>>>(
        x, W1a, y0, xs, W1b, W2, w1bp, w2p,
        b1a, g1, be1, m1, v1, b2, g2, be2, m2, v2, AB, cursor);
    // 2) partition edges into fixed bucket regions (586 blocks, high occupancy)
    part_kernel<<<NBLK_P, 256, 0, stream>>>(ei, cursor, srcbuf, dstlbuf);
    // 3) per-bucket counting sort -> csr_src + rowptr/rowend
    refine_kernel<<<NBUCK, 256, 0, stream>>>(srcbuf, dstlbuf, cursor, csr_src, rowptr, rowend);
    // 4) fused agg1+BN1+ReLU + MLP (h1,h2 in LDS): y2 = relu(h1@W1b+b1b)@W2
    gather_mlp1_kernel<<<N_NODES / 32, 256, 0, stream>>>(
        y0, rowptr, rowend, csr_src, AB, w1bp, b1b, w2p, y2b);
    // 5) agg2 + BN2 + ReLU + pool
    gather_pool_kernel<<<N_NODES / 32, 256, 0, stream>>>(
        y2b, rowptr, rowend, csr_src, AB, batch, xs);
    // 6) head
    head_kernel<<<BGRAPHS, 64, 0, stream>>>(xs, topo, Wt, bt, Wc, bc, out);
}

// Round 12
// 214.270 us; speedup vs baseline: 4.5556x; 1.0514x over previous
//
#include <hip/hip_runtime.h>

// Problem constants (match reference)
#define N_NODES 100000
#define N_EDGES 1200000
#define DIM     64
#define BGRAPHS 1000
#define NCLASS  10
#define BN_EPS  1e-5f

// CSR-build partition constants
#define NBUCK   256            // coarse buckets
#define NPB     391            // nodes per bucket (256*391 = 100096 >= N)
#define MAGIC   10984572u      // ceil(2^32/391): bucket = umulhi(d, MAGIC)
#define CHUNK   8192           // edges per partition block
#define NBLK_P  147            // ceil(E / CHUNK)
#define BCAP    8192           // fixed per-bucket region capacity (proven >= max bucket size)
#define NB_G    1563           // ceil(N/64) GEMM blocks in prep

typedef __attribute__((ext_vector_type(8))) short   bfx8;   // 8 bf16 MFMA A/B frag
typedef __attribute__((ext_vector_type(4))) float   f32x4;  // MFMA C/D frag
typedef __attribute__((ext_vector_type(8))) unsigned short u16x8;

__device__ __forceinline__ unsigned short f2bf(float f) {
    unsigned u = __builtin_bit_cast(unsigned, f);
    unsigned r = (u + 0x7FFFu + ((u >> 16) & 1u)) >> 16;   // RNE
    return (unsigned short)r;
}
__device__ __forceinline__ float bf2f(unsigned short h) {
    unsigned u = ((unsigned)h) << 16;
    return __builtin_bit_cast(float, u);
}

// B-fragment loader: element j = W[(kt*32 + q*8 + j)][col]  (fp32 W -> bf16)
__device__ __forceinline__ bfx8 load_wfrag(const float* __restrict__ W, int kt, int q, int col) {
    bfx8 f;
    #pragma unroll
    for (int j = 0; j < 8; ++j)
        f[j] = (short)f2bf(W[(kt * 32 + q * 8 + j) * 64 + col]);
    return f;
}

// ---------------------------------------------------------------------------
// Prep kernel (merged):
//   blocks [0,NB_G)  : y0 = bf16(x) @ bf16(W1a); zeros xs
//   block  NB_G      : fragment-prep W1b/W2 + BN consts AB + cursor[b]=b*BCAP
// ---------------------------------------------------------------------------
__global__ __launch_bounds__(256) void prep_kernel(
    const float* __restrict__ x,
    const float* __restrict__ W1a, unsigned short* __restrict__ y0,
    float* __restrict__ xs,
    const float* __restrict__ W1b, const float* __restrict__ W2,
    unsigned short* __restrict__ w1bp, unsigned short* __restrict__ w2p,
    const float* __restrict__ b1a, const float* __restrict__ g1,
    const float* __restrict__ be1, const float* __restrict__ m1,
    const float* __restrict__ v1,
    const float* __restrict__ b2,  const float* __restrict__ g2,
    const float* __restrict__ be2, const float* __restrict__ m2,
    const float* __restrict__ v2,
    float* __restrict__ AB, int* __restrict__ cursor) {
    __shared__ unsigned short outt[4][16 * 64];
    int t = threadIdx.x;
    if (blockIdx.x < NB_G) {
        int g = blockIdx.x;
        if (g < (BGRAPHS * DIM) / 256) xs[g * 256 + t] = 0.f;
        int w = t >> 6, lane = t & 63;
        int m = lane & 15, q = lane >> 4;
        int row0 = g * 64 + w * 16;

        bfx8 wa[4][2];
        #pragma unroll
        for (int nt = 0; nt < 4; ++nt)
            #pragma unroll
            for (int kt = 0; kt < 2; ++kt)
                wa[nt][kt] = load_wfrag(W1a, kt, q, nt * 16 + m);

        int rowA = row0 + m;
        if (rowA > N_NODES - 1) rowA = N_NODES - 1;
        const float* xp = x + (long long)rowA * 64;
        bfx8 a0, a1;
        #pragma unroll
        for (int j = 0; j < 8; ++j) {
            a0[j] = (short)f2bf(xp[q * 8 + j]);
            a1[j] = (short)f2bf(xp[32 + q * 8 + j]);
        }
        f32x4 acc[4];
        #pragma unroll
        for (int nt = 0; nt < 4; ++nt) {
            acc[nt] = (f32x4){0.f, 0.f, 0.f, 0.f};
            acc[nt] = __builtin_amdgcn_mfma_f32_16x16x32_bf16(a0, wa[nt][0], acc[nt], 0, 0, 0);
            acc[nt] = __builtin_amdgcn_mfma_f32_16x16x32_bf16(a1, wa[nt][1], acc[nt], 0, 0, 0);
        }
        #pragma unroll
        for (int nt = 0; nt < 4; ++nt)
            #pragma unroll
            for (int r = 0; r < 4; ++r)
                outt[w][(q * 4 + r) * 64 + nt * 16 + m] = f2bf(acc[nt][r]);
        __syncthreads();
        #pragma unroll
        for (int i = lane; i < 128; i += 64) {
            int rr = i >> 3, cc = i & 7;
            int rg = row0 + rr;
            if (rg < N_NODES)
                ((float4*)y0)[(long long)rg * 8 + cc] = *(const float4*)&outt[w][rr * 64 + cc * 8];
        }
    } else {
        // fragment-prep W1b, W2; AB constants; cursor init to region starts
        cursor[t] = t * BCAP;
        const float* Ws[2] = {W1b, W2};
        unsigned short* Wp[2] = {w1bp, w2p};
        #pragma unroll
        for (int wsel = 0; wsel < 2; ++wsel) {
            const float* W = Ws[wsel];
            #pragma unroll
            for (int r = 0; r < 2; ++r) {
                int e = r * 256 + t;           // 0..511
                int kt = e >> 8, q = (e >> 6) & 3, col = e & 63;
                u16x8 o;
                #pragma unroll
                for (int j = 0; j < 8; ++j)
                    o[j] = f2bf(W[(kt * 32 + q * 8 + j) * 64 + col]);
                ((u16x8*)Wp[wsel])[e] = o;
            }
        }
        if (t < 64) {
            float s1 = g1[t] * rsqrtf(v1[t] + BN_EPS);
            AB[t]       = s1;
            AB[64 + t]  = b1a[t] * s1 + (be1[t] - m1[t] * s1);
            float s2 = g2[t] * rsqrtf(v2[t] + BN_EPS);
            AB[128 + t] = s2;
            AB[192 + t] = b2[t] * s2 + (be2[t] - m2[t] * s2);
        }
    }
}

// ---------------------------------------------------------------------------
// Partition into FIXED per-bucket regions, write-coalesced: counting-sort
// the chunk by bucket in LDS (refine's proven pattern), reserve one global
// range per bucket, then flush bucket-sorted records with near-coalesced
// 8B stores (consecutive i within a bucket segment -> contiguous dest).
// Record = int2{src, dst}. Replaces the 64-scattered-cachelines-per-wave
// store pattern that made part write 39MB for 7.2MB of payload (round 11).
// ---------------------------------------------------------------------------
__global__ __launch_bounds__(256) void part_kernel(const int* __restrict__ ei,
                                                   int* __restrict__ cursor,
                                                   int2* __restrict__ ebuf) {
    __shared__ int cnt[NBUCK];
    __shared__ int cur[NBUCK];
    __shared__ int goff[NBUCK];
    __shared__ int tmp[256];
    __shared__ int2 outb[CHUNK];     // 64 KB staging
    int t = threadIdx.x, blk = blockIdx.x;
    int e0 = blk * CHUNK;
    int nE = N_EDGES - e0; if (nE > CHUNK) nE = CHUNK;

    cnt[t] = 0;
    __syncthreads();
    // pass 1: histogram by bucket (dst stream)
    for (int i = t; i < nE; i += 256) {
        unsigned d = (unsigned)ei[N_EDGES + e0 + i];
        atomicAdd(&cnt[__umulhi(d, MAGIC)], 1);
    }
    __syncthreads();
    // exclusive scan of cnt -> lbase; reserve global range; goff = gbase - lbase
    int s = cnt[t];
    tmp[t] = s;
    __syncthreads();
    for (int off = 1; off < 256; off <<= 1) {
        int a = (t >= off) ? tmp[t - off] : 0;
        __syncthreads();
        tmp[t] += a;
        __syncthreads();
    }
    int lbase = tmp[t] - s;
    int gbase = atomicAdd(&cursor[t], s);
    cur[t] = lbase;
    goff[t] = gbase - lbase;
    __syncthreads();
    // pass 2: LDS scatter (counting sort by bucket)
    for (int i = t; i < nE; i += 256) {
        int d = ei[N_EDGES + e0 + i];
        int sv = ei[e0 + i];
        int b = __umulhi((unsigned)d, MAGIC);
        int p = atomicAdd(&cur[b], 1);
        outb[p] = (int2){sv, d};
    }
    __syncthreads();
    // pass 3: coalesced flush -- ebuf[goff[b] + i], contiguous per segment
    for (int i = t; i < nE; i += 256) {
        int2 rec = outb[i];
        int b = __umulhi((unsigned)rec.y, MAGIC);
        ebuf[goff[b] + i] = rec;
    }
}

// ---------------------------------------------------------------------------
// Refine: one block per bucket region; LDS counting sort by dst_local
// (computed from the record's dst); coalesced csr_src write; emits rowptr
// (begin) and rowend (end) per node from the local exclusive scan.
// ---------------------------------------------------------------------------
__global__ __launch_bounds__(256) void refine_kernel(const int2* __restrict__ ebuf,
                                                     const int* __restrict__ cursor,
                                                     int* __restrict__ csr_src,
                                                     int* __restrict__ rowptr,
                                                     int* __restrict__ rowend) {
    __shared__ int cnt[NPB + 1];
    __shared__ int cur[NPB + 1];
    __shared__ int tmp[256];
    __shared__ int outb[BCAP];
    int t = threadIdx.x, b = blockIdx.x;
    int beg = b * BCAP;
    int end = cursor[b];
    int dbase = b * NPB;

    for (int i = t; i < NPB + 1; i += 256) cnt[i] = 0;
    __syncthreads();
    for (int i = beg + t; i < end; i += 256)
        atomicAdd(&cnt[ebuf[i].y - dbase], 1);
    __syncthreads();

    // exclusive scan over NPB entries (2 elems/thread)
    int i0 = 2 * t, i1 = 2 * t + 1;
    int v0 = (i0 < NPB) ? cnt[i0] : 0;
    int v1 = (i1 < NPB) ? cnt[i1] : 0;
    int s = v0 + v1;
    tmp[t] = s;
    __syncthreads();
    for (int off = 1; off < 256; off <<= 1) {
        int a = (t >= off) ? tmp[t - off] : 0;
        __syncthreads();
        tmp[t] += a;
        __syncthreads();
    }
    int excl = tmp[t] - s;
    if (i0 < NPB) cur[i0] = excl;
    if (i1 < NPB) cur[i1] = excl + v0;
    {
        int g0 = dbase + i0;
        if (i0 < NPB && g0 < N_NODES) {
            rowptr[g0] = beg + excl;
            rowend[g0] = beg + excl + v0;
        }
        int g1 = dbase + i1;
        if (i1 < NPB && g1 < N_NODES) {
            rowptr[g1] = beg + excl + v0;
            rowend[g1] = beg + excl + v0 + v1;
        }
    }
    __syncthreads();

    for (int i = beg + t; i < end; i += 256) {
        int2 rec = ebuf[i];
        int dl = rec.y - dbase;
        int pos = atomicAdd(&cur[dl], 1);
        if (pos < BCAP) outb[pos] = rec.x;
    }
    __syncthreads();

    int nb = end - beg; if (nb > BCAP) nb = BCAP;
    for (int i = t; i < nb; i += 256) csr_src[beg + i] = outb[i];
}

// ---------------------------------------------------------------------------
// Fused agg1 + BN1 + ReLU + MLP: per block of 32 nodes,
//   h1 = relu(A1*agg(y0)+B1)          (gather loop byte-identical to proven)
//   h2 = relu(h1 @ W1b + b1b)         (LDS-staged MFMA, 2 row-tiles x 4 col-tiles)
//   y2 = h2 @ W2
// ---------------------------------------------------------------------------
__global__ __launch_bounds__(256) void gather_mlp1_kernel(
    const unsigned short* __restrict__ feat,
    const int* __restrict__ rowptr, const int* __restrict__ rowend,
    const int* __restrict__ csr_src,
    const float* __restrict__ AB,
    const unsigned short* __restrict__ w1bp, const float* __restrict__ b1b,
    const unsigned short* __restrict__ w2p,
    unsigned short* __restrict__ y2) {
    __shared__ unsigned short h1t[32 * 72];
    __shared__ unsigned short h2t[32 * 72];
    __shared__ unsigned short outt[32 * 64];

    int t = threadIdx.x;
    int nl = t >> 3, q8 = t & 7;
    int node = blockIdx.x * 32 + nl;
    const u16x8* f8 = (const u16x8*)feat;
    {
        u16x8 sv = f8[(long long)node * 8 + q8];
        float acc[8];
        #pragma unroll
        for (int j = 0; j < 8; ++j) acc[j] = bf2f(sv[j]);
        int beg = rowptr[node], end = rowend[node];
        int k = beg;
        int sn = (k < end) ? csr_src[k] : 0;
        while (k < end) {
            int sc = sn;
            ++k;
            if (k < end) sn = csr_src[k];
            u16x8 v = f8[(long long)sc * 8 + q8];
            #pragma unroll
            for (int j = 0; j < 8; ++j) acc[j] += bf2f(v[j]);
        }
        #pragma unroll
        for (int j = 0; j < 8; ++j) {
            int c = q8 * 8 + j;
            h1t[nl * 72 + c] = f2bf(fmaxf(acc[j] * AB[c] + AB[64 + c], 0.f));
        }
    }
    __syncthreads();

    // MFMA phase: wave w owns row-tile rt=w>>1 (16 rows), col-tiles c0,c0+1
    int w = t >> 6, lane = t & 63;
    int m = lane & 15, q = lane >> 4;
    int rt = w >> 1;
    int c0 = (w & 1) * 2;

    const bfx8* wbp = (const bfx8*)w1bp;
    const bfx8* wcp = (const bfx8*)w2p;

    {
        const bfx8* hp = (const bfx8*)&h1t[(rt * 16 + m) * 72];
        bfx8 a0 = hp[q];
        bfx8 a1 = hp[4 + q];
        #pragma unroll
        for (int ci = 0; ci < 2; ++ci) {
            int ct = c0 + ci;
            bfx8 w0 = wbp[(0 * 4 + q) * 64 + ct * 16 + m];
            bfx8 w1 = wbp[(1 * 4 + q) * 64 + ct * 16 + m];
            f32x4 acc = (f32x4){0.f, 0.f, 0.f, 0.f};
            acc = __builtin_amdgcn_mfma_f32_16x16x32_bf16(a0, w0, acc, 0, 0, 0);
            acc = __builtin_amdgcn_mfma_f32_16x16x32_bf16(a1, w1, acc, 0, 0, 0);
            float bb = b1b[ct * 16 + m];
            #pragma unroll
            for (int r = 0; r < 4; ++r)
                h2t[(rt * 16 + q * 4 + r) * 72 + ct * 16 + m] = f2bf(fmaxf(acc[r] + bb, 0.f));
        }
    }
    __syncthreads();

    {
        const bfx8* hp = (const bfx8*)&h2t[(rt * 16 + m) * 72];
        bfx8 a0 = hp[q];
        bfx8 a1 = hp[4 + q];
        #pragma unroll
        for (int ci = 0; ci < 2; ++ci) {
            int ct = c0 + ci;
            bfx8 w0 = wcp[(0 * 4 + q) * 64 + ct * 16 + m];
            bfx8 w1 = wcp[(1 * 4 + q) * 64 + ct * 16 + m];
            f32x4 acc = (f32x4){0.f, 0.f, 0.f, 0.f};
            acc = __builtin_amdgcn_mfma_f32_16x16x32_bf16(a0, w0, acc, 0, 0, 0);
            acc = __builtin_amdgcn_mfma_f32_16x16x32_bf16(a1, w1, acc, 0, 0, 0);
            #pragma unroll
            for (int r = 0; r < 4; ++r)
                outt[(rt * 16 + q * 4 + r) * 64 + ct * 16 + m] = f2bf(acc[r]);
        }
    }
    __syncthreads();

    // coalesced store: one float4 (8 bf16) per thread
    int rr = t >> 3, cc = t & 7;
    ((float4*)y2)[((long long)blockIdx.x * 32 + rr) * 8 + cc] =
        *(const float4*)&outt[rr * 64 + cc * 8];
}

// ---------------------------------------------------------------------------
// gather + BN2 + ReLU + pool: h4 = relu(A2*(y2[i]+sum y2[src])+B2);
// xs[batch[i]] += h4. Segmented LDS pool.
// ---------------------------------------------------------------------------
__global__ __launch_bounds__(256) void gather_pool_kernel(
    const unsigned short* __restrict__ feat,
    const int* __restrict__ rowptr, const int* __restrict__ rowend,
    const int* __restrict__ csr_src,
    const float* __restrict__ AB, const int* __restrict__ batch,
    float* __restrict__ xs) {
    __shared__ float h4[32 * 65];
    __shared__ int bts[32];
    int t = threadIdx.x;
    int nl = t >> 3;                 // 0..31 local node
    int q = t & 7;
    int node = blockIdx.x * 32 + nl;
    if (t < 32) bts[t] = batch[blockIdx.x * 32 + t];
    const u16x8* f8 = (const u16x8*)feat;
    u16x8 sv = f8[(long long)node * 8 + q];
    float acc[8];
    #pragma unroll
    for (int j = 0; j < 8; ++j) acc[j] = bf2f(sv[j]);
    int beg = rowptr[node], end = rowend[node];
    int k = beg;
    int sn = (k < end) ? csr_src[k] : 0;
    while (k < end) {
        int sc = sn;
        ++k;
        if (k < end) sn = csr_src[k];
        u16x8 v = f8[(long long)sc * 8 + q];
        #pragma unroll
        for (int j = 0; j < 8; ++j) acc[j] += bf2f(v[j]);
    }
    #pragma unroll
    for (int j = 0; j < 8; ++j) {
        int c = q * 8 + j;
        h4[nl * 65 + c] = fmaxf(acc[j] * AB[128 + c] + AB[192 + c], 0.f);
    }
    __syncthreads();

    int col = t & 63;
    int r0 = (t >> 6) * 8;
    int cb = bts[r0];
    float cur = 0.f;
    #pragma unroll
    for (int r = 0; r < 8; ++r) {
        int b = bts[r0 + r];
        if (b != cb) {
            unsafeAtomicAdd(&xs[cb * 64 + col], cur);
            cb = b;
            cur = 0.f;
        }
        cur += h4[(r0 + r) * 65 + col];
    }
    unsafeAtomicAdd(&xs[cb * 64 + col], cur);
}

// ---------------------------------------------------------------------------
// Head: x_topo = relu(topo @ Wt + bt); out = [x_struct, x_topo] @ Wc + bc
// ---------------------------------------------------------------------------
__global__ __launch_bounds__(64) void head_kernel(
    const float* __restrict__ xs, const float* __restrict__ topo,
    const float* __restrict__ Wt, const float* __restrict__ bt,
    const float* __restrict__ Wc, const float* __restrict__ bc,
    float* __restrict__ out) {
    __shared__ float trow[64];
    __shared__ float comb[128];
    int b = blockIdx.x;
    int h = threadIdx.x;
    trow[h] = topo[b * 64 + h];
    __syncthreads();
    float acc = bt[h];
    #pragma unroll
    for (int k = 0; k < 64; ++k) acc += trow[k] * Wt[k * 64 + h];
    comb[h] = xs[b * 64 + h];
    comb[64 + h] = fmaxf(acc, 0.f);
    __syncthreads();
    if (h < NCLASS) {
        float o = bc[h];
        #pragma unroll
        for (int k = 0; k < 128; ++k) o += comb[k] * Wc[k * NCLASS + h];
        out[b * NCLASS + h] = o;
    }
}

// ---------------------------------------------------------------------------
extern "C" void kernel_launch(void* const* d_in, const int* in_sizes, int n_in,
                              void* d_out, int out_size, void* d_ws, size_t ws_size,
                              hipStream_t stream) {
    const float* x     = (const float*)d_in[0];
    const int*   ei    = (const int*)d_in[1];
    const int*   batch = (const int*)d_in[2];
    const float* topo  = (const float*)d_in[3];
    const float* W1a   = (const float*)d_in[4];
    const float* b1a   = (const float*)d_in[5];
    const float* g1    = (const float*)d_in[6];
    const float* be1   = (const float*)d_in[7];
    const float* m1    = (const float*)d_in[8];
    const float* v1    = (const float*)d_in[9];
    const float* W1b   = (const float*)d_in[10];
    const float* b1b   = (const float*)d_in[11];
    const float* W2    = (const float*)d_in[12];
    const float* b2    = (const float*)d_in[13];
    const float* g2    = (const float*)d_in[14];
    const float* be2   = (const float*)d_in[15];
    const float* m2    = (const float*)d_in[16];
    const float* v2    = (const float*)d_in[17];
    const float* Wt    = (const float*)d_in[18];
    const float* bt    = (const float*)d_in[19];
    const float* Wc    = (const float*)d_in[20];
    const float* bc    = (const float*)d_in[21];
    float* out = (float*)d_out;

    // Workspace layout (16B-aligned chunks)
    char* p = (char*)d_ws;
    unsigned short* y0   = (unsigned short*)p; p += (size_t)N_NODES * DIM * 2;  // 12.8 MB
    unsigned short* y2b  = (unsigned short*)p; p += (size_t)N_NODES * DIM * 2;  // 12.8 MB
    float* xs      = (float*)p; p += (size_t)BGRAPHS * DIM * 4;                 // 256 KB
    int*   rowptr  = (int*)p;   p += (size_t)(N_NODES + 16) * 4;                // 400 KB
    int*   rowend  = (int*)p;   p += (size_t)(N_NODES + 16) * 4;                // 400 KB
    int*   cursor  = (int*)p;   p += 1024;                                      // 256 ints
    unsigned short* w1bp = (unsigned short*)p; p += 512 * 16;                   // 8 KB
    unsigned short* w2p  = (unsigned short*)p; p += 512 * 16;                   // 8 KB
    float* AB      = (float*)p; p += 256 * 4;                                   // 1 KB
    int2*  ebuf    = (int2*)p;  p += (size_t)NBUCK * BCAP * 8;                  // 16.8 MB
    int*   csr_src = (int*)p;                                                   // 8.4 MB

    // 1) y0 = x@W1a + weight/BN-const prep + cursor region-init
    prep_kernel<<<NB_G + 1, 256, 0, stream>>>(
        x, W1a, y0, xs, W1b, W2, w1bp, w2p,
        b1a, g1, be1, m1, v1, b2, g2, be2, m2, v2, AB, cursor);
    // 2) partition edges into fixed bucket regions (LDS counting sort,
    //    coalesced flush of combined 8B records)
    part_kernel<<<NBLK_P, 256, 0, stream>>>(ei, cursor, ebuf);
    // 3) per-bucket counting sort -> csr_src + rowptr/rowend
    refine_kernel<<<NBUCK, 256, 0, stream>>>(ebuf, cursor, csr_src, rowptr, rowend);
    // 4) fused agg1+BN1+ReLU + MLP (h1,h2 in LDS): y2 = relu(h1@W1b+b1b)@W2
    gather_mlp1_kernel<<<N_NODES / 32, 256, 0, stream>>>(
        y0, rowptr, rowend, csr_src, AB, w1bp, b1b, w2p, y2b);
    // 5) agg2 + BN2 + ReLU + pool
    gather_pool_kernel<<<N_NODES / 32, 256, 0, stream>>>(
        y2b, rowptr, rowend, csr_src, AB, batch, xs);
    // 6) head
    head_kernel<<<BGRAPHS, 64, 0, stream>>>(xs, topo, Wt, bt, Wc, bc, out);
}

// Round 14
// 207.066 us; speedup vs baseline: 4.7141x; 1.0348x over previous
//
#include <hip/hip_runtime.h>

// Problem constants (match reference)
#define N_NODES 100000
#define N_EDGES 1200000
#define DIM     64
#define BGRAPHS 1000
#define NCLASS  10
#define BN_EPS  1e-5f

// CSR-build partition constants
#define NBUCK   256            // coarse buckets
#define NPB     391            // nodes per bucket (256*391 = 100096 >= N)
#define MAGIC   10984572u      // ceil(2^32/391): bucket = umulhi(d, MAGIC)
#define CHUNK   4096           // edges per partition block (32KB int2 staging)
#define NBLK_P  293            // ceil(E / CHUNK)
#define BCAP    8192           // fixed per-bucket region capacity (proven >= max bucket size)
#define NB_G    1563           // ceil(N/64) GEMM blocks in prep

typedef __attribute__((ext_vector_type(8))) short   bfx8;   // 8 bf16 MFMA A/B frag
typedef __attribute__((ext_vector_type(4))) float   f32x4;  // MFMA C/D frag
typedef __attribute__((ext_vector_type(8))) unsigned short u16x8;

__device__ __forceinline__ unsigned short f2bf(float f) {
    unsigned u = __builtin_bit_cast(unsigned, f);
    unsigned r = (u + 0x7FFFu + ((u >> 16) & 1u)) >> 16;   // RNE
    return (unsigned short)r;
}
__device__ __forceinline__ float bf2f(unsigned short h) {
    unsigned u = ((unsigned)h) << 16;
    return __builtin_bit_cast(float, u);
}

// B-fragment loader: element j = W[(kt*32 + q*8 + j)][col]  (fp32 W -> bf16)
__device__ __forceinline__ bfx8 load_wfrag(const float* __restrict__ W, int kt, int q, int col) {
    bfx8 f;
    #pragma unroll
    for (int j = 0; j < 8; ++j)
        f[j] = (short)f2bf(W[(kt * 32 + q * 8 + j) * 64 + col]);
    return f;
}

// ---------------------------------------------------------------------------
// Merged prep+part kernel (independent work streams co-scheduled):
//   blocks [0,NBLK_P)            : edge partition into fixed bucket regions
//                                  (LDS counting sort + coalesced int2 flush)
//   blocks [NBLK_P,NBLK_P+NB_G)  : y0 = bf16(x) @ bf16(W1a); zeros xs
//   block  NBLK_P+NB_G           : fragment-prep W1b/W2 + BN consts AB
// cursor zeroed by hipMemsetAsync before launch; reservation adds b*BCAP.
// ---------------------------------------------------------------------------
__global__ __launch_bounds__(256) void prep_kernel(
    const float* __restrict__ x, const int* __restrict__ ei,
    int2* __restrict__ ebuf, int* __restrict__ cursor,
    const float* __restrict__ W1a, unsigned short* __restrict__ y0,
    float* __restrict__ xs,
    const float* __restrict__ W1b, const float* __restrict__ W2,
    unsigned short* __restrict__ w1bp, unsigned short* __restrict__ w2p,
    const float* __restrict__ b1a, const float* __restrict__ g1,
    const float* __restrict__ be1, const float* __restrict__ m1,
    const float* __restrict__ v1,
    const float* __restrict__ b2,  const float* __restrict__ g2,
    const float* __restrict__ be2, const float* __restrict__ m2,
    const float* __restrict__ v2,
    float* __restrict__ AB) {
    __shared__ __align__(16) char smem[CHUNK * 8 + 4096];   // 36 KB union
    int t = threadIdx.x;
    if (blockIdx.x < NBLK_P) {
        // ---- edge partition branch ----
        int* cnt  = (int*)smem;              // 1 KB
        int* cur  = (int*)(smem + 1024);     // 1 KB
        int* goff = (int*)(smem + 2048);     // 1 KB
        int* tmp  = (int*)(smem + 3072);     // 1 KB
        int2* outb = (int2*)(smem + 4096);   // 32 KB staging
        int blk = blockIdx.x;
        int e0 = blk * CHUNK;
        int nE = N_EDGES - e0; if (nE > CHUNK) nE = CHUNK;

        cnt[t] = 0;
        __syncthreads();
        for (int i = t; i < nE; i += 256) {
            unsigned d = (unsigned)ei[N_EDGES + e0 + i];
            atomicAdd(&cnt[__umulhi(d, MAGIC)], 1);
        }
        __syncthreads();
        int s = cnt[t];
        tmp[t] = s;
        __syncthreads();
        for (int off = 1; off < 256; off <<= 1) {
            int a = (t >= off) ? tmp[t - off] : 0;
            __syncthreads();
            tmp[t] += a;
            __syncthreads();
        }
        int lbase = tmp[t] - s;
        int gbase = t * BCAP + atomicAdd(&cursor[t], s);
        cur[t] = lbase;
        goff[t] = gbase - lbase;
        __syncthreads();
        for (int i = t; i < nE; i += 256) {
            int d = ei[N_EDGES + e0 + i];
            int sv = ei[e0 + i];
            int b = __umulhi((unsigned)d, MAGIC);
            int p = atomicAdd(&cur[b], 1);
            outb[p] = (int2){sv, d};
        }
        __syncthreads();
        for (int i = t; i < nE; i += 256) {
            int2 rec = outb[i];
            int b = __umulhi((unsigned)rec.y, MAGIC);
            ebuf[goff[b] + i] = rec;
        }
    } else if (blockIdx.x < NBLK_P + NB_G) {
        // ---- y0 = x@W1a branch ----
        unsigned short* outt = (unsigned short*)smem;   // 8 KB of the union
        int g = blockIdx.x - NBLK_P;
        if (g < (BGRAPHS * DIM) / 256) xs[g * 256 + t] = 0.f;
        int w = t >> 6, lane = t & 63;
        int m = lane & 15, q = lane >> 4;
        int row0 = g * 64 + w * 16;

        bfx8 wa[4][2];
        #pragma unroll
        for (int nt = 0; nt < 4; ++nt)
            #pragma unroll
            for (int kt = 0; kt < 2; ++kt)
                wa[nt][kt] = load_wfrag(W1a, kt, q, nt * 16 + m);

        int rowA = row0 + m;
        if (rowA > N_NODES - 1) rowA = N_NODES - 1;
        const float* xp = x + (long long)rowA * 64;
        bfx8 a0, a1;
        #pragma unroll
        for (int j = 0; j < 8; ++j) {
            a0[j] = (short)f2bf(xp[q * 8 + j]);
            a1[j] = (short)f2bf(xp[32 + q * 8 + j]);
        }
        f32x4 acc[4];
        #pragma unroll
        for (int nt = 0; nt < 4; ++nt) {
            acc[nt] = (f32x4){0.f, 0.f, 0.f, 0.f};
            acc[nt] = __builtin_amdgcn_mfma_f32_16x16x32_bf16(a0, wa[nt][0], acc[nt], 0, 0, 0);
            acc[nt] = __builtin_amdgcn_mfma_f32_16x16x32_bf16(a1, wa[nt][1], acc[nt], 0, 0, 0);
        }
        #pragma unroll
        for (int nt = 0; nt < 4; ++nt)
            #pragma unroll
            for (int r = 0; r < 4; ++r)
                outt[w * 1024 + (q * 4 + r) * 64 + nt * 16 + m] = f2bf(acc[nt][r]);
        __syncthreads();
        #pragma unroll
        for (int i = lane; i < 128; i += 64) {
            int rr = i >> 3, cc = i & 7;   // rr in [0,16) within THIS wave's tile
            int rg = row0 + rr;
            if (rg < N_NODES)
                ((float4*)y0)[(long long)rg * 8 + cc] =
                    *(const float4*)&outt[w * 1024 + rr * 64 + cc * 8];
        }
    } else {
        // ---- fragment-prep W1b, W2; AB constants ----
        const float* Ws[2] = {W1b, W2};
        unsigned short* Wp[2] = {w1bp, w2p};
        #pragma unroll
        for (int wsel = 0; wsel < 2; ++wsel) {
            const float* W = Ws[wsel];
            #pragma unroll
            for (int r = 0; r < 2; ++r) {
                int e = r * 256 + t;           // 0..511
                int kt = e >> 8, q = (e >> 6) & 3, col = e & 63;
                u16x8 o;
                #pragma unroll
                for (int j = 0; j < 8; ++j)
                    o[j] = f2bf(W[(kt * 32 + q * 8 + j) * 64 + col]);
                ((u16x8*)Wp[wsel])[e] = o;
            }
        }
        if (t < 64) {
            float s1 = g1[t] * rsqrtf(v1[t] + BN_EPS);
            AB[t]       = s1;
            AB[64 + t]  = b1a[t] * s1 + (be1[t] - m1[t] * s1);
            float s2 = g2[t] * rsqrtf(v2[t] + BN_EPS);
            AB[128 + t] = s2;
            AB[192 + t] = b2[t] * s2 + (be2[t] - m2[t] * s2);
        }
    }
}

// ---------------------------------------------------------------------------
// Refine: one block per bucket region; LDS counting sort by dst_local
// (computed from the record's dst); coalesced csr_src write; emits rowptr
// (begin) and rowend (end) per node from the local exclusive scan.
// cursor[b] now holds bucket SIZE (cursor started at 0).
// ---------------------------------------------------------------------------
__global__ __launch_bounds__(256) void refine_kernel(const int2* __restrict__ ebuf,
                                                     const int* __restrict__ cursor,
                                                     int* __restrict__ csr_src,
                                                     int* __restrict__ rowptr,
                                                     int* __restrict__ rowend) {
    __shared__ int cnt[NPB + 1];
    __shared__ int cur[NPB + 1];
    __shared__ int tmp[256];
    __shared__ int outb[BCAP];
    int t = threadIdx.x, b = blockIdx.x;
    int beg = b * BCAP;
    int end = beg + cursor[b];
    int dbase = b * NPB;

    for (int i = t; i < NPB + 1; i += 256) cnt[i] = 0;
    __syncthreads();
    for (int i = beg + t; i < end; i += 256)
        atomicAdd(&cnt[ebuf[i].y - dbase], 1);
    __syncthreads();

    // exclusive scan over NPB entries (2 elems/thread)
    int i0 = 2 * t, i1 = 2 * t + 1;
    int v0 = (i0 < NPB) ? cnt[i0] : 0;
    int v1 = (i1 < NPB) ? cnt[i1] : 0;
    int s = v0 + v1;
    tmp[t] = s;
    __syncthreads();
    for (int off = 1; off < 256; off <<= 1) {
        int a = (t >= off) ? tmp[t - off] : 0;
        __syncthreads();
        tmp[t] += a;
        __syncthreads();
    }
    int excl = tmp[t] - s;
    if (i0 < NPB) cur[i0] = excl;
    if (i1 < NPB) cur[i1] = excl + v0;
    {
        int g0 = dbase + i0;
        if (i0 < NPB && g0 < N_NODES) {
            rowptr[g0] = beg + excl;
            rowend[g0] = beg + excl + v0;
        }
        int g1 = dbase + i1;
        if (i1 < NPB && g1 < N_NODES) {
            rowptr[g1] = beg + excl + v0;
            rowend[g1] = beg + excl + v0 + v1;
        }
    }
    __syncthreads();

    for (int i = beg + t; i < end; i += 256) {
        int2 rec = ebuf[i];
        int dl = rec.y - dbase;
        int pos = atomicAdd(&cur[dl], 1);
        if (pos < BCAP) outb[pos] = rec.x;
    }
    __syncthreads();

    int nb = end - beg; if (nb > BCAP) nb = BCAP;
    for (int i = t; i < nb; i += 256) csr_src[beg + i] = outb[i];
}

// ---------------------------------------------------------------------------
// Fused agg1 + BN1 + ReLU + MLP: per block of 32 nodes,
//   h1 = relu(A1*agg(y0)+B1)          (gather loop byte-identical to proven)
//   h2 = relu(h1 @ W1b + b1b)         (LDS-staged MFMA, 2 row-tiles x 4 col-tiles)
//   y2 = h2 @ W2
// ---------------------------------------------------------------------------
__global__ __launch_bounds__(256) void gather_mlp1_kernel(
    const unsigned short* __restrict__ feat,
    const int* __restrict__ rowptr, const int* __restrict__ rowend,
    const int* __restrict__ csr_src,
    const float* __restrict__ AB,
    const unsigned short* __restrict__ w1bp, const float* __restrict__ b1b,
    const unsigned short* __restrict__ w2p,
    unsigned short* __restrict__ y2) {
    __shared__ unsigned short h1t[32 * 72];
    __shared__ unsigned short h2t[32 * 72];
    __shared__ unsigned short outt[32 * 64];

    int t = threadIdx.x;
    int nl = t >> 3, q8 = t & 7;
    int node = blockIdx.x * 32 + nl;
    const u16x8* f8 = (const u16x8*)feat;
    {
        u16x8 sv = f8[(long long)node * 8 + q8];
        float acc[8];
        #pragma unroll
        for (int j = 0; j < 8; ++j) acc[j] = bf2f(sv[j]);
        int beg = rowptr[node], end = rowend[node];
        int k = beg;
        int sn = (k < end) ? csr_src[k] : 0;
        while (k < end) {
            int sc = sn;
            ++k;
            if (k < end) sn = csr_src[k];
            u16x8 v = f8[(long long)sc * 8 + q8];
            #pragma unroll
            for (int j = 0; j < 8; ++j) acc[j] += bf2f(v[j]);
        }
        #pragma unroll
        for (int j = 0; j < 8; ++j) {
            int c = q8 * 8 + j;
            h1t[nl * 72 + c] = f2bf(fmaxf(acc[j] * AB[c] + AB[64 + c], 0.f));
        }
    }
    __syncthreads();

    // MFMA phase: wave w owns row-tile rt=w>>1 (16 rows), col-tiles c0,c0+1
    int w = t >> 6, lane = t & 63;
    int m = lane & 15, q = lane >> 4;
    int rt = w >> 1;
    int c0 = (w & 1) * 2;

    const bfx8* wbp = (const bfx8*)w1bp;
    const bfx8* wcp = (const bfx8*)w2p;

    {
        const bfx8* hp = (const bfx8*)&h1t[(rt * 16 + m) * 72];
        bfx8 a0 = hp[q];
        bfx8 a1 = hp[4 + q];
        #pragma unroll
        for (int ci = 0; ci < 2; ++ci) {
            int ct = c0 + ci;
            bfx8 w0 = wbp[(0 * 4 + q) * 64 + ct * 16 + m];
            bfx8 w1 = wbp[(1 * 4 + q) * 64 + ct * 16 + m];
            f32x4 acc = (f32x4){0.f, 0.f, 0.f, 0.f};
            acc = __builtin_amdgcn_mfma_f32_16x16x32_bf16(a0, w0, acc, 0, 0, 0);
            acc = __builtin_amdgcn_mfma_f32_16x16x32_bf16(a1, w1, acc, 0, 0, 0);
            float bb = b1b[ct * 16 + m];
            #pragma unroll
            for (int r = 0; r < 4; ++r)
                h2t[(rt * 16 + q * 4 + r) * 72 + ct * 16 + m] = f2bf(fmaxf(acc[r] + bb, 0.f));
        }
    }
    __syncthreads();

    {
        const bfx8* hp = (const bfx8*)&h2t[(rt * 16 + m) * 72];
        bfx8 a0 = hp[q];
        bfx8 a1 = hp[4 + q];
        #pragma unroll
        for (int ci = 0; ci < 2; ++ci) {
            int ct = c0 + ci;
            bfx8 w0 = wcp[(0 * 4 + q) * 64 + ct * 16 + m];
            bfx8 w1 = wcp[(1 * 4 + q) * 64 + ct * 16 + m];
            f32x4 acc = (f32x4){0.f, 0.f, 0.f, 0.f};
            acc = __builtin_amdgcn_mfma_f32_16x16x32_bf16(a0, w0, acc, 0, 0, 0);
            acc = __builtin_amdgcn_mfma_f32_16x16x32_bf16(a1, w1, acc, 0, 0, 0);
            #pragma unroll
            for (int r = 0; r < 4; ++r)
                outt[(rt * 16 + q * 4 + r) * 64 + ct * 16 + m] = f2bf(acc[r]);
        }
    }
    __syncthreads();

    // coalesced store: one float4 (8 bf16) per thread
    int rr = t >> 3, cc = t & 7;
    ((float4*)y2)[((long long)blockIdx.x * 32 + rr) * 8 + cc] =
        *(const float4*)&outt[rr * 64 + cc * 8];
}

// ---------------------------------------------------------------------------
// gather + BN2 + ReLU + pool: h4 = relu(A2*(y2[i]+sum y2[src])+B2);
// xs[batch[i]] += h4. Segmented LDS pool.
// ---------------------------------------------------------------------------
__global__ __launch_bounds__(256) void gather_pool_kernel(
    const unsigned short* __restrict__ feat,
    const int* __restrict__ rowptr, const int* __restrict__ rowend,
    const int* __restrict__ csr_src,
    const float* __restrict__ AB, const int* __restrict__ batch,
    float* __restrict__ xs) {
    __shared__ float h4[32 * 65];
    __shared__ int bts[32];
    int t = threadIdx.x;
    int nl = t >> 3;                 // 0..31 local node
    int q = t & 7;
    int node = blockIdx.x * 32 + nl;
    if (t < 32) bts[t] = batch[blockIdx.x * 32 + t];
    const u16x8* f8 = (const u16x8*)feat;
    u16x8 sv = f8[(long long)node * 8 + q];
    float acc[8];
    #pragma unroll
    for (int j = 0; j < 8; ++j) acc[j] = bf2f(sv[j]);
    int beg = rowptr[node], end = rowend[node];
    int k = beg;
    int sn = (k < end) ? csr_src[k] : 0;
    while (k < end) {
        int sc = sn;
        ++k;
        if (k < end) sn = csr_src[k];
        u16x8 v = f8[(long long)sc * 8 + q];
        #pragma unroll
        for (int j = 0; j < 8; ++j) acc[j] += bf2f(v[j]);
    }
    #pragma unroll
    for (int j = 0; j < 8; ++j) {
        int c = q * 8 + j;
        h4[nl * 65 + c] = fmaxf(acc[j] * AB[128 + c] + AB[192 + c], 0.f);
    }
    __syncthreads();

    int col = t & 63;
    int r0 = (t >> 6) * 8;
    int cb = bts[r0];
    float cur = 0.f;
    #pragma unroll
    for (int r = 0; r < 8; ++r) {
        int b = bts[r0 + r];
        if (b != cb) {
            unsafeAtomicAdd(&xs[cb * 64 + col], cur);
            cb = b;
            cur = 0.f;
        }
        cur += h4[(r0 + r) * 65 + col];
    }
    unsafeAtomicAdd(&xs[cb * 64 + col], cur);
}

// ---------------------------------------------------------------------------
// Head: x_topo = relu(topo @ Wt + bt); out = [x_struct, x_topo] @ Wc + bc
// ---------------------------------------------------------------------------
__global__ __launch_bounds__(64) void head_kernel(
    const float* __restrict__ xs, const float* __restrict__ topo,
    const float* __restrict__ Wt, const float* __restrict__ bt,
    const float* __restrict__ Wc, const float* __restrict__ bc,
    float* __restrict__ out) {
    __shared__ float trow[64];
    __shared__ float comb[128];
    int b = blockIdx.x;
    int h = threadIdx.x;
    trow[h] = topo[b * 64 + h];
    __syncthreads();
    float acc = bt[h];
    #pragma unroll
    for (int k = 0; k < 64; ++k) acc += trow[k] * Wt[k * 64 + h];
    comb[h] = xs[b * 64 + h];
    comb[64 + h] = fmaxf(acc, 0.f);
    __syncthreads();
    if (h < NCLASS) {
        float o = bc[h];
        #pragma unroll
        for (int k = 0; k < 128; ++k) o += comb[k] * Wc[k * NCLASS + h];
        out[b * NCLASS + h] = o;
    }
}

// ---------------------------------------------------------------------------
extern "C" void kernel_launch(void* const* d_in, const int* in_sizes, int n_in,
                              void* d_out, int out_size, void* d_ws, size_t ws_size,
                              hipStream_t stream) {
    const float* x     = (const float*)d_in[0];
    const int*   ei    = (const int*)d_in[1];
    const int*   batch = (const int*)d_in[2];
    const float* topo  = (const float*)d_in[3];
    const float* W1a   = (const float*)d_in[4];
    const float* b1a   = (const float*)d_in[5];
    const float* g1    = (const float*)d_in[6];
    const float* be1   = (const float*)d_in[7];
    const float* m1    = (const float*)d_in[8];
    const float* v1    = (const float*)d_in[9];
    const float* W1b   = (const float*)d_in[10];
    const float* b1b   = (const float*)d_in[11];
    const float* W2    = (const float*)d_in[12];
    const float* b2    = (const float*)d_in[13];
    const float* g2    = (const float*)d_in[14];
    const float* be2   = (const float*)d_in[15];
    const float* m2    = (const float*)d_in[16];
    const float* v2    = (const float*)d_in[17];
    const float* Wt    = (const float*)d_in[18];
    const float* bt    = (const float*)d_in[19];
    const float* Wc    = (const float*)d_in[20];
    const float* bc    = (const float*)d_in[21];
    float* out = (float*)d_out;

    // Workspace layout (16B-aligned chunks)
    char* p = (char*)d_ws;
    unsigned short* y0   = (unsigned short*)p; p += (size_t)N_NODES * DIM * 2;  // 12.8 MB
    unsigned short* y2b  = (unsigned short*)p; p += (size_t)N_NODES * DIM * 2;  // 12.8 MB
    float* xs      = (float*)p; p += (size_t)BGRAPHS * DIM * 4;                 // 256 KB
    int*   rowptr  = (int*)p;   p += (size_t)(N_NODES + 16) * 4;                // 400 KB
    int*   rowend  = (int*)p;   p += (size_t)(N_NODES + 16) * 4;                // 400 KB
    int*   cursor  = (int*)p;   p += 1024;                                      // 256 ints
    unsigned short* w1bp = (unsigned short*)p; p += 512 * 16;                   // 8 KB
    unsigned short* w2p  = (unsigned short*)p; p += 512 * 16;                   // 8 KB
    float* AB      = (float*)p; p += 256 * 4;                                   // 1 KB
    int2*  ebuf    = (int2*)p;  p += (size_t)NBUCK * BCAP * 8;                  // 16.8 MB
    int*   csr_src = (int*)p;                                                   // 8.4 MB

    // 0) zero the bucket cursors (stream-ordered, graph-capturable)
    hipMemsetAsync(cursor, 0, NBUCK * sizeof(int), stream);
    // 1) merged: edge partition  ||  y0 = x@W1a  ||  weight/BN-const prep
    prep_kernel<<<NBLK_P + NB_G + 1, 256, 0, stream>>>(
        x, ei, ebuf, cursor, W1a, y0, xs, W1b, W2, w1bp, w2p,
        b1a, g1, be1, m1, v1, b2, g2, be2, m2, v2, AB);
    // 2) per-bucket counting sort -> csr_src + rowptr/rowend
    refine_kernel<<<NBUCK, 256, 0, stream>>>(ebuf, cursor, csr_src, rowptr, rowend);
    // 3) fused agg1+BN1+ReLU + MLP (h1,h2 in LDS): y2 = relu(h1@W1b+b1b)@W2
    gather_mlp1_kernel<<<N_NODES / 32, 256, 0, stream>>>(
        y0, rowptr, rowend, csr_src, AB, w1bp, b1b, w2p, y2b);
    // 4) agg2 + BN2 + ReLU + pool
    gather_pool_kernel<<<N_NODES / 32, 256, 0, stream>>>(
        y2b, rowptr, rowend, csr_src, AB, batch, xs);
    // 5) head
    head_kernel<<<BGRAPHS, 64, 0, stream>>>(xs, topo, Wt, bt, Wc, bc, out);
}

// Round 15
// 203.263 us; speedup vs baseline: 4.8023x; 1.0187x over previous
//
#include <hip/hip_runtime.h>

// Problem constants (match reference)
#define N_NODES 100000
#define N_EDGES 1200000
#define DIM     64
#define BGRAPHS 1000
#define NCLASS  10
#define BN_EPS  1e-5f

// CSR-build partition constants
#define NBUCK   256            // coarse buckets
#define NPB     391            // nodes per bucket (256*391 = 100096 >= N)
#define MAGIC   10984572u      // ceil(2^32/391): bucket = umulhi(d, MAGIC)
#define CHUNK   4096           // edges per partition block (32KB int2 staging)
#define NBLK_P  293            // ceil(E / CHUNK)
#define BCAP    8192           // fixed per-bucket region capacity (proven >= max bucket size)
#define NB_G    1563           // ceil(N/64) GEMM blocks in prep

typedef __attribute__((ext_vector_type(8))) short   bfx8;   // 8 bf16 MFMA A/B frag
typedef __attribute__((ext_vector_type(4))) float   f32x4;  // MFMA C/D frag
typedef __attribute__((ext_vector_type(8))) unsigned short u16x8;

__device__ __forceinline__ unsigned short f2bf(float f) {
    unsigned u = __builtin_bit_cast(unsigned, f);
    unsigned r = (u + 0x7FFFu + ((u >> 16) & 1u)) >> 16;   // RNE
    return (unsigned short)r;
}
__device__ __forceinline__ float bf2f(unsigned short h) {
    unsigned u = ((unsigned)h) << 16;
    return __builtin_bit_cast(float, u);
}

// B-fragment loader: element j = W[(kt*32 + q*8 + j)][col]  (fp32 W -> bf16)
__device__ __forceinline__ bfx8 load_wfrag(const float* __restrict__ W, int kt, int q, int col) {
    bfx8 f;
    #pragma unroll
    for (int j = 0; j < 8; ++j)
        f[j] = (short)f2bf(W[(kt * 32 + q * 8 + j) * 64 + col]);
    return f;
}

// ---------------------------------------------------------------------------
// Dual-accumulator gather core: self + even/odd neighbor chains (independent
// fp32 add chains keep 2 row-loads in flight per 8-lane group). Ownership,
// traffic, and layout identical to the proven single-acc loop.
// ---------------------------------------------------------------------------
__device__ __forceinline__ void gather_dual(const u16x8* __restrict__ f8,
                                            const int* __restrict__ csr_src,
                                            int node, int q, int beg, int end,
                                            float* acc) {
    u16x8 sv = f8[(long long)node * 8 + q];
    float acca[8], accb[8];
    #pragma unroll
    for (int j = 0; j < 8; ++j) { acca[j] = bf2f(sv[j]); accb[j] = 0.f; }
    int k = beg;
    for (; k + 2 <= end; k += 2) {
        int s0 = csr_src[k], s1 = csr_src[k + 1];
        u16x8 v0 = f8[(long long)s0 * 8 + q];
        u16x8 v1 = f8[(long long)s1 * 8 + q];
        #pragma unroll
        for (int j = 0; j < 8; ++j) {
            acca[j] += bf2f(v0[j]);
            accb[j] += bf2f(v1[j]);
        }
    }
    if (k < end) {
        int s0 = csr_src[k];
        u16x8 v0 = f8[(long long)s0 * 8 + q];
        #pragma unroll
        for (int j = 0; j < 8; ++j) acca[j] += bf2f(v0[j]);
    }
    #pragma unroll
    for (int j = 0; j < 8; ++j) acc[j] = acca[j] + accb[j];
}

// ---------------------------------------------------------------------------
// Merged prep+part kernel (independent work streams co-scheduled):
//   blocks [0,NBLK_P)            : edge partition into fixed bucket regions
//                                  (LDS counting sort + coalesced int2 flush)
//   blocks [NBLK_P,NBLK_P+NB_G)  : y0 = bf16(x) @ bf16(W1a); zeros xs
//   block  NBLK_P+NB_G           : fragment-prep W1b/W2 + BN consts AB
// cursor zeroed by hipMemsetAsync before launch; reservation adds b*BCAP.
// ---------------------------------------------------------------------------
__global__ __launch_bounds__(256) void prep_kernel(
    const float* __restrict__ x, const int* __restrict__ ei,
    int2* __restrict__ ebuf, int* __restrict__ cursor,
    const float* __restrict__ W1a, unsigned short* __restrict__ y0,
    float* __restrict__ xs,
    const float* __restrict__ W1b, const float* __restrict__ W2,
    unsigned short* __restrict__ w1bp, unsigned short* __restrict__ w2p,
    const float* __restrict__ b1a, const float* __restrict__ g1,
    const float* __restrict__ be1, const float* __restrict__ m1,
    const float* __restrict__ v1,
    const float* __restrict__ b2,  const float* __restrict__ g2,
    const float* __restrict__ be2, const float* __restrict__ m2,
    const float* __restrict__ v2,
    float* __restrict__ AB) {
    __shared__ __align__(16) char smem[CHUNK * 8 + 4096];   // 36 KB union
    int t = threadIdx.x;
    if (blockIdx.x < NBLK_P) {
        // ---- edge partition branch ----
        int* cnt  = (int*)smem;              // 1 KB
        int* cur  = (int*)(smem + 1024);     // 1 KB
        int* goff = (int*)(smem + 2048);     // 1 KB
        int* tmp  = (int*)(smem + 3072);     // 1 KB
        int2* outb = (int2*)(smem + 4096);   // 32 KB staging
        int blk = blockIdx.x;
        int e0 = blk * CHUNK;
        int nE = N_EDGES - e0; if (nE > CHUNK) nE = CHUNK;

        cnt[t] = 0;
        __syncthreads();
        for (int i = t; i < nE; i += 256) {
            unsigned d = (unsigned)ei[N_EDGES + e0 + i];
            atomicAdd(&cnt[__umulhi(d, MAGIC)], 1);
        }
        __syncthreads();
        int s = cnt[t];
        tmp[t] = s;
        __syncthreads();
        for (int off = 1; off < 256; off <<= 1) {
            int a = (t >= off) ? tmp[t - off] : 0;
            __syncthreads();
            tmp[t] += a;
            __syncthreads();
        }
        int lbase = tmp[t] - s;
        int gbase = t * BCAP + atomicAdd(&cursor[t], s);
        cur[t] = lbase;
        goff[t] = gbase - lbase;
        __syncthreads();
        for (int i = t; i < nE; i += 256) {
            int d = ei[N_EDGES + e0 + i];
            int sv = ei[e0 + i];
            int b = __umulhi((unsigned)d, MAGIC);
            int p = atomicAdd(&cur[b], 1);
            outb[p] = (int2){sv, d};
        }
        __syncthreads();
        for (int i = t; i < nE; i += 256) {
            int2 rec = outb[i];
            int b = __umulhi((unsigned)rec.y, MAGIC);
            ebuf[goff[b] + i] = rec;
        }
    } else if (blockIdx.x < NBLK_P + NB_G) {
        // ---- y0 = x@W1a branch ----
        unsigned short* outt = (unsigned short*)smem;   // 8 KB of the union
        int g = blockIdx.x - NBLK_P;
        if (g < (BGRAPHS * DIM) / 256) xs[g * 256 + t] = 0.f;
        int w = t >> 6, lane = t & 63;
        int m = lane & 15, q = lane >> 4;
        int row0 = g * 64 + w * 16;

        bfx8 wa[4][2];
        #pragma unroll
        for (int nt = 0; nt < 4; ++nt)
            #pragma unroll
            for (int kt = 0; kt < 2; ++kt)
                wa[nt][kt] = load_wfrag(W1a, kt, q, nt * 16 + m);

        int rowA = row0 + m;
        if (rowA > N_NODES - 1) rowA = N_NODES - 1;
        const float* xp = x + (long long)rowA * 64;
        bfx8 a0, a1;
        #pragma unroll
        for (int j = 0; j < 8; ++j) {
            a0[j] = (short)f2bf(xp[q * 8 + j]);
            a1[j] = (short)f2bf(xp[32 + q * 8 + j]);
        }
        f32x4 acc[4];
        #pragma unroll
        for (int nt = 0; nt < 4; ++nt) {
            acc[nt] = (f32x4){0.f, 0.f, 0.f, 0.f};
            acc[nt] = __builtin_amdgcn_mfma_f32_16x16x32_bf16(a0, wa[nt][0], acc[nt], 0, 0, 0);
            acc[nt] = __builtin_amdgcn_mfma_f32_16x16x32_bf16(a1, wa[nt][1], acc[nt], 0, 0, 0);
        }
        #pragma unroll
        for (int nt = 0; nt < 4; ++nt)
            #pragma unroll
            for (int r = 0; r < 4; ++r)
                outt[w * 1024 + (q * 4 + r) * 64 + nt * 16 + m] = f2bf(acc[nt][r]);
        __syncthreads();
        #pragma unroll
        for (int i = lane; i < 128; i += 64) {
            int rr = i >> 3, cc = i & 7;   // rr in [0,16) within THIS wave's tile
            int rg = row0 + rr;
            if (rg < N_NODES)
                ((float4*)y0)[(long long)rg * 8 + cc] =
                    *(const float4*)&outt[w * 1024 + rr * 64 + cc * 8];
        }
    } else {
        // ---- fragment-prep W1b, W2; AB constants ----
        const float* Ws[2] = {W1b, W2};
        unsigned short* Wp[2] = {w1bp, w2p};
        #pragma unroll
        for (int wsel = 0; wsel < 2; ++wsel) {
            const float* W = Ws[wsel];
            #pragma unroll
            for (int r = 0; r < 2; ++r) {
                int e = r * 256 + t;           // 0..511
                int kt = e >> 8, q = (e >> 6) & 3, col = e & 63;
                u16x8 o;
                #pragma unroll
                for (int j = 0; j < 8; ++j)
                    o[j] = f2bf(W[(kt * 32 + q * 8 + j) * 64 + col]);
                ((u16x8*)Wp[wsel])[e] = o;
            }
        }
        if (t < 64) {
            float s1 = g1[t] * rsqrtf(v1[t] + BN_EPS);
            AB[t]       = s1;
            AB[64 + t]  = b1a[t] * s1 + (be1[t] - m1[t] * s1);
            float s2 = g2[t] * rsqrtf(v2[t] + BN_EPS);
            AB[128 + t] = s2;
            AB[192 + t] = b2[t] * s2 + (be2[t] - m2[t] * s2);
        }
    }
}

// ---------------------------------------------------------------------------
// Refine: one block per bucket region; LDS counting sort by dst_local;
// coalesced csr_src write; emits rowspan = {begin, end} per node (int2).
// cursor[b] holds bucket SIZE (cursor started at 0).
// ---------------------------------------------------------------------------
__global__ __launch_bounds__(256) void refine_kernel(const int2* __restrict__ ebuf,
                                                     const int* __restrict__ cursor,
                                                     int* __restrict__ csr_src,
                                                     int2* __restrict__ rowspan) {
    __shared__ int cnt[NPB + 1];
    __shared__ int cur[NPB + 1];
    __shared__ int tmp[256];
    __shared__ int outb[BCAP];
    int t = threadIdx.x, b = blockIdx.x;
    int beg = b * BCAP;
    int end = beg + cursor[b];
    int dbase = b * NPB;

    for (int i = t; i < NPB + 1; i += 256) cnt[i] = 0;
    __syncthreads();
    for (int i = beg + t; i < end; i += 256)
        atomicAdd(&cnt[ebuf[i].y - dbase], 1);
    __syncthreads();

    // exclusive scan over NPB entries (2 elems/thread)
    int i0 = 2 * t, i1 = 2 * t + 1;
    int v0 = (i0 < NPB) ? cnt[i0] : 0;
    int v1 = (i1 < NPB) ? cnt[i1] : 0;
    int s = v0 + v1;
    tmp[t] = s;
    __syncthreads();
    for (int off = 1; off < 256; off <<= 1) {
        int a = (t >= off) ? tmp[t - off] : 0;
        __syncthreads();
        tmp[t] += a;
        __syncthreads();
    }
    int excl = tmp[t] - s;
    if (i0 < NPB) cur[i0] = excl;
    if (i1 < NPB) cur[i1] = excl + v0;
    {
        int g0 = dbase + i0;
        if (i0 < NPB && g0 < N_NODES)
            rowspan[g0] = (int2){beg + excl, beg + excl + v0};
        int g1 = dbase + i1;
        if (i1 < NPB && g1 < N_NODES)
            rowspan[g1] = (int2){beg + excl + v0, beg + excl + v0 + v1};
    }
    __syncthreads();

    for (int i = beg + t; i < end; i += 256) {
        int2 rec = ebuf[i];
        int dl = rec.y - dbase;
        int pos = atomicAdd(&cur[dl], 1);
        if (pos < BCAP) outb[pos] = rec.x;
    }
    __syncthreads();

    int nb = end - beg; if (nb > BCAP) nb = BCAP;
    for (int i = t; i < nb; i += 256) csr_src[beg + i] = outb[i];
}

// ---------------------------------------------------------------------------
// Fused agg1 + BN1 + ReLU + MLP: per block of 32 nodes,
//   h1 = relu(A1*agg(y0)+B1)          (dual-acc gather, same ownership)
//   h2 = relu(h1 @ W1b + b1b)         (LDS-staged MFMA)
//   y2 = h2 @ W2
// ---------------------------------------------------------------------------
__global__ __launch_bounds__(256) void gather_mlp1_kernel(
    const unsigned short* __restrict__ feat,
    const int2* __restrict__ rowspan,
    const int* __restrict__ csr_src,
    const float* __restrict__ AB,
    const unsigned short* __restrict__ w1bp, const float* __restrict__ b1b,
    const unsigned short* __restrict__ w2p,
    unsigned short* __restrict__ y2) {
    __shared__ unsigned short h1t[32 * 72];
    __shared__ unsigned short h2t[32 * 72];
    __shared__ unsigned short outt[32 * 64];

    int t = threadIdx.x;
    int nl = t >> 3, q8 = t & 7;
    int node = blockIdx.x * 32 + nl;
    const u16x8* f8 = (const u16x8*)feat;
    {
        int2 rs = rowspan[node];
        float acc[8];
        gather_dual(f8, csr_src, node, q8, rs.x, rs.y, acc);
        #pragma unroll
        for (int j = 0; j < 8; ++j) {
            int c = q8 * 8 + j;
            h1t[nl * 72 + c] = f2bf(fmaxf(acc[j] * AB[c] + AB[64 + c], 0.f));
        }
    }
    __syncthreads();

    // MFMA phase: wave w owns row-tile rt=w>>1 (16 rows), col-tiles c0,c0+1
    int w = t >> 6, lane = t & 63;
    int m = lane & 15, q = lane >> 4;
    int rt = w >> 1;
    int c0 = (w & 1) * 2;

    const bfx8* wbp = (const bfx8*)w1bp;
    const bfx8* wcp = (const bfx8*)w2p;

    {
        const bfx8* hp = (const bfx8*)&h1t[(rt * 16 + m) * 72];
        bfx8 a0 = hp[q];
        bfx8 a1 = hp[4 + q];
        #pragma unroll
        for (int ci = 0; ci < 2; ++ci) {
            int ct = c0 + ci;
            bfx8 w0 = wbp[(0 * 4 + q) * 64 + ct * 16 + m];
            bfx8 w1 = wbp[(1 * 4 + q) * 64 + ct * 16 + m];
            f32x4 acc = (f32x4){0.f, 0.f, 0.f, 0.f};
            acc = __builtin_amdgcn_mfma_f32_16x16x32_bf16(a0, w0, acc, 0, 0, 0);
            acc = __builtin_amdgcn_mfma_f32_16x16x32_bf16(a1, w1, acc, 0, 0, 0);
            float bb = b1b[ct * 16 + m];
            #pragma unroll
            for (int r = 0; r < 4; ++r)
                h2t[(rt * 16 + q * 4 + r) * 72 + ct * 16 + m] = f2bf(fmaxf(acc[r] + bb, 0.f));
        }
    }
    __syncthreads();

    {
        const bfx8* hp = (const bfx8*)&h2t[(rt * 16 + m) * 72];
        bfx8 a0 = hp[q];
        bfx8 a1 = hp[4 + q];
        #pragma unroll
        for (int ci = 0; ci < 2; ++ci) {
            int ct = c0 + ci;
            bfx8 w0 = wcp[(0 * 4 + q) * 64 + ct * 16 + m];
            bfx8 w1 = wcp[(1 * 4 + q) * 64 + ct * 16 + m];
            f32x4 acc = (f32x4){0.f, 0.f, 0.f, 0.f};
            acc = __builtin_amdgcn_mfma_f32_16x16x32_bf16(a0, w0, acc, 0, 0, 0);
            acc = __builtin_amdgcn_mfma_f32_16x16x32_bf16(a1, w1, acc, 0, 0, 0);
            #pragma unroll
            for (int r = 0; r < 4; ++r)
                outt[(rt * 16 + q * 4 + r) * 64 + ct * 16 + m] = f2bf(acc[r]);
        }
    }
    __syncthreads();

    // coalesced store: one float4 (8 bf16) per thread
    int rr = t >> 3, cc = t & 7;
    ((float4*)y2)[((long long)blockIdx.x * 32 + rr) * 8 + cc] =
        *(const float4*)&outt[rr * 64 + cc * 8];
}

// ---------------------------------------------------------------------------
// gather + BN2 + ReLU + pool: h4 = relu(A2*(y2[i]+sum y2[src])+B2);
// xs[batch[i]] += h4. Segmented LDS pool.
// ---------------------------------------------------------------------------
__global__ __launch_bounds__(256) void gather_pool_kernel(
    const unsigned short* __restrict__ feat,
    const int2* __restrict__ rowspan,
    const int* __restrict__ csr_src,
    const float* __restrict__ AB, const int* __restrict__ batch,
    float* __restrict__ xs) {
    __shared__ float h4[32 * 65];
    __shared__ int bts[32];
    int t = threadIdx.x;
    int nl = t >> 3;                 // 0..31 local node
    int q = t & 7;
    int node = blockIdx.x * 32 + nl;
    if (t < 32) bts[t] = batch[blockIdx.x * 32 + t];
    const u16x8* f8 = (const u16x8*)feat;
    int2 rs = rowspan[node];
    float acc[8];
    gather_dual(f8, csr_src, node, q, rs.x, rs.y, acc);
    #pragma unroll
    for (int j = 0; j < 8; ++j) {
        int c = q * 8 + j;
        h4[nl * 65 + c] = fmaxf(acc[j] * AB[128 + c] + AB[192 + c], 0.f);
    }
    __syncthreads();

    int col = t & 63;
    int r0 = (t >> 6) * 8;
    int cb = bts[r0];
    float cur = 0.f;
    #pragma unroll
    for (int r = 0; r < 8; ++r) {
        int b = bts[r0 + r];
        if (b != cb) {
            unsafeAtomicAdd(&xs[cb * 64 + col], cur);
            cb = b;
            cur = 0.f;
        }
        cur += h4[(r0 + r) * 65 + col];
    }
    unsafeAtomicAdd(&xs[cb * 64 + col], cur);
}

// ---------------------------------------------------------------------------
// Head: x_topo = relu(topo @ Wt + bt); out = [x_struct, x_topo] @ Wc + bc
// ---------------------------------------------------------------------------
__global__ __launch_bounds__(64) void head_kernel(
    const float* __restrict__ xs, const float* __restrict__ topo,
    const float* __restrict__ Wt, const float* __restrict__ bt,
    const float* __restrict__ Wc, const float* __restrict__ bc,
    float* __restrict__ out) {
    __shared__ float trow[64];
    __shared__ float comb[128];
    int b = blockIdx.x;
    int h = threadIdx.x;
    trow[h] = topo[b * 64 + h];
    __syncthreads();
    float acc = bt[h];
    #pragma unroll
    for (int k = 0; k < 64; ++k) acc += trow[k] * Wt[k * 64 + h];
    comb[h] = xs[b * 64 + h];
    comb[64 + h] = fmaxf(acc, 0.f);
    __syncthreads();
    if (h < NCLASS) {
        float o = bc[h];
        #pragma unroll
        for (int k = 0; k < 128; ++k) o += comb[k] * Wc[k * NCLASS + h];
        out[b * NCLASS + h] = o;
    }
}

// ---------------------------------------------------------------------------
extern "C" void kernel_launch(void* const* d_in, const int* in_sizes, int n_in,
                              void* d_out, int out_size, void* d_ws, size_t ws_size,
                              hipStream_t stream) {
    const float* x     = (const float*)d_in[0];
    const int*   ei    = (const int*)d_in[1];
    const int*   batch = (const int*)d_in[2];
    const float* topo  = (const float*)d_in[3];
    const float* W1a   = (const float*)d_in[4];
    const float* b1a   = (const float*)d_in[5];
    const float* g1    = (const float*)d_in[6];
    const float* be1   = (const float*)d_in[7];
    const float* m1    = (const float*)d_in[8];
    const float* v1    = (const float*)d_in[9];
    const float* W1b   = (const float*)d_in[10];
    const float* b1b   = (const float*)d_in[11];
    const float* W2    = (const float*)d_in[12];
    const float* b2    = (const float*)d_in[13];
    const float* g2    = (const float*)d_in[14];
    const float* be2   = (const float*)d_in[15];
    const float* m2    = (const float*)d_in[16];
    const float* v2    = (const float*)d_in[17];
    const float* Wt    = (const float*)d_in[18];
    const float* bt    = (const float*)d_in[19];
    const float* Wc    = (const float*)d_in[20];
    const float* bc    = (const float*)d_in[21];
    float* out = (float*)d_out;

    // Workspace layout (16B-aligned chunks)
    char* p = (char*)d_ws;
    unsigned short* y0   = (unsigned short*)p; p += (size_t)N_NODES * DIM * 2;  // 12.8 MB
    unsigned short* y2b  = (unsigned short*)p; p += (size_t)N_NODES * DIM * 2;  // 12.8 MB
    float* xs      = (float*)p; p += (size_t)BGRAPHS * DIM * 4;                 // 256 KB
    int2*  rowspan = (int2*)p;  p += (size_t)(N_NODES + 16) * 8;                // 800 KB
    int*   cursor  = (int*)p;   p += 1024;                                      // 256 ints
    unsigned short* w1bp = (unsigned short*)p; p += 512 * 16;                   // 8 KB
    unsigned short* w2p  = (unsigned short*)p; p += 512 * 16;                   // 8 KB
    float* AB      = (float*)p; p += 256 * 4;                                   // 1 KB
    int2*  ebuf    = (int2*)p;  p += (size_t)NBUCK * BCAP * 8;                  // 16.8 MB
    int*   csr_src = (int*)p;                                                   // 8.4 MB

    // 0) zero the bucket cursors (stream-ordered, graph-capturable)
    hipMemsetAsync(cursor, 0, NBUCK * sizeof(int), stream);
    // 1) merged: edge partition  ||  y0 = x@W1a  ||  weight/BN-const prep
    prep_kernel<<<NBLK_P + NB_G + 1, 256, 0, stream>>>(
        x, ei, ebuf, cursor, W1a, y0, xs, W1b, W2, w1bp, w2p,
        b1a, g1, be1, m1, v1, b2, g2, be2, m2, v2, AB);
    // 2) per-bucket counting sort -> csr_src + rowspan
    refine_kernel<<<NBUCK, 256, 0, stream>>>(ebuf, cursor, csr_src, rowspan);
    // 3) fused agg1+BN1+ReLU + MLP (h1,h2 in LDS): y2 = relu(h1@W1b+b1b)@W2
    gather_mlp1_kernel<<<N_NODES / 32, 256, 0, stream>>>(
        y0, rowspan, csr_src, AB, w1bp, b1b, w2p, y2b);
    // 4) agg2 + BN2 + ReLU + pool
    gather_pool_kernel<<<N_NODES / 32, 256, 0, stream>>>(
        y2b, rowspan, csr_src, AB, batch, xs);
    // 5) head
    head_kernel<<<BGRAPHS, 64, 0, stream>>>(xs, topo, Wt, bt, Wc, bc, out);
}